// Round 1
// baseline (1883.701 us; speedup 1.0000x reference)
//
#include <hip/hip_runtime.h>
#include <hip/hip_bf16.h>

typedef short v8s __attribute__((ext_vector_type(8)));
typedef float v4f __attribute__((ext_vector_type(4)));

#define S0R 12      // rounds 0..11 via gather-GEMM; lstm_tail covers s >= 12
#define NLEV 244    // tail levels 12..255

__device__ __forceinline__ float bf2f(unsigned short u) {
    union { unsigned int i; float f; } v; v.i = ((unsigned int)u) << 16; return v.f;
}
__device__ __forceinline__ unsigned short f2bf(float f) {
    union { float f; unsigned int i; } v; v.f = f;
    unsigned int x = v.i;
    return (unsigned short)((x + 0x7fffu + ((x >> 16) & 1u)) >> 16);
}
__device__ __forceinline__ float sigmoidf_(float x) { return 1.0f / (1.0f + expf(-x)); }

// async global->LDS, 16B per lane; LDS dst is wave-uniform base + lane*16
__device__ __forceinline__ void gld_lds16(const unsigned short* g, unsigned short* l) {
    __builtin_amdgcn_global_load_lds(
        (const __attribute__((address_space(1))) unsigned int*)g,
        (__attribute__((address_space(3))) unsigned int*)l, 16, 0, 0);
}

// ---------------------------------------------------------------------------
// gemm256: C[M,Npad] = act(A[M,512] @ W[Npad,512]^T + b1 (+b2)), bf16.
// 256x256 tile, BK=64, 8 waves (2Mx4N), 8-phase schedule with counted vmcnt
// (T3+T4), XOR-swizzled LDS reads (T2), setprio around MFMA (T5), XCD-chunked
// block swizzle (T1).  K fixed at 512 (8 K-tiles, 4 iterations).
//
// Per K-tile: phase q computes quadrant q (M-frags 2q,2q+1 x 4 N x 2 ks =
// 16 MFMA).  B-frags all read at the tile's first phase => whole B-half dead
// after it; A rows die quadrant-by-quadrant => staging tile t+2 into the
// buffer being read is safe at phases 2..5.  vmcnt(6) at p4/p8 covers
// everything issued through 3 phases ago = the tile consumed next.
// ---------------------------------------------------------------------------
template <bool TANH>
__global__ __launch_bounds__(512, 2)
void gemm256(const unsigned short* __restrict__ Ag, const unsigned short* __restrict__ Wg,
             const float* __restrict__ b1, const float* __restrict__ b2,
             unsigned short* __restrict__ Cg, int Nreal, int Npad, int Ntiles)
{
    __shared__ __align__(16) unsigned short As[2][256 * 64];   // 64 KB
    __shared__ __align__(16) unsigned short Bs[2][256 * 64];   // 64 KB

    const int tid  = threadIdx.x;
    const int w    = tid >> 6;          // 0..7
    const int lane = tid & 63;
    const int quad = lane >> 4;
    const int lr   = lane & 15;
    const int wm   = w >> 2;            // 0..1
    const int wn   = w & 3;             // 0..3

    // T1: XCD-chunked swizzle (all grids are multiples of 8)
    const int nwg = gridDim.x;
    const int cpx = nwg >> 3;
    const int swz = (blockIdx.x & 7) * cpx + (blockIdx.x >> 3);
    const int m0  = (swz / Ntiles) * 256;
    const int n0  = (swz % Ntiles) * 256;

    const unsigned short* gA = Ag + (size_t)m0 * 512;
    const unsigned short* gB = Wg + (size_t)n0 * 512;

    // staging map: one 64-row unit per gld_lds; wave w covers rows w*8..w*8+8
    // of the unit; source k-granule pre-swizzled so linear LDS dest + swizzled
    // read form a consistent involution (T2, key = row&7).
    const int sr  = w * 8 + (lane >> 3);
    const int skg = (lane & 7) ^ ((lane >> 3) & 7);

    auto SA = [&](int buf, int u, int kt) {
        gld_lds16(gA + (size_t)(u * 64 + sr) * 512 + kt * 64 + skg * 8,
                  &As[buf][(u * 64 + w * 8) * 64]);
    };
    auto SB = [&](int buf, int u, int kt) {
        gld_lds16(gB + (size_t)(u * 64 + sr) * 512 + kt * 64 + skg * 8,
                  &Bs[buf][(u * 64 + w * 8) * 64]);
    };

    // read-side swizzled granule offsets (row&7 == lr&7 since frag rows are
    // 16-aligned + lr)
    const int g8_0  = (quad ^ (lr & 7)) * 8;          // ks=0: kg = quad
    const int g8_1  = ((quad + 4) ^ (lr & 7)) * 8;    // ks=1: kg = 4+quad
    const int aBase = (wm * 128 + lr) * 64;
    const int bBase = (wn * 64 + lr) * 64;

    v4f zz = {0.f, 0.f, 0.f, 0.f};
    v4f acc[8][4];
    #pragma unroll
    for (int m = 0; m < 8; ++m)
        #pragma unroll
        for (int n = 0; n < 4; ++n) acc[m][n] = zz;
    v8s Bf[4][2];

#define DSB(BUF)                                                         \
    _Pragma("unroll")                                                    \
    for (int n = 0; n < 4; ++n) {                                        \
        Bf[n][0] = *(const v8s*)&Bs[BUF][bBase + n * 1024 + g8_0];       \
        Bf[n][1] = *(const v8s*)&Bs[BUF][bBase + n * 1024 + g8_1];       \
    }

#define PH(BUF, Q, STMTS, PREBAR)                                                     \
    {                                                                                 \
        const v8s a00 = *(const v8s*)&As[BUF][aBase + ((Q)*2 + 0) * 1024 + g8_0];     \
        const v8s a01 = *(const v8s*)&As[BUF][aBase + ((Q)*2 + 0) * 1024 + g8_1];     \
        const v8s a10 = *(const v8s*)&As[BUF][aBase + ((Q)*2 + 1) * 1024 + g8_0];     \
        const v8s a11 = *(const v8s*)&As[BUF][aBase + ((Q)*2 + 1) * 1024 + g8_1];     \
        STMTS;                                                                        \
        PREBAR;                                                                       \
        __builtin_amdgcn_s_barrier();                                                 \
        asm volatile("s_waitcnt lgkmcnt(0)" ::: "memory");                            \
        __builtin_amdgcn_sched_barrier(0);                                            \
        __builtin_amdgcn_s_setprio(1);                                                \
        _Pragma("unroll")                                                             \
        for (int n = 0; n < 4; ++n) {                                                 \
            acc[(Q)*2    ][n] = __builtin_amdgcn_mfma_f32_16x16x32_bf16(a00, Bf[n][0], acc[(Q)*2    ][n], 0, 0, 0); \
            acc[(Q)*2    ][n] = __builtin_amdgcn_mfma_f32_16x16x32_bf16(a01, Bf[n][1], acc[(Q)*2    ][n], 0, 0, 0); \
            acc[(Q)*2 + 1][n] = __builtin_amdgcn_mfma_f32_16x16x32_bf16(a10, Bf[n][0], acc[(Q)*2 + 1][n], 0, 0, 0); \
            acc[(Q)*2 + 1][n] = __builtin_amdgcn_mfma_f32_16x16x32_bf16(a11, Bf[n][1], acc[(Q)*2 + 1][n], 0, 0, 0); \
        }                                                                             \
        __builtin_amdgcn_s_setprio(0);                                                \
        __builtin_amdgcn_s_barrier();                                                 \
    }

    // prologue: tile0 all 8 units, then tile1 B0..B3,A0,A2 (6 units).
    // vmcnt(6) -> tile0's 8 loads complete, tile1's 6 in flight.
    SB(0, 0, 0); SB(0, 1, 0); SB(0, 2, 0); SB(0, 3, 0);
    SA(0, 0, 0); SA(0, 2, 0); SA(0, 1, 0); SA(0, 3, 0);
    SB(1, 0, 1); SB(1, 1, 1); SB(1, 2, 1); SB(1, 3, 1);
    SA(1, 0, 1); SA(1, 2, 1);
    asm volatile("s_waitcnt vmcnt(6)" ::: "memory");
    __builtin_amdgcn_s_barrier();

    #pragma unroll
    for (int i = 0; i < 4; ++i) {                 // 2 K-tiles / iteration
        const bool more = (i < 3);
        const int t1 = 2 * i + 1, t2 = 2 * i + 2, t3 = 2 * i + 3;
        // p1: q0 of buf0; read all B(buf0); stage buf1 A1,A3 (tile t1)
        PH(0, 0, { DSB(0); SA(1, 1, t1); SA(1, 3, t1); }, )
        // p2: q1 buf0; stage buf0 B0,B1 (t2)   [B(buf0) dead after p1]
        PH(0, 1, { if (more) { SB(0, 0, t2); SB(0, 1, t2); } }, )
        // p3: q2 buf0; stage buf0 B2,B3 (t2)
        PH(0, 2, { if (more) { SB(0, 2, t2); SB(0, 3, t2); } }, )
        // p4: q3 buf0; stage buf0 A0,A2 (t2)  [q0/q1 rows dead after p2]
        PH(0, 3, { if (more) { SA(0, 0, t2); SA(0, 2, t2); } },
           if (more) { asm volatile("s_waitcnt vmcnt(6)" ::: "memory"); }
           else      { asm volatile("s_waitcnt vmcnt(0)" ::: "memory"); } )
        // p5: q0 buf1; read all B(buf1); stage buf0 A1,A3 (t2)
        PH(1, 0, { DSB(1); if (more) { SA(0, 1, t2); SA(0, 3, t2); } }, )
        // p6: q1 buf1; stage buf1 B0,B1 (t3)
        PH(1, 1, { if (more) { SB(1, 0, t3); SB(1, 1, t3); } }, )
        // p7: q2 buf1; stage buf1 B2,B3 (t3)
        PH(1, 2, { if (more) { SB(1, 2, t3); SB(1, 3, t3); } }, )
        // p8: q3 buf1; stage buf1 A0,A2 (t3); vmcnt(6) -> t2 fully landed
        PH(1, 3, { if (more) { SA(1, 0, t3); SA(1, 2, t3); } },
           if (more) { asm volatile("s_waitcnt vmcnt(6)" ::: "memory"); } )
    }
#undef PH
#undef DSB

    #pragma unroll
    for (int n = 0; n < 4; ++n) {
        const int nn = n0 + wn * 64 + n * 16 + lr;
        const float bias = (nn < Nreal) ? (b1[nn] + (b2 ? b2[nn] : 0.f)) : 0.f;
        #pragma unroll
        for (int m = 0; m < 8; ++m) {
            #pragma unroll
            for (int r = 0; r < 4; ++r) {
                const int mm = m0 + wm * 128 + m * 16 + quad * 4 + r;
                float v = acc[m][n][r] + bias;
                if (TANH) v = tanhf(v);
                Cg[(size_t)mm * Npad + nn] = f2bf(v);
            }
        }
    }
}

// fp32 -> bf16, 8 elems/thread (n must be multiple of 2048)
__global__ void cvt8(const float* __restrict__ src, unsigned short* __restrict__ dst)
{
    const size_t i = ((size_t)blockIdx.x * 256 + threadIdx.x) * 8;
    float4 f0 = *(const float4*)(src + i);
    float4 f1 = *(const float4*)(src + i + 4);
    unsigned short t8[8];
    t8[0]=f2bf(f0.x); t8[1]=f2bf(f0.y); t8[2]=f2bf(f0.z); t8[3]=f2bf(f0.w);
    t8[4]=f2bf(f1.x); t8[5]=f2bf(f1.y); t8[6]=f2bf(f1.z); t8[7]=f2bf(f1.w);
    *(v8s*)(dst + i) = *(const v8s*)t8;
}

// Wa2 (1000x512 fp32) -> zero-padded 1024x512 bf16
__global__ void wa2pad(const float* __restrict__ src, unsigned short* __restrict__ dst)
{
    const int i = blockIdx.x * 256 + threadIdx.x;
    const int row = i >> 9;
    dst[i] = (row < 1000) ? f2bf(src[(size_t)row * 512 + (i & 511)]) : (unsigned short)0;
}

// masked initial state (bf16) + zero row buffer
__global__ void init_state(const float* __restrict__ h0, const float* __restrict__ c0,
                           const int* __restrict__ done,
                           unsigned short* __restrict__ h_init, unsigned short* __restrict__ c_init,
                           unsigned short* __restrict__ zbuf)
{
    const int b = blockIdx.x;
    const float m = 1.f - (float)done[b];
    for (int k = threadIdx.x; k < 512; k += 256) {
        h_init[(size_t)b * 512 + k] = f2bf(h0[(size_t)b * 512 + k] * m);
        c_init[(size_t)b * 512 + k] = f2bf(c0[(size_t)b * 512 + k] * m);
        if (b == 0) zbuf[k] = 0;
    }
}

// ---------------------------------------------------------------------------
// Segment prep (single WG): one global walk of done (bits cached in LDS),
// per-round row lists for s<12, level-grouped tail list for s>=12,
// maxS, and barrier-counter reset for lstm_tail.
// ---------------------------------------------------------------------------
__global__ __launch_bounds__(256, 1)
void seg_prep(const int* __restrict__ done, int* __restrict__ rows,
              int* __restrict__ counts, int* __restrict__ offs,
              int* __restrict__ trows, int* __restrict__ tcnt, int* __restrict__ toffs,
              int* __restrict__ maxS, int* __restrict__ bar, int T)
{
    __shared__ unsigned int   bits[256][8];
    __shared__ unsigned short cnt[256][S0R];
    __shared__ unsigned short base[256][S0R];
    __shared__ int tot[S0R];
    __shared__ int goff[S0R];
    __shared__ int tcl[NLEV];
    __shared__ int tol[NLEV];
    __shared__ int tpos[NLEV];
    __shared__ int mxl[256];
    const int b = threadIdx.x;
    #pragma unroll
    for (int s = 0; s < S0R; ++s) cnt[b][s] = 0;
    #pragma unroll
    for (int i = 0; i < 8; ++i) bits[b][i] = 0;
    for (int l = b; l < NLEV; l += 256) { tcl[l] = 0; tpos[l] = 0; }
    __syncthreads();

    int s = 0, mx = 0;
    for (int t = 0; t < T; ++t) {
        int d = done[t * 256 + b];
        if (d) bits[b][t >> 5] |= (1u << (t & 31));
        s = (t == 0 || d) ? 0 : s + 1;
        if (s < S0R) cnt[b][s]++;
        else atomicAdd(&tcl[s - S0R], 1);
        mx = mx > s ? mx : s;
    }
    mxl[b] = mx;
    __syncthreads();

    if (b < S0R) {
        int tsum = 0;
        for (int bb = 0; bb < 256; ++bb) { base[bb][b] = (unsigned short)tsum; tsum += cnt[bb][b]; }
        tot[b] = tsum;
    }
    __syncthreads();
    if (b == 0) {
        int run = 0;
        for (int ss = 0; ss < S0R; ++ss) { goff[ss] = run; run += tot[ss]; }
        run = 0;
        for (int l = 0; l < NLEV; ++l) { tol[l] = run; run += tcl[l]; }
        int m = 0;
        for (int bb = 0; bb < 256; ++bb) m = m > mxl[bb] ? m : mxl[bb];
        *maxS = m;
        *bar  = 0;
    }
    __syncthreads();
    if (b < S0R) { counts[b] = tot[b]; offs[b] = goff[b]; }
    for (int l = b; l < NLEV; l += 256) { tcnt[l] = tcl[l]; toffs[l] = tol[l]; }

    s = 0;
    for (int t = 0; t < T; ++t) {
        int d = (bits[b][t >> 5] >> (t & 31)) & 1;
        s = (t == 0 || d) ? 0 : s + 1;
        if (s < S0R) {
            int idx = goff[s] + (int)base[b][s];
            base[b][s]++;
            rows[idx] = t * 256 + b;
        } else {
            int idx = tol[s - S0R] + atomicAdd(&tpos[s - S0R], 1);
            trows[idx] = t * 256 + b;
        }
    }
}

// ---------------------------------------------------------------------------
// Fused LSTM round (s < 12): 128 gathered rows x (4 gates x 32 hidden cols),
// async-staged A/B, LDS gate exchange, fused cell update.
// ---------------------------------------------------------------------------
__global__ __launch_bounds__(256)
void lstm_round(const int* __restrict__ rows, const int* __restrict__ counts,
                const int* __restrict__ offs, int s,
                const unsigned short* __restrict__ XG,
                const unsigned short* __restrict__ Whb,
                const unsigned short* __restrict__ h_init,
                const unsigned short* __restrict__ c_init,
                const unsigned short* __restrict__ zbuf,
                unsigned short* __restrict__ Hraw, unsigned short* __restrict__ Cst)
{
    const int M = counts[s];
    if (M == 0) return;
    const int off    = offs[s];
    const int mtiles = (M + 127) >> 7;

    __shared__ __align__(16) unsigned short As[128 * 32];
    __shared__ __align__(16) unsigned short Bs[128 * 32];
    __shared__ __align__(16) unsigned short Gx[128 * 136];
    __shared__ int rl[128];

    const int tid  = threadIdx.x;
    const int w    = tid >> 6;
    const int lane = tid & 63;
    const int quad = lane >> 4;
    const int lr   = lane & 15;
    const int wm   = w & 1, wn = w >> 1;
    const int c0   = blockIdx.x * 32;
    const int srow = lane >> 2;
    const int kblk = (lane & 3) ^ ((lane >> 3) & 3);

    const int br0 = w * 16 + srow;
    const int br1 = 64 + br0;
    const unsigned short* gB0 = Whb + (size_t)((br0 >> 5) * 512 + c0 + (br0 & 31)) * 512 + kblk * 8;
    const unsigned short* gB1 = Whb + (size_t)((br1 >> 5) * 512 + c0 + (br1 & 31)) * 512 + kblk * 8;
    unsigned short* lA0 = As + (w * 16) * 32;
    unsigned short* lA1 = As + (64 + w * 16) * 32;
    unsigned short* lB0 = Bs + (w * 16) * 32;
    unsigned short* lB1 = Bs + (64 + w * 16) * 32;

    const int swz = (quad ^ ((lr >> 1) & 3)) * 8;
    int aoff[4], boff[4];
    #pragma unroll
    for (int i = 0; i < 4; ++i) {
        aoff[i] = (wm * 64 + i * 16 + lr) * 32 + swz;
        boff[i] = (wn * 64 + i * 16 + lr) * 32 + swz;
    }

    for (int mt = blockIdx.y; mt < mtiles; mt += gridDim.y) {
        __syncthreads();
        if (tid < 128) {
            int li = mt * 128 + tid;
            rl[tid] = (li < M) ? rows[off + li] : -1;
        }
        __syncthreads();

        int g0r = rl[w * 16 + srow];
        int g1r = rl[64 + w * 16 + srow];
        const unsigned short* gA0;
        const unsigned short* gA1;
        if (s == 0) {
            gA0 = (g0r >= 0 && g0r < 256) ? h_init + (size_t)g0r * 512 + kblk * 8 : zbuf + kblk * 8;
            gA1 = (g1r >= 0 && g1r < 256) ? h_init + (size_t)g1r * 512 + kblk * 8 : zbuf + kblk * 8;
        } else {
            gA0 = (g0r >= 0) ? Hraw + (size_t)(g0r - 256) * 512 + kblk * 8 : zbuf + kblk * 8;
            gA1 = (g1r >= 0) ? Hraw + (size_t)(g1r - 256) * 512 + kblk * 8 : zbuf + kblk * 8;
        }

        v4f zz = {0.f, 0.f, 0.f, 0.f};
        v4f acc[4][4] = {{zz,zz,zz,zz},{zz,zz,zz,zz},{zz,zz,zz,zz},{zz,zz,zz,zz}};

        for (int k = 0; k < 16; ++k) {
            __syncthreads();
            gld_lds16(gA0 + k * 32, lA0);
            gld_lds16(gA1 + k * 32, lA1);
            gld_lds16(gB0 + k * 32, lB0);
            gld_lds16(gB1 + k * 32, lB1);
            __syncthreads();
            v8s a[4], b[4];
            #pragma unroll
            for (int i = 0; i < 4; ++i) { a[i] = *(const v8s*)&As[aoff[i]]; b[i] = *(const v8s*)&Bs[boff[i]]; }
            #pragma unroll
            for (int i = 0; i < 4; ++i)
                #pragma unroll
                for (int j = 0; j < 4; ++j)
                    acc[i][j] = __builtin_amdgcn_mfma_f32_16x16x32_bf16(a[i], b[j], acc[i][j], 0, 0, 0);
        }

        #pragma unroll
        for (int j = 0; j < 4; ++j) {
            const int nl = wn * 64 + j * 16 + lr;
            #pragma unroll
            for (int i = 0; i < 4; ++i)
                #pragma unroll
                for (int r = 0; r < 4; ++r)
                    Gx[(wm * 64 + i * 16 + quad * 4 + r) * 136 + nl] = f2bf(acc[i][j][r]);
        }
        __syncthreads();

        {
            const int rloc = tid >> 1;
            const int half = tid & 1;
            const int gr   = rl[rloc];
            if (gr >= 0) {
                #pragma unroll
                for (int ch = 0; ch < 2; ++ch) {
                    const int co = half * 16 + ch * 8;
                    const int kg = c0 + co;
                    v8s q0 = *(const v8s*)&Gx[rloc * 136 +   0 + co];
                    v8s q1 = *(const v8s*)&Gx[rloc * 136 +  32 + co];
                    v8s q2 = *(const v8s*)&Gx[rloc * 136 +  64 + co];
                    v8s q3 = *(const v8s*)&Gx[rloc * 136 +  96 + co];
                    const size_t xb = (size_t)gr * 2048 + kg;
                    v8s x0 = *(const v8s*)&XG[xb];
                    v8s x1 = *(const v8s*)&XG[xb + 512];
                    v8s x2 = *(const v8s*)&XG[xb + 1024];
                    v8s x3 = *(const v8s*)&XG[xb + 1536];
                    float cprev[8];
                    if (s == 0) {
                        if (gr < 256) {
                            v8s cv = *(const v8s*)&c_init[(size_t)gr * 512 + kg];
                            #pragma unroll
                            for (int e = 0; e < 8; ++e) cprev[e] = bf2f((unsigned short)cv[e]);
                        } else {
                            #pragma unroll
                            for (int e = 0; e < 8; ++e) cprev[e] = 0.f;
                        }
                    } else {
                        v8s cv = *(const v8s*)&Cst[(size_t)(gr - 256) * 512 + kg];
                        #pragma unroll
                        for (int e = 0; e < 8; ++e) cprev[e] = bf2f((unsigned short)cv[e]);
                    }
                    unsigned short hc[8], cc[8];
                    #pragma unroll
                    for (int e = 0; e < 8; ++e) {
                        float gi = bf2f((unsigned short)q0[e]) + bf2f((unsigned short)x0[e]);
                        float gf = bf2f((unsigned short)q1[e]) + bf2f((unsigned short)x1[e]);
                        float gg = bf2f((unsigned short)q2[e]) + bf2f((unsigned short)x2[e]);
                        float go = bf2f((unsigned short)q3[e]) + bf2f((unsigned short)x3[e]);
                        float c  = sigmoidf_(gf) * cprev[e] + sigmoidf_(gi) * tanhf(gg);
                        float h  = sigmoidf_(go) * tanhf(c);
                        cc[e] = f2bf(c);
                        hc[e] = f2bf(h);
                    }
                    *(v8s*)&Cst[(size_t)gr * 512 + kg]  = *(const v8s*)cc;
                    *(v8s*)&Hraw[(size_t)gr * 512 + kg] = *(const v8s*)hc;
                }
            }
        }
    }
}

// ---------------------------------------------------------------------------
// Tail (s >= 12): 64 WGs, each holds its 32-row Whh slice (8 hidden cols x
// 4 gates) resident in LDS; levels processed with a device-scope spin barrier
// between them (64 blocks <= 256 CUs, stream-serialized => co-resident;
// monotone arrival counter => no deadlock; seg_prep resets it every call).
// ---------------------------------------------------------------------------
__global__ __launch_bounds__(256, 1)
void lstm_tail(const int* __restrict__ trows, const int* __restrict__ tcnt,
               const int* __restrict__ toffs, const int* __restrict__ maxS_p,
               const unsigned short* __restrict__ XG,
               const unsigned short* __restrict__ Whb,
               unsigned short* __restrict__ Hraw, unsigned short* __restrict__ Cst,
               int* __restrict__ bar)
{
    const int mS = *maxS_p;
    if (mS < S0R) return;
    __shared__ __align__(16) unsigned short Wl[32 * 512];   // 32 KB
    __shared__ __align__(16) unsigned short Hb[16 * 512];   // 16 KB
    __shared__ float Gb[16 * 32];
    __shared__ int rl[16];
    const int j    = blockIdx.x;          // hidden-col slice: cols j*8 .. j*8+8
    const int tid  = threadIdx.x;
    const int w    = tid >> 6;
    const int lane = tid & 63;
    const int quad = lane >> 4;
    const int lr   = lane & 15;

    // resident Whh slice: Wl row n = g*8+c  <-  Whh row g*512 + j*8 + c
    for (int e = tid; e < 32 * 64; e += 256) {
        int n = e >> 6, kb = e & 63;
        int g = n >> 3, c = n & 7;
        *(v8s*)&Wl[n * 512 + kb * 8] = *(const v8s*)&Whb[(size_t)(g * 512 + j * 8 + c) * 512 + kb * 8];
    }

    int target = 0;
    for (int s = S0R; s <= mS; ++s) {
        const int lev = s - S0R;
        const int M   = tcnt[lev];
        const int off = toffs[lev];
        for (int ch = 0; ch < M; ch += 16) {
            __syncthreads();
            if (tid < 16) rl[tid] = (ch + tid < M) ? trows[off + ch + tid] : -1;
            __syncthreads();
            {   // stage h_prev rows (s>=12 => prev always in Hraw)
                int r = tid >> 4, seg = (tid & 15) * 32;
                int gr = rl[r];
                if (gr >= 0) {
                    const unsigned short* src = &Hraw[(size_t)(gr - 256) * 512 + seg];
                    *(v8s*)&Hb[r * 512 + seg]      = *(const v8s*)(src);
                    *(v8s*)&Hb[r * 512 + seg + 8]  = *(const v8s*)(src + 8);
                    *(v8s*)&Hb[r * 512 + seg + 16] = *(const v8s*)(src + 16);
                    *(v8s*)&Hb[r * 512 + seg + 24] = *(const v8s*)(src + 24);
                } else {
                    v8s z = {0,0,0,0,0,0,0,0};
                    *(v8s*)&Hb[r * 512 + seg]      = z;
                    *(v8s*)&Hb[r * 512 + seg + 8]  = z;
                    *(v8s*)&Hb[r * 512 + seg + 16] = z;
                    *(v8s*)&Hb[r * 512 + seg + 24] = z;
                }
            }
            __syncthreads();
            if (w < 2) {      // wave w computes output tile n = w*16 .. w*16+16
                v4f acc = {0.f, 0.f, 0.f, 0.f};
                for (int k = 0; k < 16; ++k) {
                    v8s a = *(const v8s*)&Hb[lr * 512 + k * 32 + quad * 8];
                    v8s b = *(const v8s*)&Wl[(w * 16 + lr) * 512 + k * 32 + quad * 8];
                    acc = __builtin_amdgcn_mfma_f32_16x16x32_bf16(a, b, acc, 0, 0, 0);
                }
                #pragma unroll
                for (int r = 0; r < 4; ++r)
                    Gb[(quad * 4 + r) * 32 + w * 16 + lr] = acc[r];
            }
            __syncthreads();
            if (tid < 128) {
                int r = tid >> 3, c = tid & 7;
                int gr = rl[r];
                if (gr >= 0) {
                    int k = j * 8 + c;
                    const size_t xb = (size_t)gr * 2048 + k;
                    float gi = Gb[r * 32 +  0 + c] + bf2f(XG[xb]);
                    float gf = Gb[r * 32 +  8 + c] + bf2f(XG[xb + 512]);
                    float gg = Gb[r * 32 + 16 + c] + bf2f(XG[xb + 1024]);
                    float go = Gb[r * 32 + 24 + c] + bf2f(XG[xb + 1536]);
                    float cp = bf2f(Cst[(size_t)(gr - 256) * 512 + k]);
                    float cc = sigmoidf_(gf) * cp + sigmoidf_(gi) * tanhf(gg);
                    float hh = sigmoidf_(go) * tanhf(cc);
                    Cst[(size_t)gr * 512 + k]  = f2bf(cc);
                    Hraw[(size_t)gr * 512 + k] = f2bf(hh);
                }
            }
        }
        // inter-level device barrier
        target += 64;
        __threadfence();
        __syncthreads();
        if (tid == 0) {
            __hip_atomic_fetch_add(bar, 1, __ATOMIC_RELEASE, __HIP_MEMORY_SCOPE_AGENT);
            while (__hip_atomic_load(bar, __ATOMIC_ACQUIRE, __HIP_MEMORY_SCOPE_AGENT) < target) {}
        }
        __syncthreads();
        __threadfence();
    }
}

// Hraw += H2 in place (-> new_hidden), 8 elems/thread
__global__ void nh_add(unsigned short* __restrict__ H, const unsigned short* __restrict__ H2)
{
    const size_t i = ((size_t)blockIdx.x * 256 + threadIdx.x) * 8;
    v8s a = *(const v8s*)(H + i);
    v8s b = *(const v8s*)(H2 + i);
    unsigned short t8[8];
    #pragma unroll
    for (int e = 0; e < 8; ++e)
        t8[e] = f2bf(bf2f((unsigned short)a[e]) + bf2f((unsigned short)b[e]));
    *(v8s*)(H + i) = *(const v8s*)t8;
}

// actor head: one wave per row over bf16 logits (stride 1024, 1000 valid)
__global__ void head_reduce(const unsigned short* __restrict__ logits,
                            const int* __restrict__ action,
                            float* __restrict__ out, int TB)
{
    const int r = blockIdx.x * 4 + (threadIdx.x >> 6);
    const int lane = threadIdx.x & 63;
    const unsigned short* row = logits + (size_t)r * 1024;
    float m = -1e30f, Z = 0.f, S = 0.f;
    v8s v0 = *(const v8s*)&row[lane * 8];
    #pragma unroll
    for (int e = 0; e < 8; ++e) {
        float xv = bf2f((unsigned short)v0[e]);
        if (xv > m) { float sc = expf(m - xv); Z *= sc; S *= sc; m = xv; }
        float ev = expf(xv - m);
        Z += ev; S += xv * ev;
    }
    v8s v1 = *(const v8s*)&row[512 + lane * 8];
    #pragma unroll
    for (int e = 0; e < 8; ++e) {
        int c = 512 + lane * 8 + e;
        if (c < 1000) {
            float xv = bf2f((unsigned short)v1[e]);
            if (xv > m) { float sc = expf(m - xv); Z *= sc; S *= sc; m = xv; }
            float ev = expf(xv - m);
            Z += ev; S += xv * ev;
        }
    }
    #pragma unroll
    for (int offb = 32; offb > 0; offb >>= 1) {
        float m2 = __shfl_xor(m, offb);
        float Z2 = __shfl_xor(Z, offb);
        float S2 = __shfl_xor(S, offb);
        float M  = fmaxf(m, m2);
        float s1 = expf(m - M), s2 = expf(m2 - M);
        Z = Z * s1 + Z2 * s2;
        S = S * s1 + S2 * s2;
        m = M;
    }
    if (lane == 0) {
        float lse = m + logf(Z);
        float xa  = bf2f(row[action[r]]);
        out[r]      = xa - lse;
        out[TB + r] = lse - S / Z;
    }
}

__global__ void critic_v(const unsigned short* __restrict__ C1, const float* __restrict__ Wc2,
                         const float* __restrict__ bc2, float* __restrict__ out, int TB)
{
    const int r = blockIdx.x * 4 + (threadIdx.x >> 6);
    const int lane = threadIdx.x & 63;
    const unsigned short* row = C1 + (size_t)r * 512;
    v8s hv = *(const v8s*)&row[lane * 8];
    float4 w0 = *(const float4*)&Wc2[lane * 8];
    float4 w1 = *(const float4*)&Wc2[lane * 8 + 4];
    float s = bf2f((unsigned short)hv[0]) * w0.x + bf2f((unsigned short)hv[1]) * w0.y +
              bf2f((unsigned short)hv[2]) * w0.z + bf2f((unsigned short)hv[3]) * w0.w +
              bf2f((unsigned short)hv[4]) * w1.x + bf2f((unsigned short)hv[5]) * w1.y +
              bf2f((unsigned short)hv[6]) * w1.z + bf2f((unsigned short)hv[7]) * w1.w;
    #pragma unroll
    for (int offb = 32; offb > 0; offb >>= 1) s += __shfl_xor(s, offb);
    if (lane == 0) out[2 * TB + r] = s + bc2[0];
}

extern "C" void kernel_launch(void* const* d_in, const int* in_sizes, int n_in,
                              void* d_out, int out_size, void* d_ws, size_t ws_size,
                              hipStream_t stream)
{
    const float* x    = (const float*)d_in[0];
    const int*  done  = (const int*)d_in[1];
    const int*  action= (const int*)d_in[2];
    const float* W_t1 = (const float*)d_in[4];
    const float* b_t1 = (const float*)d_in[5];
    const float* W_t2 = (const float*)d_in[6];
    const float* b_t2 = (const float*)d_in[7];
    const float* Wih  = (const float*)d_in[8];
    const float* Whh  = (const float*)d_in[9];
    const float* bih  = (const float*)d_in[10];
    const float* bhh  = (const float*)d_in[11];
    const float* Wa1  = (const float*)d_in[12];
    const float* ba1  = (const float*)d_in[13];
    const float* Wa2  = (const float*)d_in[14];
    const float* ba2  = (const float*)d_in[15];
    const float* Wc1  = (const float*)d_in[16];
    const float* bc1  = (const float*)d_in[17];
    const float* Wc2  = (const float*)d_in[18];
    const float* bc2  = (const float*)d_in[19];
    const float* h0   = (const float*)d_in[20];
    const float* c0   = (const float*)d_in[21];
    float* out = (float*)d_out;

    const int TB = in_sizes[1];      // 65536
    const int T  = TB / 256;         // 256

    const size_t MiB = 1024 * 1024;
    char* ws = (char*)d_ws;
    unsigned short* XG     = (unsigned short*)(ws);
    unsigned short* H1     = (unsigned short*)(ws);
    unsigned short* logits = (unsigned short*)(ws);
    unsigned short* A1     = (unsigned short*)(ws + 136 * MiB);
    unsigned short* C1     = A1;
    unsigned short* Cst    = (unsigned short*)(ws + 256 * MiB);
    unsigned short* H2     = (unsigned short*)(ws + 320 * MiB);
    unsigned short* Hraw   = (unsigned short*)(ws + 384 * MiB);
    unsigned short* xbf    = Hraw;
    unsigned short* Wt1b   = (unsigned short*)(ws + 448 * MiB);
    unsigned short* Wt2b   = Wt1b + 512 * 512;
    unsigned short* Wihb   = Wt2b + 512 * 512;
    unsigned short* Whhb   = Wihb + 2048 * 512;
    unsigned short* Wa1b   = Whhb + 2048 * 512;
    unsigned short* Wc1b   = Wa1b + 512 * 512;
    unsigned short* Wa2b   = Wc1b + 512 * 512;
    unsigned short* h_init = Wa2b + 1024 * 512;
    unsigned short* c_init = h_init + 256 * 512;
    unsigned short* zbuf   = c_init + 256 * 512;
    int* rows   = (int*)(zbuf + 512);
    int* trows  = rows + 65536;
    int* counts = trows + 65536;
    int* offs   = counts + S0R;
    int* tcnt   = offs + S0R;
    int* toffs  = tcnt + NLEV;
    int* maxS   = toffs + NLEV;
    int* bar    = maxS + 1;

    dim3 blk(256);
    dim3 blk5(512);

    // dtype conversions (weights + x), init, segment lists
    cvt8<<<16384, blk, 0, stream>>>(x, xbf);
    cvt8<<<128,  blk, 0, stream>>>(W_t1, Wt1b);
    cvt8<<<128,  blk, 0, stream>>>(W_t2, Wt2b);
    cvt8<<<512,  blk, 0, stream>>>(Wih,  Wihb);
    cvt8<<<512,  blk, 0, stream>>>(Whh,  Whhb);
    cvt8<<<128,  blk, 0, stream>>>(Wa1,  Wa1b);
    cvt8<<<128,  blk, 0, stream>>>(Wc1,  Wc1b);
    wa2pad<<<2048, blk, 0, stream>>>(Wa2, Wa2b);
    init_state<<<256, blk, 0, stream>>>(h0, c0, done, h_init, c_init, zbuf);
    seg_prep<<<1, blk, 0, stream>>>(done, rows, counts, offs, trows, tcnt, toffs, maxS, bar, T);

    // trunk + hoisted x-side gates (256x256-tile 8-phase GEMM)
    gemm256<true ><<<512,  blk5, 0, stream>>>(xbf, Wt1b, b_t1, nullptr, H1, 512, 512, 2);
    gemm256<true ><<<512,  blk5, 0, stream>>>(H1,  Wt2b, b_t2, nullptr, H2, 512, 512, 2);
    gemm256<false><<<2048, blk5, 0, stream>>>(H2,  Wihb, bih,  bhh,    XG, 2048, 2048, 8);

    // segment-parallel LSTM: 12 gather-GEMM rounds + resident-weight tail
    static const int Gs[S0R] = {256, 128, 64, 32, 16, 8, 4, 2, 1, 1, 1, 1};
    for (int s = 0; s < S0R; ++s)
        lstm_round<<<dim3(16, Gs[s]), blk, 0, stream>>>(rows, counts, offs, s, XG, Whhb,
                                                        h_init, c_init, zbuf, Hraw, Cst);
    lstm_tail<<<64, blk, 0, stream>>>(trows, tcnt, toffs, maxS, XG, Whhb, Hraw, Cst, bar);

    // residual: Hraw <- Hraw + H2 (= new_hidden)
    nh_add<<<16384, blk, 0, stream>>>(Hraw, H2);

    // actor head
    gemm256<true ><<<512,  blk5, 0, stream>>>(Hraw, Wa1b, ba1, nullptr, A1, 512, 512, 2);
    gemm256<false><<<1024, blk5, 0, stream>>>(A1, Wa2b, ba2, nullptr, logits, 1000, 1024, 4);
    head_reduce<<<TB / 4, blk, 0, stream>>>(logits, action, out, TB);

    // critic head
    gemm256<true ><<<512, blk5, 0, stream>>>(Hraw, Wc1b, bc1, nullptr, C1, 512, 512, 2);
    critic_v<<<TB / 4, blk, 0, stream>>>(C1, Wc2, bc2, out, TB);
}

// Round 2
// 1673.341 us; speedup vs baseline: 1.1257x; 1.1257x over previous
//
#include <hip/hip_runtime.h>
#include <hip/hip_bf16.h>

typedef short v8s __attribute__((ext_vector_type(8)));
typedef float v4f __attribute__((ext_vector_type(4)));

#define S0R 12      // rounds 0..11 via gather-GEMM; lstm_tail covers s >= 12
#define NLEV 244    // tail levels 12..255

__device__ __forceinline__ float bf2f(unsigned short u) {
    union { unsigned int i; float f; } v; v.i = ((unsigned int)u) << 16; return v.f;
}
__device__ __forceinline__ unsigned short f2bf(float f) {
    union { float f; unsigned int i; } v; v.f = f;
    unsigned int x = v.i;
    return (unsigned short)((x + 0x7fffu + ((x >> 16) & 1u)) >> 16);
}
__device__ __forceinline__ float sigmoidf_(float x) { return 1.0f / (1.0f + expf(-x)); }

// async global->LDS, 16B per lane; LDS dst is wave-uniform base + lane*16
__device__ __forceinline__ void gld_lds16(const unsigned short* g, unsigned short* l) {
    __builtin_amdgcn_global_load_lds(
        (const __attribute__((address_space(1))) unsigned int*)g,
        (__attribute__((address_space(3))) unsigned int*)l, 16, 0, 0);
}

// ---------------------------------------------------------------------------
// gemm256: C[M,Npad] = act(A[M,512] @ W[Npad,512]^T + b1 (+b2)), bf16.
// 256x256 tile, BK=64, 8 waves (2Mx4N), 8-phase schedule with counted vmcnt
// (T3+T4), XOR-swizzled LDS reads (T2), setprio around MFMA (T5), XCD-chunked
// block swizzle (T1).  K fixed at 512 (8 K-tiles, 4 iterations).
//
// Epilogue: acc -> LDS (As/Bs reused, XOR-granule swizzle) -> 16B/lane
// coalesced global stores.  Direct scalar stores caused 2.1x HBM write
// amplification (partial 32B segments evicted before line merge) + 16k cyc
// of store-issue per block (round-1 counters: WRITE_SIZE 573MB vs 268MB
// logical).
// ---------------------------------------------------------------------------
template <bool TANH>
__global__ __launch_bounds__(512, 2)
void gemm256(const unsigned short* __restrict__ Ag, const unsigned short* __restrict__ Wg,
             const float* __restrict__ b1, const float* __restrict__ b2,
             unsigned short* __restrict__ Cg, int Nreal, int Npad, int Ntiles)
{
    __shared__ __align__(16) unsigned short As[2][256 * 64];   // 64 KB
    __shared__ __align__(16) unsigned short Bs[2][256 * 64];   // 64 KB

    const int tid  = threadIdx.x;
    const int w    = tid >> 6;          // 0..7
    const int lane = tid & 63;
    const int quad = lane >> 4;
    const int lr   = lane & 15;
    const int wm   = w >> 2;            // 0..1
    const int wn   = w & 3;             // 0..3

    // T1: XCD-chunked swizzle (all grids are multiples of 8)
    const int nwg = gridDim.x;
    const int cpx = nwg >> 3;
    const int swz = (blockIdx.x & 7) * cpx + (blockIdx.x >> 3);
    const int m0  = (swz / Ntiles) * 256;
    const int n0  = (swz % Ntiles) * 256;

    const unsigned short* gA = Ag + (size_t)m0 * 512;
    const unsigned short* gB = Wg + (size_t)n0 * 512;

    // staging map: one 64-row unit per gld_lds; wave w covers rows w*8..w*8+8
    // of the unit; source k-granule pre-swizzled so linear LDS dest + swizzled
    // read form a consistent involution (T2, key = row&7).
    const int sr  = w * 8 + (lane >> 3);
    const int skg = (lane & 7) ^ ((lane >> 3) & 7);

    auto SA = [&](int buf, int u, int kt) {
        gld_lds16(gA + (size_t)(u * 64 + sr) * 512 + kt * 64 + skg * 8,
                  &As[buf][(u * 64 + w * 8) * 64]);
    };
    auto SB = [&](int buf, int u, int kt) {
        gld_lds16(gB + (size_t)(u * 64 + sr) * 512 + kt * 64 + skg * 8,
                  &Bs[buf][(u * 64 + w * 8) * 64]);
    };

    // read-side swizzled granule offsets (row&7 == lr&7 since frag rows are
    // 16-aligned + lr)
    const int g8_0  = (quad ^ (lr & 7)) * 8;          // ks=0: kg = quad
    const int g8_1  = ((quad + 4) ^ (lr & 7)) * 8;    // ks=1: kg = 4+quad
    const int aBase = (wm * 128 + lr) * 64;
    const int bBase = (wn * 64 + lr) * 64;

    v4f zz = {0.f, 0.f, 0.f, 0.f};
    v4f acc[8][4];
    #pragma unroll
    for (int m = 0; m < 8; ++m)
        #pragma unroll
        for (int n = 0; n < 4; ++n) acc[m][n] = zz;
    v8s Bf[4][2];

#define DSB(BUF)                                                         \
    _Pragma("unroll")                                                    \
    for (int n = 0; n < 4; ++n) {                                        \
        Bf[n][0] = *(const v8s*)&Bs[BUF][bBase + n * 1024 + g8_0];       \
        Bf[n][1] = *(const v8s*)&Bs[BUF][bBase + n * 1024 + g8_1];       \
    }

#define PH(BUF, Q, STMTS, PREBAR)                                                     \
    {                                                                                 \
        const v8s a00 = *(const v8s*)&As[BUF][aBase + ((Q)*2 + 0) * 1024 + g8_0];     \
        const v8s a01 = *(const v8s*)&As[BUF][aBase + ((Q)*2 + 0) * 1024 + g8_1];     \
        const v8s a10 = *(const v8s*)&As[BUF][aBase + ((Q)*2 + 1) * 1024 + g8_0];     \
        const v8s a11 = *(const v8s*)&As[BUF][aBase + ((Q)*2 + 1) * 1024 + g8_1];     \
        STMTS;                                                                        \
        PREBAR;                                                                       \
        __builtin_amdgcn_s_barrier();                                                 \
        asm volatile("s_waitcnt lgkmcnt(0)" ::: "memory");                            \
        __builtin_amdgcn_sched_barrier(0);                                            \
        __builtin_amdgcn_s_setprio(1);                                                \
        _Pragma("unroll")                                                             \
        for (int n = 0; n < 4; ++n) {                                                 \
            acc[(Q)*2    ][n] = __builtin_amdgcn_mfma_f32_16x16x32_bf16(a00, Bf[n][0], acc[(Q)*2    ][n], 0, 0, 0); \
            acc[(Q)*2    ][n] = __builtin_amdgcn_mfma_f32_16x16x32_bf16(a01, Bf[n][1], acc[(Q)*2    ][n], 0, 0, 0); \
            acc[(Q)*2 + 1][n] = __builtin_amdgcn_mfma_f32_16x16x32_bf16(a10, Bf[n][0], acc[(Q)*2 + 1][n], 0, 0, 0); \
            acc[(Q)*2 + 1][n] = __builtin_amdgcn_mfma_f32_16x16x32_bf16(a11, Bf[n][1], acc[(Q)*2 + 1][n], 0, 0, 0); \
        }                                                                             \
        __builtin_amdgcn_s_setprio(0);                                                \
        __builtin_amdgcn_s_barrier();                                                 \
    }

    // prologue: tile0 all 8 units, then tile1 B0..B3,A0,A2 (6 units).
    // vmcnt(6) -> tile0's 8 loads complete, tile1's 6 in flight.
    SB(0, 0, 0); SB(0, 1, 0); SB(0, 2, 0); SB(0, 3, 0);
    SA(0, 0, 0); SA(0, 2, 0); SA(0, 1, 0); SA(0, 3, 0);
    SB(1, 0, 1); SB(1, 1, 1); SB(1, 2, 1); SB(1, 3, 1);
    SA(1, 0, 1); SA(1, 2, 1);
    asm volatile("s_waitcnt vmcnt(6)" ::: "memory");
    __builtin_amdgcn_s_barrier();

    #pragma unroll
    for (int i = 0; i < 4; ++i) {                 // 2 K-tiles / iteration
        const bool more = (i < 3);
        const int t1 = 2 * i + 1, t2 = 2 * i + 2, t3 = 2 * i + 3;
        // p1: q0 of buf0; read all B(buf0); stage buf1 A1,A3 (tile t1)
        PH(0, 0, { DSB(0); SA(1, 1, t1); SA(1, 3, t1); }, )
        // p2: q1 buf0; stage buf0 B0,B1 (t2)   [B(buf0) dead after p1]
        PH(0, 1, { if (more) { SB(0, 0, t2); SB(0, 1, t2); } }, )
        // p3: q2 buf0; stage buf0 B2,B3 (t2)
        PH(0, 2, { if (more) { SB(0, 2, t2); SB(0, 3, t2); } }, )
        // p4: q3 buf0; stage buf0 A0,A2 (t2)  [q0/q1 rows dead after p2]
        PH(0, 3, { if (more) { SA(0, 0, t2); SA(0, 2, t2); } },
           if (more) { asm volatile("s_waitcnt vmcnt(6)" ::: "memory"); }
           else      { asm volatile("s_waitcnt vmcnt(0)" ::: "memory"); } )
        // p5: q0 buf1; read all B(buf1); stage buf0 A1,A3 (t2)
        PH(1, 0, { DSB(1); if (more) { SA(0, 1, t2); SA(0, 3, t2); } }, )
        // p6: q1 buf1; stage buf1 B0,B1 (t3)
        PH(1, 1, { if (more) { SB(1, 0, t3); SB(1, 1, t3); } }, )
        // p7: q2 buf1; stage buf1 B2,B3 (t3)
        PH(1, 2, { if (more) { SB(1, 2, t3); SB(1, 3, t3); } }, )
        // p8: q3 buf1; stage buf1 A0,A2 (t3); vmcnt(6) -> t2 fully landed
        PH(1, 3, { if (more) { SA(1, 0, t3); SA(1, 2, t3); } },
           if (more) { asm volatile("s_waitcnt vmcnt(6)" ::: "memory"); } )
    }
#undef PH
#undef DSB

    // ---- epilogue: acc -> LDS (swizzled bf16 [256][256]) -> coalesced flush
    __syncthreads();                       // all LDS reads of the loop done
    unsigned short* Ct = wm ? &Bs[0][0] : &As[0][0];   // rows 0..127 / 128..255
    #pragma unroll
    for (int n = 0; n < 4; ++n) {
        const int nn = n0 + wn * 64 + n * 16 + lr;
        const float bias = (nn < Nreal) ? (b1[nn] + (b2 ? b2[nn] : 0.f)) : 0.f;
        const int col = wn * 64 + n * 16 + lr;
        #pragma unroll
        for (int m = 0; m < 8; ++m) {
            #pragma unroll
            for (int r = 0; r < 4; ++r) {
                const int row = m * 16 + quad * 4 + r;     // local to 128-half
                float v = acc[m][n][r] + bias;
                if (TANH) v = tanhf(v);
                Ct[row * 256 + (((col >> 3) ^ (row & 7)) << 3) + (col & 7)] = f2bf(v);
            }
        }
    }
    __syncthreads();
    // flush 128KB: 512 threads x 16 iters x 16B, fully contiguous per wave
    #pragma unroll
    for (int it = 0; it < 16; ++it) {
        const int c   = it * 512 + tid;
        const int row = c >> 5;                 // 0..255
        const int gc  = c & 31;                 // 16B granule in row
        const unsigned short* src = (row < 128)
            ? &As[0][row * 256 + ((gc ^ (row & 7)) << 3)]
            : &Bs[0][(row - 128) * 256 + ((gc ^ (row & 7)) << 3)];
        v8s val = *(const v8s*)src;
        *(v8s*)&Cg[(size_t)(m0 + row) * Npad + n0 + gc * 8] = val;
    }
}

// fp32 -> bf16, 8 elems/thread (n must be multiple of 2048)
__global__ void cvt8(const float* __restrict__ src, unsigned short* __restrict__ dst)
{
    const size_t i = ((size_t)blockIdx.x * 256 + threadIdx.x) * 8;
    float4 f0 = *(const float4*)(src + i);
    float4 f1 = *(const float4*)(src + i + 4);
    unsigned short t8[8];
    t8[0]=f2bf(f0.x); t8[1]=f2bf(f0.y); t8[2]=f2bf(f0.z); t8[3]=f2bf(f0.w);
    t8[4]=f2bf(f1.x); t8[5]=f2bf(f1.y); t8[6]=f2bf(f1.z); t8[7]=f2bf(f1.w);
    *(v8s*)(dst + i) = *(const v8s*)t8;
}

// Wa2 (1000x512 fp32) -> zero-padded 1024x512 bf16
__global__ void wa2pad(const float* __restrict__ src, unsigned short* __restrict__ dst)
{
    const int i = blockIdx.x * 256 + threadIdx.x;
    const int row = i >> 9;
    dst[i] = (row < 1000) ? f2bf(src[(size_t)row * 512 + (i & 511)]) : (unsigned short)0;
}

// masked initial state (bf16) + zero row buffer
__global__ void init_state(const float* __restrict__ h0, const float* __restrict__ c0,
                           const int* __restrict__ done,
                           unsigned short* __restrict__ h_init, unsigned short* __restrict__ c_init,
                           unsigned short* __restrict__ zbuf)
{
    const int b = blockIdx.x;
    const float m = 1.f - (float)done[b];
    for (int k = threadIdx.x; k < 512; k += 256) {
        h_init[(size_t)b * 512 + k] = f2bf(h0[(size_t)b * 512 + k] * m);
        c_init[(size_t)b * 512 + k] = f2bf(c0[(size_t)b * 512 + k] * m);
        if (b == 0) zbuf[k] = 0;
    }
}

// ---------------------------------------------------------------------------
// Segment prep (single WG): one global walk of done (bits cached in LDS),
// per-round row lists for s<12, level-grouped tail list for s>=12,
// maxS, and barrier-counter reset for lstm_tail.
// ---------------------------------------------------------------------------
__global__ __launch_bounds__(256, 1)
void seg_prep(const int* __restrict__ done, int* __restrict__ rows,
              int* __restrict__ counts, int* __restrict__ offs,
              int* __restrict__ trows, int* __restrict__ tcnt, int* __restrict__ toffs,
              int* __restrict__ maxS, int* __restrict__ bar, int T)
{
    __shared__ unsigned int   bits[256][8];
    __shared__ unsigned short cnt[256][S0R];
    __shared__ unsigned short base[256][S0R];
    __shared__ int tot[S0R];
    __shared__ int goff[S0R];
    __shared__ int tcl[NLEV];
    __shared__ int tol[NLEV];
    __shared__ int tpos[NLEV];
    __shared__ int mxl[256];
    const int b = threadIdx.x;
    #pragma unroll
    for (int s = 0; s < S0R; ++s) cnt[b][s] = 0;
    #pragma unroll
    for (int i = 0; i < 8; ++i) bits[b][i] = 0;
    for (int l = b; l < NLEV; l += 256) { tcl[l] = 0; tpos[l] = 0; }
    __syncthreads();

    int s = 0, mx = 0;
    for (int t = 0; t < T; ++t) {
        int d = done[t * 256 + b];
        if (d) bits[b][t >> 5] |= (1u << (t & 31));
        s = (t == 0 || d) ? 0 : s + 1;
        if (s < S0R) cnt[b][s]++;
        else atomicAdd(&tcl[s - S0R], 1);
        mx = mx > s ? mx : s;
    }
    mxl[b] = mx;
    __syncthreads();

    if (b < S0R) {
        int tsum = 0;
        for (int bb = 0; bb < 256; ++bb) { base[bb][b] = (unsigned short)tsum; tsum += cnt[bb][b]; }
        tot[b] = tsum;
    }
    __syncthreads();
    if (b == 0) {
        int run = 0;
        for (int ss = 0; ss < S0R; ++ss) { goff[ss] = run; run += tot[ss]; }
        run = 0;
        for (int l = 0; l < NLEV; ++l) { tol[l] = run; run += tcl[l]; }
        int m = 0;
        for (int bb = 0; bb < 256; ++bb) m = m > mxl[bb] ? m : mxl[bb];
        *maxS = m;
        *bar  = 0;
    }
    __syncthreads();
    if (b < S0R) { counts[b] = tot[b]; offs[b] = goff[b]; }
    for (int l = b; l < NLEV; l += 256) { tcnt[l] = tcl[l]; toffs[l] = tol[l]; }

    s = 0;
    for (int t = 0; t < T; ++t) {
        int d = (bits[b][t >> 5] >> (t & 31)) & 1;
        s = (t == 0 || d) ? 0 : s + 1;
        if (s < S0R) {
            int idx = goff[s] + (int)base[b][s];
            base[b][s]++;
            rows[idx] = t * 256 + b;
        } else {
            int idx = tol[s - S0R] + atomicAdd(&tpos[s - S0R], 1);
            trows[idx] = t * 256 + b;
        }
    }
}

// ---------------------------------------------------------------------------
// Fused LSTM round (s < 12): 128 gathered rows x (4 gates x 32 hidden cols),
// async-staged A/B, LDS gate exchange, fused cell update.
// ---------------------------------------------------------------------------
__global__ __launch_bounds__(256)
void lstm_round(const int* __restrict__ rows, const int* __restrict__ counts,
                const int* __restrict__ offs, int s,
                const unsigned short* __restrict__ XG,
                const unsigned short* __restrict__ Whb,
                const unsigned short* __restrict__ h_init,
                const unsigned short* __restrict__ c_init,
                const unsigned short* __restrict__ zbuf,
                unsigned short* __restrict__ Hraw, unsigned short* __restrict__ Cst)
{
    const int M = counts[s];
    if (M == 0) return;
    const int off    = offs[s];
    const int mtiles = (M + 127) >> 7;

    __shared__ __align__(16) unsigned short As[128 * 32];
    __shared__ __align__(16) unsigned short Bs[128 * 32];
    __shared__ __align__(16) unsigned short Gx[128 * 136];
    __shared__ int rl[128];

    const int tid  = threadIdx.x;
    const int w    = tid >> 6;
    const int lane = tid & 63;
    const int quad = lane >> 4;
    const int lr   = lane & 15;
    const int wm   = w & 1, wn = w >> 1;
    const int c0   = blockIdx.x * 32;
    const int srow = lane >> 2;
    const int kblk = (lane & 3) ^ ((lane >> 3) & 3);

    const int br0 = w * 16 + srow;
    const int br1 = 64 + br0;
    const unsigned short* gB0 = Whb + (size_t)((br0 >> 5) * 512 + c0 + (br0 & 31)) * 512 + kblk * 8;
    const unsigned short* gB1 = Whb + (size_t)((br1 >> 5) * 512 + c0 + (br1 & 31)) * 512 + kblk * 8;
    unsigned short* lA0 = As + (w * 16) * 32;
    unsigned short* lA1 = As + (64 + w * 16) * 32;
    unsigned short* lB0 = Bs + (w * 16) * 32;
    unsigned short* lB1 = Bs + (64 + w * 16) * 32;

    const int swz = (quad ^ ((lr >> 1) & 3)) * 8;
    int aoff[4], boff[4];
    #pragma unroll
    for (int i = 0; i < 4; ++i) {
        aoff[i] = (wm * 64 + i * 16 + lr) * 32 + swz;
        boff[i] = (wn * 64 + i * 16 + lr) * 32 + swz;
    }

    for (int mt = blockIdx.y; mt < mtiles; mt += gridDim.y) {
        __syncthreads();
        if (tid < 128) {
            int li = mt * 128 + tid;
            rl[tid] = (li < M) ? rows[off + li] : -1;
        }
        __syncthreads();

        int g0r = rl[w * 16 + srow];
        int g1r = rl[64 + w * 16 + srow];
        const unsigned short* gA0;
        const unsigned short* gA1;
        if (s == 0) {
            gA0 = (g0r >= 0 && g0r < 256) ? h_init + (size_t)g0r * 512 + kblk * 8 : zbuf + kblk * 8;
            gA1 = (g1r >= 0 && g1r < 256) ? h_init + (size_t)g1r * 512 + kblk * 8 : zbuf + kblk * 8;
        } else {
            gA0 = (g0r >= 0) ? Hraw + (size_t)(g0r - 256) * 512 + kblk * 8 : zbuf + kblk * 8;
            gA1 = (g1r >= 0) ? Hraw + (size_t)(g1r - 256) * 512 + kblk * 8 : zbuf + kblk * 8;
        }

        v4f zz = {0.f, 0.f, 0.f, 0.f};
        v4f acc[4][4] = {{zz,zz,zz,zz},{zz,zz,zz,zz},{zz,zz,zz,zz},{zz,zz,zz,zz}};

        for (int k = 0; k < 16; ++k) {
            __syncthreads();
            gld_lds16(gA0 + k * 32, lA0);
            gld_lds16(gA1 + k * 32, lA1);
            gld_lds16(gB0 + k * 32, lB0);
            gld_lds16(gB1 + k * 32, lB1);
            __syncthreads();
            v8s a[4], b[4];
            #pragma unroll
            for (int i = 0; i < 4; ++i) { a[i] = *(const v8s*)&As[aoff[i]]; b[i] = *(const v8s*)&Bs[boff[i]]; }
            #pragma unroll
            for (int i = 0; i < 4; ++i)
                #pragma unroll
                for (int j = 0; j < 4; ++j)
                    acc[i][j] = __builtin_amdgcn_mfma_f32_16x16x32_bf16(a[i], b[j], acc[i][j], 0, 0, 0);
        }

        #pragma unroll
        for (int j = 0; j < 4; ++j) {
            const int nl = wn * 64 + j * 16 + lr;
            #pragma unroll
            for (int i = 0; i < 4; ++i)
                #pragma unroll
                for (int r = 0; r < 4; ++r)
                    Gx[(wm * 64 + i * 16 + quad * 4 + r) * 136 + nl] = f2bf(acc[i][j][r]);
        }
        __syncthreads();

        {
            const int rloc = tid >> 1;
            const int half = tid & 1;
            const int gr   = rl[rloc];
            if (gr >= 0) {
                #pragma unroll
                for (int ch = 0; ch < 2; ++ch) {
                    const int co = half * 16 + ch * 8;
                    const int kg = c0 + co;
                    v8s q0 = *(const v8s*)&Gx[rloc * 136 +   0 + co];
                    v8s q1 = *(const v8s*)&Gx[rloc * 136 +  32 + co];
                    v8s q2 = *(const v8s*)&Gx[rloc * 136 +  64 + co];
                    v8s q3 = *(const v8s*)&Gx[rloc * 136 +  96 + co];
                    const size_t xb = (size_t)gr * 2048 + kg;
                    v8s x0 = *(const v8s*)&XG[xb];
                    v8s x1 = *(const v8s*)&XG[xb + 512];
                    v8s x2 = *(const v8s*)&XG[xb + 1024];
                    v8s x3 = *(const v8s*)&XG[xb + 1536];
                    float cprev[8];
                    if (s == 0) {
                        if (gr < 256) {
                            v8s cv = *(const v8s*)&c_init[(size_t)gr * 512 + kg];
                            #pragma unroll
                            for (int e = 0; e < 8; ++e) cprev[e] = bf2f((unsigned short)cv[e]);
                        } else {
                            #pragma unroll
                            for (int e = 0; e < 8; ++e) cprev[e] = 0.f;
                        }
                    } else {
                        v8s cv = *(const v8s*)&Cst[(size_t)(gr - 256) * 512 + kg];
                        #pragma unroll
                        for (int e = 0; e < 8; ++e) cprev[e] = bf2f((unsigned short)cv[e]);
                    }
                    unsigned short hc[8], cc[8];
                    #pragma unroll
                    for (int e = 0; e < 8; ++e) {
                        float gi = bf2f((unsigned short)q0[e]) + bf2f((unsigned short)x0[e]);
                        float gf = bf2f((unsigned short)q1[e]) + bf2f((unsigned short)x1[e]);
                        float gg = bf2f((unsigned short)q2[e]) + bf2f((unsigned short)x2[e]);
                        float go = bf2f((unsigned short)q3[e]) + bf2f((unsigned short)x3[e]);
                        float c  = sigmoidf_(gf) * cprev[e] + sigmoidf_(gi) * tanhf(gg);
                        float h  = sigmoidf_(go) * tanhf(c);
                        cc[e] = f2bf(c);
                        hc[e] = f2bf(h);
                    }
                    *(v8s*)&Cst[(size_t)gr * 512 + kg]  = *(const v8s*)cc;
                    *(v8s*)&Hraw[(size_t)gr * 512 + kg] = *(const v8s*)hc;
                }
            }
        }
    }
}

// ---------------------------------------------------------------------------
// Tail (s >= 12): 64 WGs, each holds its 32-row Whh slice (8 hidden cols x
// 4 gates) resident in LDS; levels processed with a device-scope spin barrier
// between them (64 blocks <= 256 CUs, stream-serialized => co-resident;
// monotone arrival counter => no deadlock; seg_prep resets it every call).
// ---------------------------------------------------------------------------
__global__ __launch_bounds__(256, 1)
void lstm_tail(const int* __restrict__ trows, const int* __restrict__ tcnt,
               const int* __restrict__ toffs, const int* __restrict__ maxS_p,
               const unsigned short* __restrict__ XG,
               const unsigned short* __restrict__ Whb,
               unsigned short* __restrict__ Hraw, unsigned short* __restrict__ Cst,
               int* __restrict__ bar)
{
    const int mS = *maxS_p;
    if (mS < S0R) return;
    __shared__ __align__(16) unsigned short Wl[32 * 512];   // 32 KB
    __shared__ __align__(16) unsigned short Hb[16 * 512];   // 16 KB
    __shared__ float Gb[16 * 32];
    __shared__ int rl[16];
    const int j    = blockIdx.x;          // hidden-col slice: cols j*8 .. j*8+8
    const int tid  = threadIdx.x;
    const int w    = tid >> 6;
    const int lane = tid & 63;
    const int quad = lane >> 4;
    const int lr   = lane & 15;

    // resident Whh slice: Wl row n = g*8+c  <-  Whh row g*512 + j*8 + c
    for (int e = tid; e < 32 * 64; e += 256) {
        int n = e >> 6, kb = e & 63;
        int g = n >> 3, c = n & 7;
        *(v8s*)&Wl[n * 512 + kb * 8] = *(const v8s*)&Whb[(size_t)(g * 512 + j * 8 + c) * 512 + kb * 8];
    }

    int target = 0;
    for (int s = S0R; s <= mS; ++s) {
        const int lev = s - S0R;
        const int M   = tcnt[lev];
        const int off = toffs[lev];
        for (int ch = 0; ch < M; ch += 16) {
            __syncthreads();
            if (tid < 16) rl[tid] = (ch + tid < M) ? trows[off + ch + tid] : -1;
            __syncthreads();
            {   // stage h_prev rows (s>=12 => prev always in Hraw)
                int r = tid >> 4, seg = (tid & 15) * 32;
                int gr = rl[r];
                if (gr >= 0) {
                    const unsigned short* src = &Hraw[(size_t)(gr - 256) * 512 + seg];
                    *(v8s*)&Hb[r * 512 + seg]      = *(const v8s*)(src);
                    *(v8s*)&Hb[r * 512 + seg + 8]  = *(const v8s*)(src + 8);
                    *(v8s*)&Hb[r * 512 + seg + 16] = *(const v8s*)(src + 16);
                    *(v8s*)&Hb[r * 512 + seg + 24] = *(const v8s*)(src + 24);
                } else {
                    v8s z = {0,0,0,0,0,0,0,0};
                    *(v8s*)&Hb[r * 512 + seg]      = z;
                    *(v8s*)&Hb[r * 512 + seg + 8]  = z;
                    *(v8s*)&Hb[r * 512 + seg + 16] = z;
                    *(v8s*)&Hb[r * 512 + seg + 24] = z;
                }
            }
            __syncthreads();
            if (w < 2) {      // wave w computes output tile n = w*16 .. w*16+16
                v4f acc = {0.f, 0.f, 0.f, 0.f};
                for (int k = 0; k < 16; ++k) {
                    v8s a = *(const v8s*)&Hb[lr * 512 + k * 32 + quad * 8];
                    v8s b = *(const v8s*)&Wl[(w * 16 + lr) * 512 + k * 32 + quad * 8];
                    acc = __builtin_amdgcn_mfma_f32_16x16x32_bf16(a, b, acc, 0, 0, 0);
                }
                #pragma unroll
                for (int r = 0; r < 4; ++r)
                    Gb[(quad * 4 + r) * 32 + w * 16 + lr] = acc[r];
            }
            __syncthreads();
            if (tid < 128) {
                int r = tid >> 3, c = tid & 7;
                int gr = rl[r];
                if (gr >= 0) {
                    int k = j * 8 + c;
                    const size_t xb = (size_t)gr * 2048 + k;
                    float gi = Gb[r * 32 +  0 + c] + bf2f(XG[xb]);
                    float gf = Gb[r * 32 +  8 + c] + bf2f(XG[xb + 512]);
                    float gg = Gb[r * 32 + 16 + c] + bf2f(XG[xb + 1024]);
                    float go = Gb[r * 32 + 24 + c] + bf2f(XG[xb + 1536]);
                    float cp = bf2f(Cst[(size_t)(gr - 256) * 512 + k]);
                    float cc = sigmoidf_(gf) * cp + sigmoidf_(gi) * tanhf(gg);
                    float hh = sigmoidf_(go) * tanhf(cc);
                    Cst[(size_t)gr * 512 + k]  = f2bf(cc);
                    Hraw[(size_t)gr * 512 + k] = f2bf(hh);
                }
            }
        }
        // inter-level device barrier
        target += 64;
        __threadfence();
        __syncthreads();
        if (tid == 0) {
            __hip_atomic_fetch_add(bar, 1, __ATOMIC_RELEASE, __HIP_MEMORY_SCOPE_AGENT);
            while (__hip_atomic_load(bar, __ATOMIC_ACQUIRE, __HIP_MEMORY_SCOPE_AGENT) < target) {}
        }
        __syncthreads();
        __threadfence();
    }
}

// Hraw += H2 in place (-> new_hidden), 8 elems/thread
__global__ void nh_add(unsigned short* __restrict__ H, const unsigned short* __restrict__ H2)
{
    const size_t i = ((size_t)blockIdx.x * 256 + threadIdx.x) * 8;
    v8s a = *(const v8s*)(H + i);
    v8s b = *(const v8s*)(H + i);
    (void)b;
    v8s b2 = *(const v8s*)(H2 + i);
    unsigned short t8[8];
    #pragma unroll
    for (int e = 0; e < 8; ++e)
        t8[e] = f2bf(bf2f((unsigned short)a[e]) + bf2f((unsigned short)b2[e]));
    *(v8s*)(H + i) = *(const v8s*)t8;
}

// actor head: one wave per row over bf16 logits (stride 1024, 1000 valid)
__global__ void head_reduce(const unsigned short* __restrict__ logits,
                            const int* __restrict__ action,
                            float* __restrict__ out, int TB)
{
    const int r = blockIdx.x * 4 + (threadIdx.x >> 6);
    const int lane = threadIdx.x & 63;
    const unsigned short* row = logits + (size_t)r * 1024;
    float m = -1e30f, Z = 0.f, S = 0.f;
    v8s v0 = *(const v8s*)&row[lane * 8];
    #pragma unroll
    for (int e = 0; e < 8; ++e) {
        float xv = bf2f((unsigned short)v0[e]);
        if (xv > m) { float sc = expf(m - xv); Z *= sc; S *= sc; m = xv; }
        float ev = expf(xv - m);
        Z += ev; S += xv * ev;
    }
    v8s v1 = *(const v8s*)&row[512 + lane * 8];
    #pragma unroll
    for (int e = 0; e < 8; ++e) {
        int c = 512 + lane * 8 + e;
        if (c < 1000) {
            float xv = bf2f((unsigned short)v1[e]);
            if (xv > m) { float sc = expf(m - xv); Z *= sc; S *= sc; m = xv; }
            float ev = expf(xv - m);
            Z += ev; S += xv * ev;
        }
    }
    #pragma unroll
    for (int offb = 32; offb > 0; offb >>= 1) {
        float m2 = __shfl_xor(m, offb);
        float Z2 = __shfl_xor(Z, offb);
        float S2 = __shfl_xor(S, offb);
        float M  = fmaxf(m, m2);
        float s1 = expf(m - M), s2 = expf(m2 - M);
        Z = Z * s1 + Z2 * s2;
        S = S * s1 + S2 * s2;
        m = M;
    }
    if (lane == 0) {
        float lse = m + logf(Z);
        float xa  = bf2f(row[action[r]]);
        out[r]      = xa - lse;
        out[TB + r] = lse - S / Z;
    }
}

__global__ void critic_v(const unsigned short* __restrict__ C1, const float* __restrict__ Wc2,
                         const float* __restrict__ bc2, float* __restrict__ out, int TB)
{
    const int r = blockIdx.x * 4 + (threadIdx.x >> 6);
    const int lane = threadIdx.x & 63;
    const unsigned short* row = C1 + (size_t)r * 512;
    v8s hv = *(const v8s*)&row[lane * 8];
    float4 w0 = *(const float4*)&Wc2[lane * 8];
    float4 w1 = *(const float4*)&Wc2[lane * 8 + 4];
    float s = bf2f((unsigned short)hv[0]) * w0.x + bf2f((unsigned short)hv[1]) * w0.y +
              bf2f((unsigned short)hv[2]) * w0.z + bf2f((unsigned short)hv[3]) * w0.w +
              bf2f((unsigned short)hv[4]) * w1.x + bf2f((unsigned short)hv[5]) * w1.y +
              bf2f((unsigned short)hv[6]) * w1.z + bf2f((unsigned short)hv[7]) * w1.w;
    #pragma unroll
    for (int offb = 32; offb > 0; offb >>= 1) s += __shfl_xor(s, offb);
    if (lane == 0) out[2 * TB + r] = s + bc2[0];
}

extern "C" void kernel_launch(void* const* d_in, const int* in_sizes, int n_in,
                              void* d_out, int out_size, void* d_ws, size_t ws_size,
                              hipStream_t stream)
{
    const float* x    = (const float*)d_in[0];
    const int*  done  = (const int*)d_in[1];
    const int*  action= (const int*)d_in[2];
    const float* W_t1 = (const float*)d_in[4];
    const float* b_t1 = (const float*)d_in[5];
    const float* W_t2 = (const float*)d_in[6];
    const float* b_t2 = (const float*)d_in[7];
    const float* Wih  = (const float*)d_in[8];
    const float* Whh  = (const float*)d_in[9];
    const float* bih  = (const float*)d_in[10];
    const float* bhh  = (const float*)d_in[11];
    const float* Wa1  = (const float*)d_in[12];
    const float* ba1  = (const float*)d_in[13];
    const float* Wa2  = (const float*)d_in[14];
    const float* ba2  = (const float*)d_in[15];
    const float* Wc1  = (const float*)d_in[16];
    const float* bc1  = (const float*)d_in[17];
    const float* Wc2  = (const float*)d_in[18];
    const float* bc2  = (const float*)d_in[19];
    const float* h0   = (const float*)d_in[20];
    const float* c0   = (const float*)d_in[21];
    float* out = (float*)d_out;

    const int TB = in_sizes[1];      // 65536
    const int T  = TB / 256;         // 256

    const size_t MiB = 1024 * 1024;
    char* ws = (char*)d_ws;
    unsigned short* XG     = (unsigned short*)(ws);
    unsigned short* H1     = (unsigned short*)(ws);
    unsigned short* logits = (unsigned short*)(ws);
    unsigned short* A1     = (unsigned short*)(ws + 136 * MiB);
    unsigned short* C1     = A1;
    unsigned short* Cst    = (unsigned short*)(ws + 256 * MiB);
    unsigned short* H2     = (unsigned short*)(ws + 320 * MiB);
    unsigned short* Hraw   = (unsigned short*)(ws + 384 * MiB);
    unsigned short* xbf    = Hraw;
    unsigned short* Wt1b   = (unsigned short*)(ws + 448 * MiB);
    unsigned short* Wt2b   = Wt1b + 512 * 512;
    unsigned short* Wihb   = Wt2b + 512 * 512;
    unsigned short* Whhb   = Wihb + 2048 * 512;
    unsigned short* Wa1b   = Whhb + 2048 * 512;
    unsigned short* Wc1b   = Wa1b + 512 * 512;
    unsigned short* Wa2b   = Wc1b + 512 * 512;
    unsigned short* h_init = Wa2b + 1024 * 512;
    unsigned short* c_init = h_init + 256 * 512;
    unsigned short* zbuf   = c_init + 256 * 512;
    int* rows   = (int*)(zbuf + 512);
    int* trows  = rows + 65536;
    int* counts = trows + 65536;
    int* offs   = counts + S0R;
    int* tcnt   = offs + S0R;
    int* toffs  = tcnt + NLEV;
    int* maxS   = toffs + NLEV;
    int* bar    = maxS + 1;

    dim3 blk(256);
    dim3 blk5(512);

    // dtype conversions (weights + x), init, segment lists
    cvt8<<<16384, blk, 0, stream>>>(x, xbf);
    cvt8<<<128,  blk, 0, stream>>>(W_t1, Wt1b);
    cvt8<<<128,  blk, 0, stream>>>(W_t2, Wt2b);
    cvt8<<<512,  blk, 0, stream>>>(Wih,  Wihb);
    cvt8<<<512,  blk, 0, stream>>>(Whh,  Whhb);
    cvt8<<<128,  blk, 0, stream>>>(Wa1,  Wa1b);
    cvt8<<<128,  blk, 0, stream>>>(Wc1,  Wc1b);
    wa2pad<<<2048, blk, 0, stream>>>(Wa2, Wa2b);
    init_state<<<256, blk, 0, stream>>>(h0, c0, done, h_init, c_init, zbuf);
    seg_prep<<<1, blk, 0, stream>>>(done, rows, counts, offs, trows, tcnt, toffs, maxS, bar, T);

    // trunk + hoisted x-side gates (256x256-tile 8-phase GEMM)
    gemm256<true ><<<512,  blk5, 0, stream>>>(xbf, Wt1b, b_t1, nullptr, H1, 512, 512, 2);
    gemm256<true ><<<512,  blk5, 0, stream>>>(H1,  Wt2b, b_t2, nullptr, H2, 512, 512, 2);
    gemm256<false><<<2048, blk5, 0, stream>>>(H2,  Wihb, bih,  bhh,    XG, 2048, 2048, 8);

    // segment-parallel LSTM: 12 gather-GEMM rounds + resident-weight tail
    static const int Gs[S0R] = {256, 128, 64, 32, 16, 8, 4, 2, 1, 1, 1, 1};
    for (int s = 0; s < S0R; ++s)
        lstm_round<<<dim3(16, Gs[s]), blk, 0, stream>>>(rows, counts, offs, s, XG, Whhb,
                                                        h_init, c_init, zbuf, Hraw, Cst);
    lstm_tail<<<64, blk, 0, stream>>>(trows, tcnt, toffs, maxS, XG, Whhb, Hraw, Cst, bar);

    // residual: Hraw <- Hraw + H2 (= new_hidden)
    nh_add<<<16384, blk, 0, stream>>>(Hraw, H2);

    // actor head
    gemm256<true ><<<512,  blk5, 0, stream>>>(Hraw, Wa1b, ba1, nullptr, A1, 512, 512, 2);
    gemm256<false><<<1024, blk5, 0, stream>>>(A1, Wa2b, ba2, nullptr, logits, 1000, 1024, 4);
    head_reduce<<<TB / 4, blk, 0, stream>>>(logits, action, out, TB);

    // critic head
    gemm256<true ><<<512, blk5, 0, stream>>>(Hraw, Wc1b, bc1, nullptr, C1, 512, 512, 2);
    critic_v<<<TB / 4, blk, 0, stream>>>(C1, Wc2, bc2, out, TB);
}

// Round 3
// 1626.485 us; speedup vs baseline: 1.1581x; 1.0288x over previous
//
#include <hip/hip_runtime.h>
#include <hip/hip_bf16.h>

typedef short v8s __attribute__((ext_vector_type(8)));
typedef float v4f __attribute__((ext_vector_type(4)));

#define S0R 12      // rounds 0..11 via gather-GEMM; lstm_tail covers s >= 12
#define NLEV 244    // tail levels 12..255

__device__ __forceinline__ float bf2f(unsigned short u) {
    union { unsigned int i; float f; } v; v.i = ((unsigned int)u) << 16; return v.f;
}
__device__ __forceinline__ unsigned short f2bf(float f) {
    union { float f; unsigned int i; } v; v.f = f;
    unsigned int x = v.i;
    return (unsigned short)((x + 0x7fffu + ((x >> 16) & 1u)) >> 16);
}
__device__ __forceinline__ float sigmoidf_(float x) { return 1.0f / (1.0f + expf(-x)); }

// async global->LDS, 16B per lane; LDS dst is wave-uniform base + lane*16
__device__ __forceinline__ void gld_lds16(const unsigned short* g, unsigned short* l) {
    __builtin_amdgcn_global_load_lds(
        (const __attribute__((address_space(1))) unsigned int*)g,
        (__attribute__((address_space(3))) unsigned int*)l, 16, 0, 0);
}

// ---------------------------------------------------------------------------
// gemm256: C[M,Npad] = act(A[.,Astr][:512] @ W[Npad,512]^T + b1), bf16.
// 256x256 tile, BK=64, 8 waves (2Mx4N), 8-phase counted-vmcnt schedule,
// XOR-swizzled LDS, setprio, XCD-chunked swizzle.  K fixed at 512.
// Epilogue via LDS re-use -> 16B/lane coalesced stores (write-amp fix, r2).
// ---------------------------------------------------------------------------
template <bool TANH>
__global__ __launch_bounds__(512, 2)
void gemm256(const unsigned short* __restrict__ Ag, const unsigned short* __restrict__ Wg,
             const float* __restrict__ b1,
             unsigned short* __restrict__ Cg, int Nreal, int Npad, int Ntiles, int Astr)
{
    __shared__ __align__(16) unsigned short As[2][256 * 64];   // 64 KB
    __shared__ __align__(16) unsigned short Bs[2][256 * 64];   // 64 KB

    const int tid  = threadIdx.x;
    const int w    = tid >> 6;          // 0..7
    const int lane = tid & 63;
    const int quad = lane >> 4;
    const int lr   = lane & 15;
    const int wm   = w >> 2;            // 0..1
    const int wn   = w & 3;             // 0..3

    const int nwg = gridDim.x;
    const int cpx = nwg >> 3;
    const int swz = (blockIdx.x & 7) * cpx + (blockIdx.x >> 3);
    const int m0  = (swz / Ntiles) * 256;
    const int n0  = (swz % Ntiles) * 256;

    const unsigned short* gA = Ag + (size_t)m0 * Astr;
    const unsigned short* gB = Wg + (size_t)n0 * 512;

    const int sr  = w * 8 + (lane >> 3);
    const int skg = (lane & 7) ^ ((lane >> 3) & 7);

    auto SA = [&](int buf, int u, int kt) {
        gld_lds16(gA + (size_t)(u * 64 + sr) * Astr + kt * 64 + skg * 8,
                  &As[buf][(u * 64 + w * 8) * 64]);
    };
    auto SB = [&](int buf, int u, int kt) {
        gld_lds16(gB + (size_t)(u * 64 + sr) * 512 + kt * 64 + skg * 8,
                  &Bs[buf][(u * 64 + w * 8) * 64]);
    };

    const int g8_0  = (quad ^ (lr & 7)) * 8;
    const int g8_1  = ((quad + 4) ^ (lr & 7)) * 8;
    const int aBase = (wm * 128 + lr) * 64;
    const int bBase = (wn * 64 + lr) * 64;

    v4f zz = {0.f, 0.f, 0.f, 0.f};
    v4f acc[8][4];
    #pragma unroll
    for (int m = 0; m < 8; ++m)
        #pragma unroll
        for (int n = 0; n < 4; ++n) acc[m][n] = zz;
    v8s Bf[4][2];

#define DSB(BUF)                                                         \
    _Pragma("unroll")                                                    \
    for (int n = 0; n < 4; ++n) {                                        \
        Bf[n][0] = *(const v8s*)&Bs[BUF][bBase + n * 1024 + g8_0];       \
        Bf[n][1] = *(const v8s*)&Bs[BUF][bBase + n * 1024 + g8_1];       \
    }

#define PH(BUF, Q, STMTS, PREBAR)                                                     \
    {                                                                                 \
        const v8s a00 = *(const v8s*)&As[BUF][aBase + ((Q)*2 + 0) * 1024 + g8_0];     \
        const v8s a01 = *(const v8s*)&As[BUF][aBase + ((Q)*2 + 0) * 1024 + g8_1];     \
        const v8s a10 = *(const v8s*)&As[BUF][aBase + ((Q)*2 + 1) * 1024 + g8_0];     \
        const v8s a11 = *(const v8s*)&As[BUF][aBase + ((Q)*2 + 1) * 1024 + g8_1];     \
        STMTS;                                                                        \
        PREBAR;                                                                       \
        __builtin_amdgcn_s_barrier();                                                 \
        asm volatile("s_waitcnt lgkmcnt(0)" ::: "memory");                            \
        __builtin_amdgcn_sched_barrier(0);                                            \
        __builtin_amdgcn_s_setprio(1);                                                \
        _Pragma("unroll")                                                             \
        for (int n = 0; n < 4; ++n) {                                                 \
            acc[(Q)*2    ][n] = __builtin_amdgcn_mfma_f32_16x16x32_bf16(a00, Bf[n][0], acc[(Q)*2    ][n], 0, 0, 0); \
            acc[(Q)*2    ][n] = __builtin_amdgcn_mfma_f32_16x16x32_bf16(a01, Bf[n][1], acc[(Q)*2    ][n], 0, 0, 0); \
            acc[(Q)*2 + 1][n] = __builtin_amdgcn_mfma_f32_16x16x32_bf16(a10, Bf[n][0], acc[(Q)*2 + 1][n], 0, 0, 0); \
            acc[(Q)*2 + 1][n] = __builtin_amdgcn_mfma_f32_16x16x32_bf16(a11, Bf[n][1], acc[(Q)*2 + 1][n], 0, 0, 0); \
        }                                                                             \
        __builtin_amdgcn_s_setprio(0);                                                \
        __builtin_amdgcn_s_barrier();                                                 \
    }

    SB(0, 0, 0); SB(0, 1, 0); SB(0, 2, 0); SB(0, 3, 0);
    SA(0, 0, 0); SA(0, 2, 0); SA(0, 1, 0); SA(0, 3, 0);
    SB(1, 0, 1); SB(1, 1, 1); SB(1, 2, 1); SB(1, 3, 1);
    SA(1, 0, 1); SA(1, 2, 1);
    asm volatile("s_waitcnt vmcnt(6)" ::: "memory");
    __builtin_amdgcn_s_barrier();

    #pragma unroll
    for (int i = 0; i < 4; ++i) {                 // 2 K-tiles / iteration
        const bool more = (i < 3);
        const int t1 = 2 * i + 1, t2 = 2 * i + 2, t3 = 2 * i + 3;
        PH(0, 0, { DSB(0); SA(1, 1, t1); SA(1, 3, t1); }, )
        PH(0, 1, { if (more) { SB(0, 0, t2); SB(0, 1, t2); } }, )
        PH(0, 2, { if (more) { SB(0, 2, t2); SB(0, 3, t2); } }, )
        PH(0, 3, { if (more) { SA(0, 0, t2); SA(0, 2, t2); } },
           if (more) { asm volatile("s_waitcnt vmcnt(6)" ::: "memory"); }
           else      { asm volatile("s_waitcnt vmcnt(0)" ::: "memory"); } )
        PH(1, 0, { DSB(1); if (more) { SA(0, 1, t2); SA(0, 3, t2); } }, )
        PH(1, 1, { if (more) { SB(1, 0, t3); SB(1, 1, t3); } }, )
        PH(1, 2, { if (more) { SB(1, 2, t3); SB(1, 3, t3); } }, )
        PH(1, 3, { if (more) { SA(1, 0, t3); SA(1, 2, t3); } },
           if (more) { asm volatile("s_waitcnt vmcnt(6)" ::: "memory"); } )
    }
#undef PH
#undef DSB

    // ---- epilogue: acc -> LDS (swizzled bf16 [256][256]) -> coalesced flush
    __syncthreads();
    unsigned short* Ct = wm ? &Bs[0][0] : &As[0][0];
    #pragma unroll
    for (int n = 0; n < 4; ++n) {
        const int nn = n0 + wn * 64 + n * 16 + lr;
        const float bias = (nn < Nreal) ? b1[nn] : 0.f;
        const int col = wn * 64 + n * 16 + lr;
        #pragma unroll
        for (int m = 0; m < 8; ++m) {
            #pragma unroll
            for (int r = 0; r < 4; ++r) {
                const int row = m * 16 + quad * 4 + r;
                float v = acc[m][n][r] + bias;
                if (TANH) v = tanhf(v);
                Ct[row * 256 + (((col >> 3) ^ (row & 7)) << 3) + (col & 7)] = f2bf(v);
            }
        }
    }
    __syncthreads();
    #pragma unroll
    for (int it = 0; it < 16; ++it) {
        const int c   = it * 512 + tid;
        const int row = c >> 5;
        const int gc  = c & 31;
        const unsigned short* src = (row < 128)
            ? &As[0][row * 256 + ((gc ^ (row & 7)) << 3)]
            : &Bs[0][(row - 128) * 256 + ((gc ^ (row & 7)) << 3)];
        v8s val = *(const v8s*)src;
        *(v8s*)&Cg[(size_t)(m0 + row) * Npad + n0 + gc * 8] = val;
    }
}

// fp32 -> bf16, 8 elems/thread (n must be multiple of 2048)
__global__ void cvt8(const float* __restrict__ src, unsigned short* __restrict__ dst)
{
    const size_t i = ((size_t)blockIdx.x * 256 + threadIdx.x) * 8;
    float4 f0 = *(const float4*)(src + i);
    float4 f1 = *(const float4*)(src + i + 4);
    unsigned short t8[8];
    t8[0]=f2bf(f0.x); t8[1]=f2bf(f0.y); t8[2]=f2bf(f0.z); t8[3]=f2bf(f0.w);
    t8[4]=f2bf(f1.x); t8[5]=f2bf(f1.y); t8[6]=f2bf(f1.z); t8[7]=f2bf(f1.w);
    *(v8s*)(dst + i) = *(const v8s*)t8;
}

// Wcat[2048][1024] = [Whh | Wih] bf16 (K-dim concat), 8 elems/thread, grid 1024
__global__ void cvt_cat(const float* __restrict__ Whh, const float* __restrict__ Wih,
                        unsigned short* __restrict__ Wcat)
{
    const size_t i = ((size_t)blockIdx.x * 256 + threadIdx.x) * 8;
    const int row = (int)(i >> 10), col = (int)(i & 1023);
    const float* src = (col < 512) ? &Whh[(size_t)row * 512 + col]
                                   : &Wih[(size_t)row * 512 + (col - 512)];
    float4 f0 = *(const float4*)src;
    float4 f1 = *(const float4*)(src + 4);
    unsigned short t8[8];
    t8[0]=f2bf(f0.x); t8[1]=f2bf(f0.y); t8[2]=f2bf(f0.z); t8[3]=f2bf(f0.w);
    t8[4]=f2bf(f1.x); t8[5]=f2bf(f1.y); t8[6]=f2bf(f1.z); t8[7]=f2bf(f1.w);
    *(v8s*)(Wcat + i) = *(const v8s*)t8;
}

// Wa2 (1000x512 fp32) -> zero-padded 1024x512 bf16
__global__ void wa2pad(const float* __restrict__ src, unsigned short* __restrict__ dst)
{
    const int i = blockIdx.x * 256 + threadIdx.x;
    const int row = i >> 9;
    dst[i] = (row < 1000) ? f2bf(src[(size_t)row * 512 + (i & 511)]) : (unsigned short)0;
}

// bsum[2048] = bih+bhh ; bac[1024] = [ba1 ; bc1]   (grid 12 x 256)
__global__ void prep_misc(const float* __restrict__ bih, const float* __restrict__ bhh,
                          const float* __restrict__ ba1, const float* __restrict__ bc1,
                          float* __restrict__ bsum, float* __restrict__ bac)
{
    const int i = blockIdx.x * 256 + threadIdx.x;
    if (i < 2048) bsum[i] = bih[i] + bhh[i];
    else if (i < 3072) {
        int k = i - 2048;
        bac[k] = (k < 512) ? ba1[k] : bc1[k - 512];
    }
}

// masked initial state (bf16) + zero row buffer
__global__ void init_state(const float* __restrict__ h0, const float* __restrict__ c0,
                           const int* __restrict__ done,
                           unsigned short* __restrict__ h_init, unsigned short* __restrict__ c_init,
                           unsigned short* __restrict__ zbuf)
{
    const int b = blockIdx.x;
    const float m = 1.f - (float)done[b];
    for (int k = threadIdx.x; k < 512; k += 256) {
        h_init[(size_t)b * 512 + k] = f2bf(h0[(size_t)b * 512 + k] * m);
        c_init[(size_t)b * 512 + k] = f2bf(c0[(size_t)b * 512 + k] * m);
        if (b == 0) zbuf[k] = 0;
    }
}

// ---------------------------------------------------------------------------
// Segment prep (single WG).
// ---------------------------------------------------------------------------
__global__ __launch_bounds__(256, 1)
void seg_prep(const int* __restrict__ done, int* __restrict__ rows,
              int* __restrict__ counts, int* __restrict__ offs,
              int* __restrict__ trows, int* __restrict__ tcnt, int* __restrict__ toffs,
              int* __restrict__ maxS, int* __restrict__ bar, int T)
{
    __shared__ unsigned int   bits[256][8];
    __shared__ unsigned short cnt[256][S0R];
    __shared__ unsigned short base[256][S0R];
    __shared__ int tot[S0R];
    __shared__ int goff[S0R];
    __shared__ int tcl[NLEV];
    __shared__ int tol[NLEV];
    __shared__ int tpos[NLEV];
    __shared__ int mxl[256];
    const int b = threadIdx.x;
    #pragma unroll
    for (int s = 0; s < S0R; ++s) cnt[b][s] = 0;
    #pragma unroll
    for (int i = 0; i < 8; ++i) bits[b][i] = 0;
    for (int l = b; l < NLEV; l += 256) { tcl[l] = 0; tpos[l] = 0; }
    __syncthreads();

    int s = 0, mx = 0;
    for (int t = 0; t < T; ++t) {
        int d = done[t * 256 + b];
        if (d) bits[b][t >> 5] |= (1u << (t & 31));
        s = (t == 0 || d) ? 0 : s + 1;
        if (s < S0R) cnt[b][s]++;
        else atomicAdd(&tcl[s - S0R], 1);
        mx = mx > s ? mx : s;
    }
    mxl[b] = mx;
    __syncthreads();

    if (b < S0R) {
        int tsum = 0;
        for (int bb = 0; bb < 256; ++bb) { base[bb][b] = (unsigned short)tsum; tsum += cnt[bb][b]; }
        tot[b] = tsum;
    }
    __syncthreads();
    if (b == 0) {
        int run = 0;
        for (int ss = 0; ss < S0R; ++ss) { goff[ss] = run; run += tot[ss]; }
        run = 0;
        for (int l = 0; l < NLEV; ++l) { tol[l] = run; run += tcl[l]; }
        int m = 0;
        for (int bb = 0; bb < 256; ++bb) m = m > mxl[bb] ? m : mxl[bb];
        *maxS = m;
        *bar  = 0;
    }
    __syncthreads();
    if (b < S0R) { counts[b] = tot[b]; offs[b] = goff[b]; }
    for (int l = b; l < NLEV; l += 256) { tcnt[l] = tcl[l]; toffs[l] = tol[l]; }

    s = 0;
    for (int t = 0; t < T; ++t) {
        int d = (bits[b][t >> 5] >> (t & 31)) & 1;
        s = (t == 0 || d) ? 0 : s + 1;
        if (s < S0R) {
            int idx = goff[s] + (int)base[b][s];
            base[b][s]++;
            rows[idx] = t * 256 + b;
        } else {
            int idx = tol[s - S0R] + atomicAdd(&tpos[s - S0R], 1);
            trows[idx] = t * 256 + b;
        }
    }
}

// ---------------------------------------------------------------------------
// Fused LSTM round (s < 12): gates = [h_prev ; h2] @ [Whh|Wih]^T + bsum.
// K=1024 (32 staged k-blocks: 16 from h-source, 16 from H2), 128 gathered
// rows x (4 gates x 32 hidden cols), LDS gate exchange, fused cell update.
// XG buffer eliminated (r3): x-side gates computed in-place, 512 MiB of
// HBM transport + a 196us producer dispatch removed.
// ---------------------------------------------------------------------------
__global__ __launch_bounds__(256)
void lstm_round(const int* __restrict__ rows, const int* __restrict__ counts,
                const int* __restrict__ offs, int s,
                const unsigned short* __restrict__ H2,
                const unsigned short* __restrict__ Wcat,
                const float* __restrict__ bsum,
                const unsigned short* __restrict__ h_init,
                const unsigned short* __restrict__ c_init,
                const unsigned short* __restrict__ zbuf,
                unsigned short* __restrict__ Hraw, unsigned short* __restrict__ Cst)
{
    const int M = counts[s];
    if (M == 0) return;
    const int off    = offs[s];
    const int mtiles = (M + 127) >> 7;

    __shared__ __align__(16) unsigned short As[128 * 32];
    __shared__ __align__(16) unsigned short Bs[128 * 32];
    __shared__ __align__(16) unsigned short Gx[128 * 136];
    __shared__ float bls[128];
    __shared__ int rl[128];

    const int tid  = threadIdx.x;
    const int w    = tid >> 6;
    const int lane = tid & 63;
    const int quad = lane >> 4;
    const int lr   = lane & 15;
    const int wm   = w & 1, wn = w >> 1;
    const int c0   = blockIdx.x * 32;
    const int srow = lane >> 2;
    const int kblk = (lane & 3) ^ ((lane >> 3) & 3);

    if (tid < 128) bls[tid] = bsum[(tid >> 5) * 512 + c0 + (tid & 31)];

    const int br0 = w * 16 + srow;
    const int br1 = 64 + br0;
    const unsigned short* gB0 = Wcat + (size_t)((br0 >> 5) * 512 + c0 + (br0 & 31)) * 1024 + kblk * 8;
    const unsigned short* gB1 = Wcat + (size_t)((br1 >> 5) * 512 + c0 + (br1 & 31)) * 1024 + kblk * 8;
    unsigned short* lA0 = As + (w * 16) * 32;
    unsigned short* lA1 = As + (64 + w * 16) * 32;
    unsigned short* lB0 = Bs + (w * 16) * 32;
    unsigned short* lB1 = Bs + (64 + w * 16) * 32;

    const int swz = (quad ^ ((lr >> 1) & 3)) * 8;
    int aoff[4], boff[4];
    #pragma unroll
    for (int i = 0; i < 4; ++i) {
        aoff[i] = (wm * 64 + i * 16 + lr) * 32 + swz;
        boff[i] = (wn * 64 + i * 16 + lr) * 32 + swz;
    }

    for (int mt = blockIdx.y; mt < mtiles; mt += gridDim.y) {
        __syncthreads();
        if (tid < 128) {
            int li = mt * 128 + tid;
            rl[tid] = (li < M) ? rows[off + li] : -1;
        }
        __syncthreads();

        int g0r = rl[w * 16 + srow];
        int g1r = rl[64 + w * 16 + srow];
        const unsigned short* gA0h;
        const unsigned short* gA1h;
        if (s == 0) {
            gA0h = (g0r >= 0 && g0r < 256) ? h_init + (size_t)g0r * 512 + kblk * 8 : zbuf + kblk * 8;
            gA1h = (g1r >= 0 && g1r < 256) ? h_init + (size_t)g1r * 512 + kblk * 8 : zbuf + kblk * 8;
        } else {
            gA0h = (g0r >= 0) ? Hraw + (size_t)(g0r - 256) * 512 + kblk * 8 : zbuf + kblk * 8;
            gA1h = (g1r >= 0) ? Hraw + (size_t)(g1r - 256) * 512 + kblk * 8 : zbuf + kblk * 8;
        }
        const unsigned short* gA0x = (g0r >= 0) ? H2 + (size_t)g0r * 512 + kblk * 8 : zbuf + kblk * 8;
        const unsigned short* gA1x = (g1r >= 0) ? H2 + (size_t)g1r * 512 + kblk * 8 : zbuf + kblk * 8;

        v4f zz = {0.f, 0.f, 0.f, 0.f};
        v4f acc[4][4] = {{zz,zz,zz,zz},{zz,zz,zz,zz},{zz,zz,zz,zz},{zz,zz,zz,zz}};

        for (int k = 0; k < 32; ++k) {
            __syncthreads();
            const unsigned short* a0 = (k < 16) ? gA0h + k * 32 : gA0x + (k - 16) * 32;
            const unsigned short* a1 = (k < 16) ? gA1h + k * 32 : gA1x + (k - 16) * 32;
            gld_lds16(a0, lA0);
            gld_lds16(a1, lA1);
            gld_lds16(gB0 + k * 32, lB0);
            gld_lds16(gB1 + k * 32, lB1);
            __syncthreads();
            v8s a[4], b[4];
            #pragma unroll
            for (int i = 0; i < 4; ++i) { a[i] = *(const v8s*)&As[aoff[i]]; b[i] = *(const v8s*)&Bs[boff[i]]; }
            #pragma unroll
            for (int i = 0; i < 4; ++i)
                #pragma unroll
                for (int j = 0; j < 4; ++j)
                    acc[i][j] = __builtin_amdgcn_mfma_f32_16x16x32_bf16(a[i], b[j], acc[i][j], 0, 0, 0);
        }

        #pragma unroll
        for (int j = 0; j < 4; ++j) {
            const int nl = wn * 64 + j * 16 + lr;
            #pragma unroll
            for (int i = 0; i < 4; ++i)
                #pragma unroll
                for (int r = 0; r < 4; ++r)
                    Gx[(wm * 64 + i * 16 + quad * 4 + r) * 136 + nl] = f2bf(acc[i][j][r]);
        }
        __syncthreads();

        {
            const int rloc = tid >> 1;
            const int half = tid & 1;
            const int gr   = rl[rloc];
            if (gr >= 0) {
                #pragma unroll
                for (int ch = 0; ch < 2; ++ch) {
                    const int co = half * 16 + ch * 8;
                    const int kg = c0 + co;
                    v8s q0 = *(const v8s*)&Gx[rloc * 136 +   0 + co];
                    v8s q1 = *(const v8s*)&Gx[rloc * 136 +  32 + co];
                    v8s q2 = *(const v8s*)&Gx[rloc * 136 +  64 + co];
                    v8s q3 = *(const v8s*)&Gx[rloc * 136 +  96 + co];
                    float cprev[8];
                    if (s == 0) {
                        if (gr < 256) {
                            v8s cv = *(const v8s*)&c_init[(size_t)gr * 512 + kg];
                            #pragma unroll
                            for (int e = 0; e < 8; ++e) cprev[e] = bf2f((unsigned short)cv[e]);
                        } else {
                            #pragma unroll
                            for (int e = 0; e < 8; ++e) cprev[e] = 0.f;
                        }
                    } else {
                        v8s cv = *(const v8s*)&Cst[(size_t)(gr - 256) * 512 + kg];
                        #pragma unroll
                        for (int e = 0; e < 8; ++e) cprev[e] = bf2f((unsigned short)cv[e]);
                    }
                    unsigned short hc[8], cc[8];
                    #pragma unroll
                    for (int e = 0; e < 8; ++e) {
                        float gi = bf2f((unsigned short)q0[e]) + bls[ 0 + co + e];
                        float gf = bf2f((unsigned short)q1[e]) + bls[32 + co + e];
                        float gg = bf2f((unsigned short)q2[e]) + bls[64 + co + e];
                        float go = bf2f((unsigned short)q3[e]) + bls[96 + co + e];
                        float c  = sigmoidf_(gf) * cprev[e] + sigmoidf_(gi) * tanhf(gg);
                        float h  = sigmoidf_(go) * tanhf(c);
                        cc[e] = f2bf(c);
                        hc[e] = f2bf(h);
                    }
                    *(v8s*)&Cst[(size_t)gr * 512 + kg]  = *(const v8s*)cc;
                    *(v8s*)&Hraw[(size_t)gr * 512 + kg] = *(const v8s*)hc;
                }
            }
        }
    }
}

// ---------------------------------------------------------------------------
// Tail (s >= 12): 64 WGs, resident [Whh|Wih] slice (32 rows x 1024 = 64 KB),
// K=1024 over [h_prev ; h2]; device-scope spin barrier between levels.
// ---------------------------------------------------------------------------
__global__ __launch_bounds__(256, 1)
void lstm_tail(const int* __restrict__ trows, const int* __restrict__ tcnt,
               const int* __restrict__ toffs, const int* __restrict__ maxS_p,
               const unsigned short* __restrict__ H2,
               const unsigned short* __restrict__ Wcat,
               const float* __restrict__ bsum,
               unsigned short* __restrict__ Hraw, unsigned short* __restrict__ Cst,
               int* __restrict__ bar)
{
    const int mS = *maxS_p;
    if (mS < S0R) return;
    __shared__ __align__(16) unsigned short Wl[32 * 1024];   // 64 KB
    __shared__ __align__(16) unsigned short Hb[16 * 1024];   // 32 KB
    __shared__ float Gb[16 * 32];
    __shared__ float bl[32];
    __shared__ int rl[16];
    const int j    = blockIdx.x;
    const int tid  = threadIdx.x;
    const int w    = tid >> 6;
    const int lane = tid & 63;
    const int quad = lane >> 4;
    const int lr   = lane & 15;

    if (tid < 32) bl[tid] = bsum[(tid >> 3) * 512 + j * 8 + (tid & 7)];

    // resident Wcat slice: Wl row n = g*8+c <- Wcat row g*512 + j*8 + c (1024 cols)
    for (int e = tid; e < 32 * 128; e += 256) {
        int n = e >> 7, kb = e & 127;
        int g = n >> 3, c = n & 7;
        *(v8s*)&Wl[n * 1024 + kb * 8] = *(const v8s*)&Wcat[(size_t)(g * 512 + j * 8 + c) * 1024 + kb * 8];
    }

    int target = 0;
    for (int s = S0R; s <= mS; ++s) {
        const int lev = s - S0R;
        const int M   = tcnt[lev];
        const int off = toffs[lev];
        for (int ch = 0; ch < M; ch += 16) {
            __syncthreads();
            if (tid < 16) rl[tid] = (ch + tid < M) ? trows[off + ch + tid] : -1;
            __syncthreads();
            {   // stage [h_prev ; h2] rows
                int r = tid >> 4, seg = (tid & 15) * 32;
                int gr = rl[r];
                if (gr >= 0) {
                    const unsigned short* srcH = &Hraw[(size_t)(gr - 256) * 512 + seg];
                    const unsigned short* srcX = &H2[(size_t)gr * 512 + seg];
                    #pragma unroll
                    for (int q = 0; q < 4; ++q) {
                        *(v8s*)&Hb[r * 1024 + seg + q * 8]       = *(const v8s*)(srcH + q * 8);
                        *(v8s*)&Hb[r * 1024 + 512 + seg + q * 8] = *(const v8s*)(srcX + q * 8);
                    }
                } else {
                    v8s z = {0,0,0,0,0,0,0,0};
                    #pragma unroll
                    for (int q = 0; q < 4; ++q) {
                        *(v8s*)&Hb[r * 1024 + seg + q * 8]       = z;
                        *(v8s*)&Hb[r * 1024 + 512 + seg + q * 8] = z;
                    }
                }
            }
            __syncthreads();
            if (w < 2) {
                v4f acc = {0.f, 0.f, 0.f, 0.f};
                for (int k = 0; k < 32; ++k) {
                    v8s a = *(const v8s*)&Hb[lr * 1024 + k * 32 + quad * 8];
                    v8s b = *(const v8s*)&Wl[(w * 16 + lr) * 1024 + k * 32 + quad * 8];
                    acc = __builtin_amdgcn_mfma_f32_16x16x32_bf16(a, b, acc, 0, 0, 0);
                }
                #pragma unroll
                for (int r = 0; r < 4; ++r)
                    Gb[(quad * 4 + r) * 32 + w * 16 + lr] = acc[r];
            }
            __syncthreads();
            if (tid < 128) {
                int r = tid >> 3, c = tid & 7;
                int gr = rl[r];
                if (gr >= 0) {
                    int k = j * 8 + c;
                    float gi = Gb[r * 32 +  0 + c] + bl[ 0 + c];
                    float gf = Gb[r * 32 +  8 + c] + bl[ 8 + c];
                    float gg = Gb[r * 32 + 16 + c] + bl[16 + c];
                    float go = Gb[r * 32 + 24 + c] + bl[24 + c];
                    float cp = bf2f(Cst[(size_t)(gr - 256) * 512 + k]);
                    float cc = sigmoidf_(gf) * cp + sigmoidf_(gi) * tanhf(gg);
                    float hh = sigmoidf_(go) * tanhf(cc);
                    Cst[(size_t)gr * 512 + k]  = f2bf(cc);
                    Hraw[(size_t)gr * 512 + k] = f2bf(hh);
                }
            }
        }
        target += 64;
        __threadfence();
        __syncthreads();
        if (tid == 0) {
            __hip_atomic_fetch_add(bar, 1, __ATOMIC_RELEASE, __HIP_MEMORY_SCOPE_AGENT);
            while (__hip_atomic_load(bar, __ATOMIC_ACQUIRE, __HIP_MEMORY_SCOPE_AGENT) < target) {}
        }
        __syncthreads();
        __threadfence();
    }
}

// Hraw += H2 in place (-> new_hidden), 8 elems/thread
__global__ void nh_add(unsigned short* __restrict__ H, const unsigned short* __restrict__ H2)
{
    const size_t i = ((size_t)blockIdx.x * 256 + threadIdx.x) * 8;
    v8s a = *(const v8s*)(H + i);
    v8s b = *(const v8s*)(H2 + i);
    unsigned short t8[8];
    #pragma unroll
    for (int e = 0; e < 8; ++e)
        t8[e] = f2bf(bf2f((unsigned short)a[e]) + bf2f((unsigned short)b[e]));
    *(v8s*)(H + i) = *(const v8s*)t8;
}

// actor head: one wave per row over bf16 logits (stride 1024, 1000 valid)
__global__ void head_reduce(const unsigned short* __restrict__ logits,
                            const int* __restrict__ action,
                            float* __restrict__ out, int TB)
{
    const int r = blockIdx.x * 4 + (threadIdx.x >> 6);
    const int lane = threadIdx.x & 63;
    const unsigned short* row = logits + (size_t)r * 1024;
    float m = -1e30f, Z = 0.f, S = 0.f;
    v8s v0 = *(const v8s*)&row[lane * 8];
    #pragma unroll
    for (int e = 0; e < 8; ++e) {
        float xv = bf2f((unsigned short)v0[e]);
        if (xv > m) { float sc = expf(m - xv); Z *= sc; S *= sc; m = xv; }
        float ev = expf(xv - m);
        Z += ev; S += xv * ev;
    }
    v8s v1 = *(const v8s*)&row[512 + lane * 8];
    #pragma unroll
    for (int e = 0; e < 8; ++e) {
        int c = 512 + lane * 8 + e;
        if (c < 1000) {
            float xv = bf2f((unsigned short)v1[e]);
            if (xv > m) { float sc = expf(m - xv); Z *= sc; S *= sc; m = xv; }
            float ev = expf(xv - m);
            Z += ev; S += xv * ev;
        }
    }
    #pragma unroll
    for (int offb = 32; offb > 0; offb >>= 1) {
        float m2 = __shfl_xor(m, offb);
        float Z2 = __shfl_xor(Z, offb);
        float S2 = __shfl_xor(S, offb);
        float M  = fmaxf(m, m2);
        float s1 = expf(m - M), s2 = expf(m2 - M);
        Z = Z * s1 + Z2 * s2;
        S = S * s1 + S2 * s2;
        m = M;
    }
    if (lane == 0) {
        float lse = m + logf(Z);
        float xa  = bf2f(row[action[r]]);
        out[r]      = xa - lse;
        out[TB + r] = lse - S / Z;
    }
}

// critic head over fused AC1 (stride 1024, critic half at +512)
__global__ void critic_v(const unsigned short* __restrict__ AC, const float* __restrict__ Wc2,
                         const float* __restrict__ bc2, float* __restrict__ out, int TB)
{
    const int r = blockIdx.x * 4 + (threadIdx.x >> 6);
    const int lane = threadIdx.x & 63;
    const unsigned short* row = AC + (size_t)r * 1024 + 512;
    v8s hv = *(const v8s*)&row[lane * 8];
    float4 w0 = *(const float4*)&Wc2[lane * 8];
    float4 w1 = *(const float4*)&Wc2[lane * 8 + 4];
    float s = bf2f((unsigned short)hv[0]) * w0.x + bf2f((unsigned short)hv[1]) * w0.y +
              bf2f((unsigned short)hv[2]) * w0.z + bf2f((unsigned short)hv[3]) * w0.w +
              bf2f((unsigned short)hv[4]) * w1.x + bf2f((unsigned short)hv[5]) * w1.y +
              bf2f((unsigned short)hv[6]) * w1.z + bf2f((unsigned short)hv[7]) * w1.w;
    #pragma unroll
    for (int offb = 32; offb > 0; offb >>= 1) s += __shfl_xor(s, offb);
    if (lane == 0) out[2 * TB + r] = s + bc2[0];
}

extern "C" void kernel_launch(void* const* d_in, const int* in_sizes, int n_in,
                              void* d_out, int out_size, void* d_ws, size_t ws_size,
                              hipStream_t stream)
{
    const float* x    = (const float*)d_in[0];
    const int*  done  = (const int*)d_in[1];
    const int*  action= (const int*)d_in[2];
    const float* W_t1 = (const float*)d_in[4];
    const float* b_t1 = (const float*)d_in[5];
    const float* W_t2 = (const float*)d_in[6];
    const float* b_t2 = (const float*)d_in[7];
    const float* Wih  = (const float*)d_in[8];
    const float* Whh  = (const float*)d_in[9];
    const float* bih  = (const float*)d_in[10];
    const float* bhh  = (const float*)d_in[11];
    const float* Wa1  = (const float*)d_in[12];
    const float* ba1  = (const float*)d_in[13];
    const float* Wa2  = (const float*)d_in[14];
    const float* ba2  = (const float*)d_in[15];
    const float* Wc1  = (const float*)d_in[16];
    const float* bc1  = (const float*)d_in[17];
    const float* Wc2  = (const float*)d_in[18];
    const float* bc2  = (const float*)d_in[19];
    const float* h0   = (const float*)d_in[20];
    const float* c0   = (const float*)d_in[21];
    float* out = (float*)d_out;

    const int TB = in_sizes[1];      // 65536
    const int T  = TB / 256;         // 256

    const size_t MiB = 1024 * 1024;
    char* ws = (char*)d_ws;
    unsigned short* H1     = (unsigned short*)(ws);               // 64 MiB
    unsigned short* logits = (unsigned short*)(ws);               // 128 MiB (alias H1)
    unsigned short* AC1    = (unsigned short*)(ws + 128 * MiB);   // 128 MiB
    unsigned short* Cst    = (unsigned short*)(ws + 256 * MiB);   // 64 MiB
    unsigned short* H2     = (unsigned short*)(ws + 320 * MiB);   // 64 MiB
    unsigned short* Hraw   = (unsigned short*)(ws + 384 * MiB);   // 64 MiB
    unsigned short* xbf    = Hraw;                                 // alias (x dead after trunk1)
    unsigned short* Wt1b   = (unsigned short*)(ws + 448 * MiB);
    unsigned short* Wt2b   = Wt1b + 512 * 512;
    unsigned short* Wcat   = Wt2b + 512 * 512;                     // 2048 x 1024
    unsigned short* Wacb   = Wcat + 2048 * 1024;                   // 1024 x 512
    unsigned short* Wa2b   = Wacb + 1024 * 512;                    // 1024 x 512
    unsigned short* h_init = Wa2b + 1024 * 512;
    unsigned short* c_init = h_init + 256 * 512;
    unsigned short* zbuf   = c_init + 256 * 512;
    int* rows   = (int*)(zbuf + 512);
    int* trows  = rows + 65536;
    int* counts = trows + 65536;
    int* offs   = counts + S0R;
    int* tcnt   = offs + S0R;
    int* toffs  = tcnt + NLEV;
    int* maxS   = toffs + NLEV;
    int* bar    = maxS + 1;
    float* bsum = (float*)(bar + 1);          // 2048 f32
    float* bac  = bsum + 2048;                // 1024 f32

    dim3 blk(256);
    dim3 blk5(512);

    // dtype conversions + weight packing + init + segment lists
    cvt8<<<16384, blk, 0, stream>>>(x, xbf);
    cvt8<<<128,  blk, 0, stream>>>(W_t1, Wt1b);
    cvt8<<<128,  blk, 0, stream>>>(W_t2, Wt2b);
    cvt_cat<<<1024, blk, 0, stream>>>(Whh, Wih, Wcat);
    cvt8<<<128,  blk, 0, stream>>>(Wa1, Wacb);
    cvt8<<<128,  blk, 0, stream>>>(Wc1, Wacb + 512 * 512);
    wa2pad<<<2048, blk, 0, stream>>>(Wa2, Wa2b);
    prep_misc<<<12, blk, 0, stream>>>(bih, bhh, ba1, bc1, bsum, bac);
    init_state<<<256, blk, 0, stream>>>(h0, c0, done, h_init, c_init, zbuf);
    seg_prep<<<1, blk, 0, stream>>>(done, rows, counts, offs, trows, tcnt, toffs, maxS, bar, T);

    // trunk
    gemm256<true ><<<512, blk5, 0, stream>>>(xbf, Wt1b, b_t1, H1, 512, 512, 2, 512);
    gemm256<true ><<<512, blk5, 0, stream>>>(H1,  Wt2b, b_t2, H2, 512, 512, 2, 512);

    // segment-parallel LSTM, x-gates fused (K=1024)
    static const int Gs[S0R] = {256, 128, 64, 32, 16, 8, 4, 2, 1, 1, 1, 1};
    for (int s = 0; s < S0R; ++s)
        lstm_round<<<dim3(16, Gs[s]), blk, 0, stream>>>(rows, counts, offs, s, H2, Wcat, bsum,
                                                        h_init, c_init, zbuf, Hraw, Cst);
    lstm_tail<<<64, blk, 0, stream>>>(trows, tcnt, toffs, maxS, H2, Wcat, bsum, Hraw, Cst, bar);

    // residual: Hraw <- Hraw + H2 (= new_hidden)
    nh_add<<<16384, blk, 0, stream>>>(Hraw, H2);

    // fused actor/critic first layers: AC1 = tanh(new_hidden @ [Wa1;Wc1]^T + [ba1;bc1])
    gemm256<true ><<<1024, blk5, 0, stream>>>(Hraw, Wacb, bac, AC1, 1024, 1024, 4, 512);

    // actor logits from A1 half (stride-1024 A)
    gemm256<false><<<1024, blk5, 0, stream>>>(AC1, Wa2b, ba2, logits, 1000, 1024, 4, 1024);
    head_reduce<<<TB / 4, blk, 0, stream>>>(logits, action, out, TB);

    // critic from C1 half
    critic_v<<<TB / 4, blk, 0, stream>>>(AC1, Wc2, bc2, out, TB);
}

// Round 4
// 1369.626 us; speedup vs baseline: 1.3753x; 1.1875x over previous
//
#include <hip/hip_runtime.h>
#include <hip/hip_bf16.h>

typedef short v8s __attribute__((ext_vector_type(8)));
typedef float v4f __attribute__((ext_vector_type(4)));

#define S0R 12      // rounds 0..11 via gather-GEMM; lstm_tail covers s >= 12
#define NLEV 244    // tail levels 12..255
#define L2E 1.4426950408889634f

__device__ __forceinline__ float bf2f(unsigned short u) {
    union { unsigned int i; float f; } v; v.i = ((unsigned int)u) << 16; return v.f;
}
__device__ __forceinline__ unsigned short f2bf(float f) {
    union { float f; unsigned int i; } v; v.f = f;
    unsigned int x = v.i;
    return (unsigned short)((x + 0x7fffu + ((x >> 16) & 1u)) >> 16);
}
// fast sigmoid/tanh: v_exp_f32 + v_rcp_f32 (1-2 ulp; invisible under bf16)
__device__ __forceinline__ float fsig(float x) {
    return __builtin_amdgcn_rcpf(1.f + __builtin_amdgcn_exp2f(-L2E * x));
}
__device__ __forceinline__ float ftanh(float x) {
    return 2.f * __builtin_amdgcn_rcpf(1.f + __builtin_amdgcn_exp2f((-2.f * L2E) * x)) - 1.f;
}

// async global->LDS, 16B per lane; LDS dst is wave-uniform base + lane*16
__device__ __forceinline__ void gld_lds16(const unsigned short* g, unsigned short* l) {
    __builtin_amdgcn_global_load_lds(
        (const __attribute__((address_space(1))) unsigned int*)g,
        (__attribute__((address_space(3))) unsigned int*)l, 16, 0, 0);
}

// ---------------------------------------------------------------------------
// gemm256: C[M,Npad] = act(A[.,Astr][:512] @ W[Npad,512]^T + b1), bf16.
// 256x256 tile, BK=64, 8 waves, 8-phase counted-vmcnt schedule, XOR-swizzled
// LDS, setprio, XCD-chunked swizzle.  Epilogue via LDS -> coalesced stores.
// ---------------------------------------------------------------------------
template <bool TANH>
__global__ __launch_bounds__(512, 2)
void gemm256(const unsigned short* __restrict__ Ag, const unsigned short* __restrict__ Wg,
             const float* __restrict__ b1,
             unsigned short* __restrict__ Cg, int Nreal, int Npad, int Ntiles, int Astr)
{
    __shared__ __align__(16) unsigned short As[2][256 * 64];   // 64 KB
    __shared__ __align__(16) unsigned short Bs[2][256 * 64];   // 64 KB

    const int tid  = threadIdx.x;
    const int w    = tid >> 6;          // 0..7
    const int lane = tid & 63;
    const int quad = lane >> 4;
    const int lr   = lane & 15;
    const int wm   = w >> 2;            // 0..1
    const int wn   = w & 3;             // 0..3

    const int nwg = gridDim.x;
    const int cpx = nwg >> 3;
    const int swz = (blockIdx.x & 7) * cpx + (blockIdx.x >> 3);
    const int m0  = (swz / Ntiles) * 256;
    const int n0  = (swz % Ntiles) * 256;

    const unsigned short* gA = Ag + (size_t)m0 * Astr;
    const unsigned short* gB = Wg + (size_t)n0 * 512;

    const int sr  = w * 8 + (lane >> 3);
    const int skg = (lane & 7) ^ ((lane >> 3) & 7);

    auto SA = [&](int buf, int u, int kt) {
        gld_lds16(gA + (size_t)(u * 64 + sr) * Astr + kt * 64 + skg * 8,
                  &As[buf][(u * 64 + w * 8) * 64]);
    };
    auto SB = [&](int buf, int u, int kt) {
        gld_lds16(gB + (size_t)(u * 64 + sr) * 512 + kt * 64 + skg * 8,
                  &Bs[buf][(u * 64 + w * 8) * 64]);
    };

    const int g8_0  = (quad ^ (lr & 7)) * 8;
    const int g8_1  = ((quad + 4) ^ (lr & 7)) * 8;
    const int aBase = (wm * 128 + lr) * 64;
    const int bBase = (wn * 64 + lr) * 64;

    v4f zz = {0.f, 0.f, 0.f, 0.f};
    v4f acc[8][4];
    #pragma unroll
    for (int m = 0; m < 8; ++m)
        #pragma unroll
        for (int n = 0; n < 4; ++n) acc[m][n] = zz;
    v8s Bf[4][2];

#define DSB(BUF)                                                         \
    _Pragma("unroll")                                                    \
    for (int n = 0; n < 4; ++n) {                                        \
        Bf[n][0] = *(const v8s*)&Bs[BUF][bBase + n * 1024 + g8_0];       \
        Bf[n][1] = *(const v8s*)&Bs[BUF][bBase + n * 1024 + g8_1];       \
    }

#define PH(BUF, Q, STMTS, PREBAR)                                                     \
    {                                                                                 \
        const v8s a00 = *(const v8s*)&As[BUF][aBase + ((Q)*2 + 0) * 1024 + g8_0];     \
        const v8s a01 = *(const v8s*)&As[BUF][aBase + ((Q)*2 + 0) * 1024 + g8_1];     \
        const v8s a10 = *(const v8s*)&As[BUF][aBase + ((Q)*2 + 1) * 1024 + g8_0];     \
        const v8s a11 = *(const v8s*)&As[BUF][aBase + ((Q)*2 + 1) * 1024 + g8_1];     \
        STMTS;                                                                        \
        PREBAR;                                                                       \
        __builtin_amdgcn_s_barrier();                                                 \
        asm volatile("s_waitcnt lgkmcnt(0)" ::: "memory");                            \
        __builtin_amdgcn_sched_barrier(0);                                            \
        __builtin_amdgcn_s_setprio(1);                                                \
        _Pragma("unroll")                                                             \
        for (int n = 0; n < 4; ++n) {                                                 \
            acc[(Q)*2    ][n] = __builtin_amdgcn_mfma_f32_16x16x32_bf16(a00, Bf[n][0], acc[(Q)*2    ][n], 0, 0, 0); \
            acc[(Q)*2    ][n] = __builtin_amdgcn_mfma_f32_16x16x32_bf16(a01, Bf[n][1], acc[(Q)*2    ][n], 0, 0, 0); \
            acc[(Q)*2 + 1][n] = __builtin_amdgcn_mfma_f32_16x16x32_bf16(a10, Bf[n][0], acc[(Q)*2 + 1][n], 0, 0, 0); \
            acc[(Q)*2 + 1][n] = __builtin_amdgcn_mfma_f32_16x16x32_bf16(a11, Bf[n][1], acc[(Q)*2 + 1][n], 0, 0, 0); \
        }                                                                             \
        __builtin_amdgcn_s_setprio(0);                                                \
        __builtin_amdgcn_s_barrier();                                                 \
    }

    SB(0, 0, 0); SB(0, 1, 0); SB(0, 2, 0); SB(0, 3, 0);
    SA(0, 0, 0); SA(0, 2, 0); SA(0, 1, 0); SA(0, 3, 0);
    SB(1, 0, 1); SB(1, 1, 1); SB(1, 2, 1); SB(1, 3, 1);
    SA(1, 0, 1); SA(1, 2, 1);
    asm volatile("s_waitcnt vmcnt(6)" ::: "memory");
    __builtin_amdgcn_s_barrier();

    #pragma unroll
    for (int i = 0; i < 4; ++i) {                 // 2 K-tiles / iteration
        const bool more = (i < 3);
        const int t1 = 2 * i + 1, t2 = 2 * i + 2, t3 = 2 * i + 3;
        PH(0, 0, { DSB(0); SA(1, 1, t1); SA(1, 3, t1); }, )
        PH(0, 1, { if (more) { SB(0, 0, t2); SB(0, 1, t2); } }, )
        PH(0, 2, { if (more) { SB(0, 2, t2); SB(0, 3, t2); } }, )
        PH(0, 3, { if (more) { SA(0, 0, t2); SA(0, 2, t2); } },
           if (more) { asm volatile("s_waitcnt vmcnt(6)" ::: "memory"); }
           else      { asm volatile("s_waitcnt vmcnt(0)" ::: "memory"); } )
        PH(1, 0, { DSB(1); if (more) { SA(0, 1, t2); SA(0, 3, t2); } }, )
        PH(1, 1, { if (more) { SB(1, 0, t3); SB(1, 1, t3); } }, )
        PH(1, 2, { if (more) { SB(1, 2, t3); SB(1, 3, t3); } }, )
        PH(1, 3, { if (more) { SA(1, 0, t3); SA(1, 2, t3); } },
           if (more) { asm volatile("s_waitcnt vmcnt(6)" ::: "memory"); } )
    }
#undef PH
#undef DSB

    // ---- epilogue: acc -> LDS (swizzled bf16 [256][256]) -> coalesced flush
    __syncthreads();
    unsigned short* Ct = wm ? &Bs[0][0] : &As[0][0];
    #pragma unroll
    for (int n = 0; n < 4; ++n) {
        const int nn = n0 + wn * 64 + n * 16 + lr;
        const float bias = (nn < Nreal) ? b1[nn] : 0.f;
        const int col = wn * 64 + n * 16 + lr;
        #pragma unroll
        for (int m = 0; m < 8; ++m) {
            #pragma unroll
            for (int r = 0; r < 4; ++r) {
                const int row = m * 16 + quad * 4 + r;
                float v = acc[m][n][r] + bias;
                if (TANH) v = ftanh(v);
                Ct[row * 256 + (((col >> 3) ^ (row & 7)) << 3) + (col & 7)] = f2bf(v);
            }
        }
    }
    __syncthreads();
    #pragma unroll
    for (int it = 0; it < 16; ++it) {
        const int c   = it * 512 + tid;
        const int row = c >> 5;
        const int gc  = c & 31;
        const unsigned short* src = (row < 128)
            ? &As[0][row * 256 + ((gc ^ (row & 7)) << 3)]
            : &Bs[0][(row - 128) * 256 + ((gc ^ (row & 7)) << 3)];
        v8s val = *(const v8s*)src;
        *(v8s*)&Cg[(size_t)(m0 + row) * Npad + n0 + gc * 8] = val;
    }
}

// fp32 -> bf16, 8 elems/thread (n must be multiple of 2048)
__global__ void cvt8(const float* __restrict__ src, unsigned short* __restrict__ dst)
{
    const size_t i = ((size_t)blockIdx.x * 256 + threadIdx.x) * 8;
    float4 f0 = *(const float4*)(src + i);
    float4 f1 = *(const float4*)(src + i + 4);
    unsigned short t8[8];
    t8[0]=f2bf(f0.x); t8[1]=f2bf(f0.y); t8[2]=f2bf(f0.z); t8[3]=f2bf(f0.w);
    t8[4]=f2bf(f1.x); t8[5]=f2bf(f1.y); t8[6]=f2bf(f1.z); t8[7]=f2bf(f1.w);
    *(v8s*)(dst + i) = *(const v8s*)t8;
}

// Wcat[2048][1024] = [Whh | Wih] bf16 (K-dim concat), 8 elems/thread, grid 1024
__global__ void cvt_cat(const float* __restrict__ Whh, const float* __restrict__ Wih,
                        unsigned short* __restrict__ Wcat)
{
    const size_t i = ((size_t)blockIdx.x * 256 + threadIdx.x) * 8;
    const int row = (int)(i >> 10), col = (int)(i & 1023);
    const float* src = (col < 512) ? &Whh[(size_t)row * 512 + col]
                                   : &Wih[(size_t)row * 512 + (col - 512)];
    float4 f0 = *(const float4*)src;
    float4 f1 = *(const float4*)(src + 4);
    unsigned short t8[8];
    t8[0]=f2bf(f0.x); t8[1]=f2bf(f0.y); t8[2]=f2bf(f0.z); t8[3]=f2bf(f0.w);
    t8[4]=f2bf(f1.x); t8[5]=f2bf(f1.y); t8[6]=f2bf(f1.z); t8[7]=f2bf(f1.w);
    *(v8s*)(Wcat + i) = *(const v8s*)t8;
}

// Wa2 (1000x512 fp32) -> zero-padded 1024x512 bf16
__global__ void wa2pad(const float* __restrict__ src, unsigned short* __restrict__ dst)
{
    const int i = blockIdx.x * 256 + threadIdx.x;
    const int row = i >> 9;
    dst[i] = (row < 1000) ? f2bf(src[(size_t)row * 512 + (i & 511)]) : (unsigned short)0;
}

// bsum[2048] = bih+bhh ; bac[1024] = [ba1 ; bc1]   (grid 12 x 256)
__global__ void prep_misc(const float* __restrict__ bih, const float* __restrict__ bhh,
                          const float* __restrict__ ba1, const float* __restrict__ bc1,
                          float* __restrict__ bsum, float* __restrict__ bac)
{
    const int i = blockIdx.x * 256 + threadIdx.x;
    if (i < 2048) bsum[i] = bih[i] + bhh[i];
    else if (i < 3072) {
        int k = i - 2048;
        bac[k] = (k < 512) ? ba1[k] : bc1[k - 512];
    }
}

// masked initial state (bf16) + zero row buffer
__global__ void init_state(const float* __restrict__ h0, const float* __restrict__ c0,
                           const int* __restrict__ done,
                           unsigned short* __restrict__ h_init, unsigned short* __restrict__ c_init,
                           unsigned short* __restrict__ zbuf)
{
    const int b = blockIdx.x;
    const float m = 1.f - (float)done[b];
    for (int k = threadIdx.x; k < 512; k += 256) {
        h_init[(size_t)b * 512 + k] = f2bf(h0[(size_t)b * 512 + k] * m);
        c_init[(size_t)b * 512 + k] = f2bf(c0[(size_t)b * 512 + k] * m);
        if (b == 0) zbuf[k] = 0;
    }
}

// ---------------------------------------------------------------------------
// Segment prep (single WG).  r4: 8x-unrolled done loads (independent-load
// pipelining); s=0 list reordered so the 256 t=0 rows come FIRST -> round 0
// tiles with mt*128>=256 are pure reset rows (h_prev==0) and skip the h-part
// of the K loop entirely.
// ---------------------------------------------------------------------------
__global__ __launch_bounds__(256, 1)
void seg_prep(const int* __restrict__ done, int* __restrict__ rows,
              int* __restrict__ counts, int* __restrict__ offs,
              int* __restrict__ trows, int* __restrict__ tcnt, int* __restrict__ toffs,
              int* __restrict__ maxS, int* __restrict__ bar, int T)
{
    __shared__ unsigned int   bits[256][8];
    __shared__ unsigned short cnt[256][S0R];
    __shared__ unsigned short base[256][S0R];
    __shared__ int tot[S0R];
    __shared__ int goff[S0R];
    __shared__ int tcl[NLEV];
    __shared__ int tol[NLEV];
    __shared__ int tpos[NLEV];
    __shared__ int mxl[256];
    const int b = threadIdx.x;
    #pragma unroll
    for (int s = 0; s < S0R; ++s) cnt[b][s] = 0;
    #pragma unroll
    for (int i = 0; i < 8; ++i) bits[b][i] = 0;
    for (int l = b; l < NLEV; l += 256) { tcl[l] = 0; tpos[l] = 0; }
    __syncthreads();

    int s = 0, mx = 0;
    for (int t0 = 0; t0 < T; t0 += 8) {
        int d8[8];
        #pragma unroll
        for (int i = 0; i < 8; ++i) d8[i] = done[(t0 + i) * 256 + b];
        #pragma unroll
        for (int i = 0; i < 8; ++i) {
            const int t = t0 + i, d = d8[i];
            if (d) bits[b][t >> 5] |= (1u << (t & 31));
            s = (t == 0 || d) ? 0 : s + 1;
            if (s < S0R) { if (t != 0) cnt[b][s]++; }   // t=0 rows reserved
            else atomicAdd(&tcl[s - S0R], 1);
            mx = mx > s ? mx : s;
        }
    }
    mxl[b] = mx;
    __syncthreads();

    if (b < S0R) {
        int tsum = 0;
        for (int bb = 0; bb < 256; ++bb) { base[bb][b] = (unsigned short)tsum; tsum += cnt[bb][b]; }
        tot[b] = tsum;
    }
    __syncthreads();
    if (b == 0) {
        int run = 256;                               // [0,256) = t=0 rows
        for (int ss = 0; ss < S0R; ++ss) { goff[ss] = run; run += tot[ss]; }
        run = 0;
        for (int l = 0; l < NLEV; ++l) { tol[l] = run; run += tcl[l]; }
        int m = 0;
        for (int bb = 0; bb < 256; ++bb) m = m > mxl[bb] ? m : mxl[bb];
        *maxS = m;
        *bar  = 0;
    }
    __syncthreads();
    if (b < S0R) {
        counts[b] = tot[b] + (b == 0 ? 256 : 0);
        offs[b]   = (b == 0) ? 0 : goff[b];
    }
    for (int l = b; l < NLEV; l += 256) { tcnt[l] = tcl[l]; toffs[l] = tol[l]; }

    s = 0;
    for (int t = 0; t < T; ++t) {
        int d = (bits[b][t >> 5] >> (t & 31)) & 1;
        s = (t == 0 || d) ? 0 : s + 1;
        if (t == 0) {
            rows[b] = b;                             // t=0 row of env b
        } else if (s < S0R) {
            int idx = goff[s] + (int)base[b][s];
            base[b][s]++;
            rows[idx] = t * 256 + b;
        } else {
            int idx = tol[s - S0R] + atomicAdd(&tpos[s - S0R], 1);
            trows[idx] = t * 256 + b;
        }
    }
}

// ---------------------------------------------------------------------------
// Fused LSTM round (s < 12): gates = [h_prev ; h2] @ [Whh|Wih]^T + bsum.
// K=1024; round 0 reset-row tiles skip the h-half (kbeg=16).  Epilogue also
// writes Hnew = h + h2 (residual fused; nh_add pass eliminated).
// ---------------------------------------------------------------------------
__global__ __launch_bounds__(256)
void lstm_round(const int* __restrict__ rows, const int* __restrict__ counts,
                const int* __restrict__ offs, int s,
                const unsigned short* __restrict__ H2,
                const unsigned short* __restrict__ Wcat,
                const float* __restrict__ bsum,
                const unsigned short* __restrict__ h_init,
                const unsigned short* __restrict__ c_init,
                const unsigned short* __restrict__ zbuf,
                unsigned short* __restrict__ Hraw, unsigned short* __restrict__ Cst,
                unsigned short* __restrict__ Hnew)
{
    const int M = counts[s];
    if (M == 0) return;
    const int off    = offs[s];
    const int mtiles = (M + 127) >> 7;

    __shared__ __align__(16) unsigned short As[128 * 32];
    __shared__ __align__(16) unsigned short Bs[128 * 32];
    __shared__ __align__(16) unsigned short Gx[128 * 136];
    __shared__ float bls[128];
    __shared__ int rl[128];

    const int tid  = threadIdx.x;
    const int w    = tid >> 6;
    const int lane = tid & 63;
    const int quad = lane >> 4;
    const int lr   = lane & 15;
    const int wm   = w & 1, wn = w >> 1;
    const int c0   = blockIdx.x * 32;
    const int srow = lane >> 2;
    const int kblk = (lane & 3) ^ ((lane >> 3) & 3);

    if (tid < 128) bls[tid] = bsum[(tid >> 5) * 512 + c0 + (tid & 31)];

    const int br0 = w * 16 + srow;
    const int br1 = 64 + br0;
    const unsigned short* gB0 = Wcat + (size_t)((br0 >> 5) * 512 + c0 + (br0 & 31)) * 1024 + kblk * 8;
    const unsigned short* gB1 = Wcat + (size_t)((br1 >> 5) * 512 + c0 + (br1 & 31)) * 1024 + kblk * 8;
    unsigned short* lA0 = As + (w * 16) * 32;
    unsigned short* lA1 = As + (64 + w * 16) * 32;
    unsigned short* lB0 = Bs + (w * 16) * 32;
    unsigned short* lB1 = Bs + (64 + w * 16) * 32;

    const int swz = (quad ^ ((lr >> 1) & 3)) * 8;
    int aoff[4], boff[4];
    #pragma unroll
    for (int i = 0; i < 4; ++i) {
        aoff[i] = (wm * 64 + i * 16 + lr) * 32 + swz;
        boff[i] = (wn * 64 + i * 16 + lr) * 32 + swz;
    }

    for (int mt = blockIdx.y; mt < mtiles; mt += gridDim.y) {
        __syncthreads();
        if (tid < 128) {
            int li = mt * 128 + tid;
            rl[tid] = (li < M) ? rows[off + li] : -1;
        }
        __syncthreads();

        // round 0, tiles past the 256 t=0 rows: all h_prev are zero -> skip h-half
        const int kbeg = (s == 0 && mt * 128 >= 256) ? 16 : 0;

        int g0r = rl[w * 16 + srow];
        int g1r = rl[64 + w * 16 + srow];
        const unsigned short* gA0h;
        const unsigned short* gA1h;
        if (s == 0) {
            gA0h = (g0r >= 0 && g0r < 256) ? h_init + (size_t)g0r * 512 + kblk * 8 : zbuf + kblk * 8;
            gA1h = (g1r >= 0 && g1r < 256) ? h_init + (size_t)g1r * 512 + kblk * 8 : zbuf + kblk * 8;
        } else {
            gA0h = (g0r >= 0) ? Hraw + (size_t)(g0r - 256) * 512 + kblk * 8 : zbuf + kblk * 8;
            gA1h = (g1r >= 0) ? Hraw + (size_t)(g1r - 256) * 512 + kblk * 8 : zbuf + kblk * 8;
        }
        const unsigned short* gA0x = (g0r >= 0) ? H2 + (size_t)g0r * 512 + kblk * 8 : zbuf + kblk * 8;
        const unsigned short* gA1x = (g1r >= 0) ? H2 + (size_t)g1r * 512 + kblk * 8 : zbuf + kblk * 8;

        v4f zz = {0.f, 0.f, 0.f, 0.f};
        v4f acc[4][4] = {{zz,zz,zz,zz},{zz,zz,zz,zz},{zz,zz,zz,zz},{zz,zz,zz,zz}};

        for (int k = kbeg; k < 32; ++k) {
            __syncthreads();
            const unsigned short* a0 = (k < 16) ? gA0h + k * 32 : gA0x + (k - 16) * 32;
            const unsigned short* a1 = (k < 16) ? gA1h + k * 32 : gA1x + (k - 16) * 32;
            gld_lds16(a0, lA0);
            gld_lds16(a1, lA1);
            gld_lds16(gB0 + k * 32, lB0);
            gld_lds16(gB1 + k * 32, lB1);
            __syncthreads();
            v8s a[4], b[4];
            #pragma unroll
            for (int i = 0; i < 4; ++i) { a[i] = *(const v8s*)&As[aoff[i]]; b[i] = *(const v8s*)&Bs[boff[i]]; }
            #pragma unroll
            for (int i = 0; i < 4; ++i)
                #pragma unroll
                for (int j = 0; j < 4; ++j)
                    acc[i][j] = __builtin_amdgcn_mfma_f32_16x16x32_bf16(a[i], b[j], acc[i][j], 0, 0, 0);
        }

        #pragma unroll
        for (int j = 0; j < 4; ++j) {
            const int nl = wn * 64 + j * 16 + lr;
            #pragma unroll
            for (int i = 0; i < 4; ++i)
                #pragma unroll
                for (int r = 0; r < 4; ++r)
                    Gx[(wm * 64 + i * 16 + quad * 4 + r) * 136 + nl] = f2bf(acc[i][j][r]);
        }
        __syncthreads();

        {
            const int rloc = tid >> 1;
            const int half = tid & 1;
            const int gr   = rl[rloc];
            if (gr >= 0) {
                #pragma unroll
                for (int ch = 0; ch < 2; ++ch) {
                    const int co = half * 16 + ch * 8;
                    const int kg = c0 + co;
                    v8s q0 = *(const v8s*)&Gx[rloc * 136 +   0 + co];
                    v8s q1 = *(const v8s*)&Gx[rloc * 136 +  32 + co];
                    v8s q2 = *(const v8s*)&Gx[rloc * 136 +  64 + co];
                    v8s q3 = *(const v8s*)&Gx[rloc * 136 +  96 + co];
                    v8s h2v = *(const v8s*)&H2[(size_t)gr * 512 + kg];
                    float cprev[8];
                    if (s == 0) {
                        if (gr < 256) {
                            v8s cv = *(const v8s*)&c_init[(size_t)gr * 512 + kg];
                            #pragma unroll
                            for (int e = 0; e < 8; ++e) cprev[e] = bf2f((unsigned short)cv[e]);
                        } else {
                            #pragma unroll
                            for (int e = 0; e < 8; ++e) cprev[e] = 0.f;
                        }
                    } else {
                        v8s cv = *(const v8s*)&Cst[(size_t)(gr - 256) * 512 + kg];
                        #pragma unroll
                        for (int e = 0; e < 8; ++e) cprev[e] = bf2f((unsigned short)cv[e]);
                    }
                    unsigned short hc[8], cc[8], hn[8];
                    #pragma unroll
                    for (int e = 0; e < 8; ++e) {
                        float gi = bf2f((unsigned short)q0[e]) + bls[ 0 + co + e];
                        float gf = bf2f((unsigned short)q1[e]) + bls[32 + co + e];
                        float gg = bf2f((unsigned short)q2[e]) + bls[64 + co + e];
                        float go = bf2f((unsigned short)q3[e]) + bls[96 + co + e];
                        float c  = fsig(gf) * cprev[e] + fsig(gi) * ftanh(gg);
                        float h  = fsig(go) * ftanh(c);
                        cc[e] = f2bf(c);
                        hc[e] = f2bf(h);
                        hn[e] = f2bf(h + bf2f((unsigned short)h2v[e]));
                    }
                    *(v8s*)&Cst[(size_t)gr * 512 + kg]  = *(const v8s*)cc;
                    *(v8s*)&Hraw[(size_t)gr * 512 + kg] = *(const v8s*)hc;
                    *(v8s*)&Hnew[(size_t)gr * 512 + kg] = *(const v8s*)hn;
                }
            }
        }
    }
}

// ---------------------------------------------------------------------------
// Tail (s >= 12): 64 WGs, resident [Whh|Wih] slice (32 rows x 1024 = 64 KB),
// K=1024 over [h_prev ; h2]; device-scope spin barrier between levels.
// ---------------------------------------------------------------------------
__global__ __launch_bounds__(256, 1)
void lstm_tail(const int* __restrict__ trows, const int* __restrict__ tcnt,
               const int* __restrict__ toffs, const int* __restrict__ maxS_p,
               const unsigned short* __restrict__ H2,
               const unsigned short* __restrict__ Wcat,
               const float* __restrict__ bsum,
               unsigned short* __restrict__ Hraw, unsigned short* __restrict__ Cst,
               unsigned short* __restrict__ Hnew,
               int* __restrict__ bar)
{
    const int mS = *maxS_p;
    if (mS < S0R) return;
    __shared__ __align__(16) unsigned short Wl[32 * 1024];   // 64 KB
    __shared__ __align__(16) unsigned short Hb[16 * 1024];   // 32 KB
    __shared__ float Gb[16 * 32];
    __shared__ float bl[32];
    __shared__ int rl[16];
    const int j    = blockIdx.x;
    const int tid  = threadIdx.x;
    const int w    = tid >> 6;
    const int lane = tid & 63;
    const int quad = lane >> 4;
    const int lr   = lane & 15;

    if (tid < 32) bl[tid] = bsum[(tid >> 3) * 512 + j * 8 + (tid & 7)];

    for (int e = tid; e < 32 * 128; e += 256) {
        int n = e >> 7, kb = e & 127;
        int g = n >> 3, c = n & 7;
        *(v8s*)&Wl[n * 1024 + kb * 8] = *(const v8s*)&Wcat[(size_t)(g * 512 + j * 8 + c) * 1024 + kb * 8];
    }

    int target = 0;
    for (int s = S0R; s <= mS; ++s) {
        const int lev = s - S0R;
        const int M   = tcnt[lev];
        const int off = toffs[lev];
        for (int ch = 0; ch < M; ch += 16) {
            __syncthreads();
            if (tid < 16) rl[tid] = (ch + tid < M) ? trows[off + ch + tid] : -1;
            __syncthreads();
            {   // stage [h_prev ; h2] rows
                int r = tid >> 4, seg = (tid & 15) * 32;
                int gr = rl[r];
                if (gr >= 0) {
                    const unsigned short* srcH = &Hraw[(size_t)(gr - 256) * 512 + seg];
                    const unsigned short* srcX = &H2[(size_t)gr * 512 + seg];
                    #pragma unroll
                    for (int q = 0; q < 4; ++q) {
                        *(v8s*)&Hb[r * 1024 + seg + q * 8]       = *(const v8s*)(srcH + q * 8);
                        *(v8s*)&Hb[r * 1024 + 512 + seg + q * 8] = *(const v8s*)(srcX + q * 8);
                    }
                } else {
                    v8s z = {0,0,0,0,0,0,0,0};
                    #pragma unroll
                    for (int q = 0; q < 4; ++q) {
                        *(v8s*)&Hb[r * 1024 + seg + q * 8]       = z;
                        *(v8s*)&Hb[r * 1024 + 512 + seg + q * 8] = z;
                    }
                }
            }
            __syncthreads();
            if (w < 2) {
                v4f acc = {0.f, 0.f, 0.f, 0.f};
                for (int k = 0; k < 32; ++k) {
                    v8s a = *(const v8s*)&Hb[lr * 1024 + k * 32 + quad * 8];
                    v8s b = *(const v8s*)&Wl[(w * 16 + lr) * 1024 + k * 32 + quad * 8];
                    acc = __builtin_amdgcn_mfma_f32_16x16x32_bf16(a, b, acc, 0, 0, 0);
                }
                #pragma unroll
                for (int r = 0; r < 4; ++r)
                    Gb[(quad * 4 + r) * 32 + w * 16 + lr] = acc[r];
            }
            __syncthreads();
            if (tid < 128) {
                int r = tid >> 3, c = tid & 7;
                int gr = rl[r];
                if (gr >= 0) {
                    int k = j * 8 + c;
                    float gi = Gb[r * 32 +  0 + c] + bl[ 0 + c];
                    float gf = Gb[r * 32 +  8 + c] + bl[ 8 + c];
                    float gg = Gb[r * 32 + 16 + c] + bl[16 + c];
                    float go = Gb[r * 32 + 24 + c] + bl[24 + c];
                    float cp = bf2f(Cst[(size_t)(gr - 256) * 512 + k]);
                    float cc = fsig(gf) * cp + fsig(gi) * ftanh(gg);
                    float hh = fsig(go) * ftanh(cc);
                    Cst[(size_t)gr * 512 + k]  = f2bf(cc);
                    Hraw[(size_t)gr * 512 + k] = f2bf(hh);
                    Hnew[(size_t)gr * 512 + k] = f2bf(hh + bf2f(H2[(size_t)gr * 512 + k]));
                }
            }
        }
        target += 64;
        __threadfence();
        __syncthreads();
        if (tid == 0) {
            __hip_atomic_fetch_add(bar, 1, __ATOMIC_RELEASE, __HIP_MEMORY_SCOPE_AGENT);
            while (__hip_atomic_load(bar, __ATOMIC_ACQUIRE, __HIP_MEMORY_SCOPE_AGENT) < target) {}
        }
        __syncthreads();
        __threadfence();
    }
}

// actor head: one wave per row over bf16 logits (stride 1024, 1000 valid)
__global__ void head_reduce(const unsigned short* __restrict__ logits,
                            const int* __restrict__ action,
                            float* __restrict__ out, int TB)
{
    const int r = blockIdx.x * 4 + (threadIdx.x >> 6);
    const int lane = threadIdx.x & 63;
    const unsigned short* row = logits + (size_t)r * 1024;
    float m = -1e30f, Z = 0.f, S = 0.f;
    v8s v0 = *(const v8s*)&row[lane * 8];
    #pragma unroll
    for (int e = 0; e < 8; ++e) {
        float xv = bf2f((unsigned short)v0[e]);
        if (xv > m) { float sc = __builtin_amdgcn_exp2f((m - xv) * L2E); Z *= sc; S *= sc; m = xv; }
        float ev = __builtin_amdgcn_exp2f((xv - m) * L2E);
        Z += ev; S += xv * ev;
    }
    v8s v1 = *(const v8s*)&row[512 + lane * 8];
    #pragma unroll
    for (int e = 0; e < 8; ++e) {
        int c = 512 + lane * 8 + e;
        if (c < 1000) {
            float xv = bf2f((unsigned short)v1[e]);
            if (xv > m) { float sc = __builtin_amdgcn_exp2f((m - xv) * L2E); Z *= sc; S *= sc; m = xv; }
            float ev = __builtin_amdgcn_exp2f((xv - m) * L2E);
            Z += ev; S += xv * ev;
        }
    }
    #pragma unroll
    for (int offb = 32; offb > 0; offb >>= 1) {
        float m2 = __shfl_xor(m, offb);
        float Z2 = __shfl_xor(Z, offb);
        float S2 = __shfl_xor(S, offb);
        float M  = fmaxf(m, m2);
        float s1 = __builtin_amdgcn_exp2f((m - M) * L2E), s2 = __builtin_amdgcn_exp2f((m2 - M) * L2E);
        Z = Z * s1 + Z2 * s2;
        S = S * s1 + S2 * s2;
        m = M;
    }
    if (lane == 0) {
        float lse = m + 0.6931471805599453f * __builtin_amdgcn_logf(Z);
        float xa  = bf2f(row[action[r]]);
        out[r]      = xa - lse;
        out[TB + r] = lse - S / Z;
    }
}

// critic head over fused AC1 (stride 1024, critic half at +512)
__global__ void critic_v(const unsigned short* __restrict__ AC, const float* __restrict__ Wc2,
                         const float* __restrict__ bc2, float* __restrict__ out, int TB)
{
    const int r = blockIdx.x * 4 + (threadIdx.x >> 6);
    const int lane = threadIdx.x & 63;
    const unsigned short* row = AC + (size_t)r * 1024 + 512;
    v8s hv = *(const v8s*)&row[lane * 8];
    float4 w0 = *(const float4*)&Wc2[lane * 8];
    float4 w1 = *(const float4*)&Wc2[lane * 8 + 4];
    float s = bf2f((unsigned short)hv[0]) * w0.x + bf2f((unsigned short)hv[1]) * w0.y +
              bf2f((unsigned short)hv[2]) * w0.z + bf2f((unsigned short)hv[3]) * w0.w +
              bf2f((unsigned short)hv[4]) * w1.x + bf2f((unsigned short)hv[5]) * w1.y +
              bf2f((unsigned short)hv[6]) * w1.z + bf2f((unsigned short)hv[7]) * w1.w;
    #pragma unroll
    for (int offb = 32; offb > 0; offb >>= 1) s += __shfl_xor(s, offb);
    if (lane == 0) out[2 * TB + r] = s + bc2[0];
}

extern "C" void kernel_launch(void* const* d_in, const int* in_sizes, int n_in,
                              void* d_out, int out_size, void* d_ws, size_t ws_size,
                              hipStream_t stream)
{
    const float* x    = (const float*)d_in[0];
    const int*  done  = (const int*)d_in[1];
    const int*  action= (const int*)d_in[2];
    const float* W_t1 = (const float*)d_in[4];
    const float* b_t1 = (const float*)d_in[5];
    const float* W_t2 = (const float*)d_in[6];
    const float* b_t2 = (const float*)d_in[7];
    const float* Wih  = (const float*)d_in[8];
    const float* Whh  = (const float*)d_in[9];
    const float* bih  = (const float*)d_in[10];
    const float* bhh  = (const float*)d_in[11];
    const float* Wa1  = (const float*)d_in[12];
    const float* ba1  = (const float*)d_in[13];
    const float* Wa2  = (const float*)d_in[14];
    const float* ba2  = (const float*)d_in[15];
    const float* Wc1  = (const float*)d_in[16];
    const float* bc1  = (const float*)d_in[17];
    const float* Wc2  = (const float*)d_in[18];
    const float* bc2  = (const float*)d_in[19];
    const float* h0   = (const float*)d_in[20];
    const float* c0   = (const float*)d_in[21];
    float* out = (float*)d_out;

    const int TB = in_sizes[1];      // 65536
    const int T  = TB / 256;         // 256

    const size_t MiB = 1024 * 1024;
    char* ws = (char*)d_ws;
    unsigned short* H1     = (unsigned short*)(ws);               // 64 MiB (trunk tmp)
    unsigned short* Hnew   = (unsigned short*)(ws);               // alias: H1 dead before rounds
    unsigned short* logits = (unsigned short*)(ws);               // alias: Hnew dead after AC1
    unsigned short* AC1    = (unsigned short*)(ws + 128 * MiB);   // 128 MiB
    unsigned short* Cst    = (unsigned short*)(ws + 256 * MiB);   // 64 MiB
    unsigned short* H2     = (unsigned short*)(ws + 320 * MiB);   // 64 MiB
    unsigned short* Hraw   = (unsigned short*)(ws + 384 * MiB);   // 64 MiB
    unsigned short* xbf    = Hraw;                                 // alias (x dead after trunk1)
    unsigned short* Wt1b   = (unsigned short*)(ws + 448 * MiB);
    unsigned short* Wt2b   = Wt1b + 512 * 512;
    unsigned short* Wcat   = Wt2b + 512 * 512;                     // 2048 x 1024
    unsigned short* Wacb   = Wcat + 2048 * 1024;                   // 1024 x 512
    unsigned short* Wa2b   = Wacb + 1024 * 512;                    // 1024 x 512
    unsigned short* h_init = Wa2b + 1024 * 512;
    unsigned short* c_init = h_init + 256 * 512;
    unsigned short* zbuf   = c_init + 256 * 512;
    int* rows   = (int*)(zbuf + 512);
    int* trows  = rows + 65536;
    int* counts = trows + 65536;
    int* offs   = counts + S0R;
    int* tcnt   = offs + S0R;
    int* toffs  = tcnt + NLEV;
    int* maxS   = toffs + NLEV;
    int* bar    = maxS + 1;
    float* bsum = (float*)(bar + 1);          // 2048 f32
    float* bac  = bsum + 2048;                // 1024 f32

    dim3 blk(256);
    dim3 blk5(512);

    // dtype conversions + weight packing + init + segment lists
    cvt8<<<16384, blk, 0, stream>>>(x, xbf);
    cvt8<<<128,  blk, 0, stream>>>(W_t1, Wt1b);
    cvt8<<<128,  blk, 0, stream>>>(W_t2, Wt2b);
    cvt_cat<<<1024, blk, 0, stream>>>(Whh, Wih, Wcat);
    cvt8<<<128,  blk, 0, stream>>>(Wa1, Wacb);
    cvt8<<<128,  blk, 0, stream>>>(Wc1, Wacb + 512 * 512);
    wa2pad<<<2048, blk, 0, stream>>>(Wa2, Wa2b);
    prep_misc<<<12, blk, 0, stream>>>(bih, bhh, ba1, bc1, bsum, bac);
    init_state<<<256, blk, 0, stream>>>(h0, c0, done, h_init, c_init, zbuf);
    seg_prep<<<1, blk, 0, stream>>>(done, rows, counts, offs, trows, tcnt, toffs, maxS, bar, T);

    // trunk
    gemm256<true ><<<512, blk5, 0, stream>>>(xbf, Wt1b, b_t1, H1, 512, 512, 2, 512);
    gemm256<true ><<<512, blk5, 0, stream>>>(H1,  Wt2b, b_t2, H2, 512, 512, 2, 512);

    // segment-parallel LSTM, x-gates fused (K=1024), residual fused into epilogue
    static const int Gs[S0R] = {256, 128, 64, 32, 16, 8, 4, 2, 1, 1, 1, 1};
    for (int s = 0; s < S0R; ++s)
        lstm_round<<<dim3(16, Gs[s]), blk, 0, stream>>>(rows, counts, offs, s, H2, Wcat, bsum,
                                                        h_init, c_init, zbuf, Hraw, Cst, Hnew);
    lstm_tail<<<64, blk, 0, stream>>>(trows, tcnt, toffs, maxS, H2, Wcat, bsum, Hraw, Cst, Hnew, bar);

    // fused actor/critic first layers: AC1 = tanh(Hnew @ [Wa1;Wc1]^T + [ba1;bc1])
    gemm256<true ><<<1024, blk5, 0, stream>>>(Hnew, Wacb, bac, AC1, 1024, 1024, 4, 512);

    // actor logits from A1 half (stride-1024 A)
    gemm256<false><<<1024, blk5, 0, stream>>>(AC1, Wa2b, ba2, logits, 1000, 1024, 4, 1024);
    head_reduce<<<TB / 4, blk, 0, stream>>>(logits, action, out, TB);

    // critic from C1 half
    critic_v<<<TB / 4, blk, 0, stream>>>(AC1, Wc2, bc2, out, TB);
}

// Round 5
// 1334.580 us; speedup vs baseline: 1.4115x; 1.0263x over previous
//
#include <hip/hip_runtime.h>
#include <hip/hip_bf16.h>

typedef short v8s __attribute__((ext_vector_type(8)));
typedef float v4f __attribute__((ext_vector_type(4)));

#define S0R 12      // rounds 0..11 via gather-GEMM; lstm_tail covers s >= 12
#define NLEV 244    // tail levels 12..255
#define L2E 1.4426950408889634f

__device__ __forceinline__ float bf2f(unsigned short u) {
    union { unsigned int i; float f; } v; v.i = ((unsigned int)u) << 16; return v.f;
}
__device__ __forceinline__ unsigned short f2bf(float f) {
    union { float f; unsigned int i; } v; v.f = f;
    unsigned int x = v.i;
    return (unsigned short)((x + 0x7fffu + ((x >> 16) & 1u)) >> 16);
}
// fast sigmoid/tanh: v_exp_f32 + v_rcp_f32 (1-2 ulp; invisible under bf16)
__device__ __forceinline__ float fsig(float x) {
    return __builtin_amdgcn_rcpf(1.f + __builtin_amdgcn_exp2f(-L2E * x));
}
__device__ __forceinline__ float ftanh(float x) {
    return 2.f * __builtin_amdgcn_rcpf(1.f + __builtin_amdgcn_exp2f((-2.f * L2E) * x)) - 1.f;
}

// async global->LDS, 16B per lane; LDS dst is wave-uniform base + lane*16
__device__ __forceinline__ void gld_lds16(const unsigned short* g, unsigned short* l) {
    __builtin_amdgcn_global_load_lds(
        (const __attribute__((address_space(1))) unsigned int*)g,
        (__attribute__((address_space(3))) unsigned int*)l, 16, 0, 0);
}

// ---------------------------------------------------------------------------
// gemm256: C[M,Npad] = act(A[.,Astr][:512] @ W[Npad,512]^T + b1), bf16.
// 256x256 tile, BK=64, 8 waves, 8-phase counted-vmcnt schedule, XOR-swizzled
// LDS, setprio, XCD-chunked swizzle.  Epilogue via LDS -> coalesced stores.
// ---------------------------------------------------------------------------
template <bool TANH>
__global__ __launch_bounds__(512, 2)
void gemm256(const unsigned short* __restrict__ Ag, const unsigned short* __restrict__ Wg,
             const float* __restrict__ b1,
             unsigned short* __restrict__ Cg, int Nreal, int Npad, int Ntiles, int Astr)
{
    __shared__ __align__(16) unsigned short As[2][256 * 64];   // 64 KB
    __shared__ __align__(16) unsigned short Bs[2][256 * 64];   // 64 KB

    const int tid  = threadIdx.x;
    const int w    = tid >> 6;          // 0..7
    const int lane = tid & 63;
    const int quad = lane >> 4;
    const int lr   = lane & 15;
    const int wm   = w >> 2;            // 0..1
    const int wn   = w & 3;             // 0..3

    const int nwg = gridDim.x;
    const int cpx = nwg >> 3;
    const int swz = (blockIdx.x & 7) * cpx + (blockIdx.x >> 3);
    const int m0  = (swz / Ntiles) * 256;
    const int n0  = (swz % Ntiles) * 256;

    const unsigned short* gA = Ag + (size_t)m0 * Astr;
    const unsigned short* gB = Wg + (size_t)n0 * 512;

    const int sr  = w * 8 + (lane >> 3);
    const int skg = (lane & 7) ^ ((lane >> 3) & 7);

    auto SA = [&](int buf, int u, int kt) {
        gld_lds16(gA + (size_t)(u * 64 + sr) * Astr + kt * 64 + skg * 8,
                  &As[buf][(u * 64 + w * 8) * 64]);
    };
    auto SB = [&](int buf, int u, int kt) {
        gld_lds16(gB + (size_t)(u * 64 + sr) * 512 + kt * 64 + skg * 8,
                  &Bs[buf][(u * 64 + w * 8) * 64]);
    };

    const int g8_0  = (quad ^ (lr & 7)) * 8;
    const int g8_1  = ((quad + 4) ^ (lr & 7)) * 8;
    const int aBase = (wm * 128 + lr) * 64;
    const int bBase = (wn * 64 + lr) * 64;

    v4f zz = {0.f, 0.f, 0.f, 0.f};
    v4f acc[8][4];
    #pragma unroll
    for (int m = 0; m < 8; ++m)
        #pragma unroll
        for (int n = 0; n < 4; ++n) acc[m][n] = zz;
    v8s Bf[4][2];

#define DSB(BUF)                                                         \
    _Pragma("unroll")                                                    \
    for (int n = 0; n < 4; ++n) {                                        \
        Bf[n][0] = *(const v8s*)&Bs[BUF][bBase + n * 1024 + g8_0];       \
        Bf[n][1] = *(const v8s*)&Bs[BUF][bBase + n * 1024 + g8_1];       \
    }

#define PH(BUF, Q, STMTS, PREBAR)                                                     \
    {                                                                                 \
        const v8s a00 = *(const v8s*)&As[BUF][aBase + ((Q)*2 + 0) * 1024 + g8_0];     \
        const v8s a01 = *(const v8s*)&As[BUF][aBase + ((Q)*2 + 0) * 1024 + g8_1];     \
        const v8s a10 = *(const v8s*)&As[BUF][aBase + ((Q)*2 + 1) * 1024 + g8_0];     \
        const v8s a11 = *(const v8s*)&As[BUF][aBase + ((Q)*2 + 1) * 1024 + g8_1];     \
        STMTS;                                                                        \
        PREBAR;                                                                       \
        __builtin_amdgcn_s_barrier();                                                 \
        asm volatile("s_waitcnt lgkmcnt(0)" ::: "memory");                            \
        __builtin_amdgcn_sched_barrier(0);                                            \
        __builtin_amdgcn_s_setprio(1);                                                \
        _Pragma("unroll")                                                             \
        for (int n = 0; n < 4; ++n) {                                                 \
            acc[(Q)*2    ][n] = __builtin_amdgcn_mfma_f32_16x16x32_bf16(a00, Bf[n][0], acc[(Q)*2    ][n], 0, 0, 0); \
            acc[(Q)*2    ][n] = __builtin_amdgcn_mfma_f32_16x16x32_bf16(a01, Bf[n][1], acc[(Q)*2    ][n], 0, 0, 0); \
            acc[(Q)*2 + 1][n] = __builtin_amdgcn_mfma_f32_16x16x32_bf16(a10, Bf[n][0], acc[(Q)*2 + 1][n], 0, 0, 0); \
            acc[(Q)*2 + 1][n] = __builtin_amdgcn_mfma_f32_16x16x32_bf16(a11, Bf[n][1], acc[(Q)*2 + 1][n], 0, 0, 0); \
        }                                                                             \
        __builtin_amdgcn_s_setprio(0);                                                \
        __builtin_amdgcn_s_barrier();                                                 \
    }

    SB(0, 0, 0); SB(0, 1, 0); SB(0, 2, 0); SB(0, 3, 0);
    SA(0, 0, 0); SA(0, 2, 0); SA(0, 1, 0); SA(0, 3, 0);
    SB(1, 0, 1); SB(1, 1, 1); SB(1, 2, 1); SB(1, 3, 1);
    SA(1, 0, 1); SA(1, 2, 1);
    asm volatile("s_waitcnt vmcnt(6)" ::: "memory");
    __builtin_amdgcn_s_barrier();

    #pragma unroll
    for (int i = 0; i < 4; ++i) {                 // 2 K-tiles / iteration
        const bool more = (i < 3);
        const int t1 = 2 * i + 1, t2 = 2 * i + 2, t3 = 2 * i + 3;
        PH(0, 0, { DSB(0); SA(1, 1, t1); SA(1, 3, t1); }, )
        PH(0, 1, { if (more) { SB(0, 0, t2); SB(0, 1, t2); } }, )
        PH(0, 2, { if (more) { SB(0, 2, t2); SB(0, 3, t2); } }, )
        PH(0, 3, { if (more) { SA(0, 0, t2); SA(0, 2, t2); } },
           if (more) { asm volatile("s_waitcnt vmcnt(6)" ::: "memory"); }
           else      { asm volatile("s_waitcnt vmcnt(0)" ::: "memory"); } )
        PH(1, 0, { DSB(1); if (more) { SA(0, 1, t2); SA(0, 3, t2); } }, )
        PH(1, 1, { if (more) { SB(1, 0, t3); SB(1, 1, t3); } }, )
        PH(1, 2, { if (more) { SB(1, 2, t3); SB(1, 3, t3); } }, )
        PH(1, 3, { if (more) { SA(1, 0, t3); SA(1, 2, t3); } },
           if (more) { asm volatile("s_waitcnt vmcnt(6)" ::: "memory"); } )
    }
#undef PH
#undef DSB

    // ---- epilogue: acc -> LDS (swizzled bf16 [256][256]) -> coalesced flush
    __syncthreads();
    unsigned short* Ct = wm ? &Bs[0][0] : &As[0][0];
    #pragma unroll
    for (int n = 0; n < 4; ++n) {
        const int nn = n0 + wn * 64 + n * 16 + lr;
        const float bias = (nn < Nreal) ? b1[nn] : 0.f;
        const int col = wn * 64 + n * 16 + lr;
        #pragma unroll
        for (int m = 0; m < 8; ++m) {
            #pragma unroll
            for (int r = 0; r < 4; ++r) {
                const int row = m * 16 + quad * 4 + r;
                float v = acc[m][n][r] + bias;
                if (TANH) v = ftanh(v);
                Ct[row * 256 + (((col >> 3) ^ (row & 7)) << 3) + (col & 7)] = f2bf(v);
            }
        }
    }
    __syncthreads();
    #pragma unroll
    for (int it = 0; it < 16; ++it) {
        const int c   = it * 512 + tid;
        const int row = c >> 5;
        const int gc  = c & 31;
        const unsigned short* src = (row < 128)
            ? &As[0][row * 256 + ((gc ^ (row & 7)) << 3)]
            : &Bs[0][(row - 128) * 256 + ((gc ^ (row & 7)) << 3)];
        v8s val = *(const v8s*)src;
        *(v8s*)&Cg[(size_t)(m0 + row) * Npad + n0 + gc * 8] = val;
    }
}

// fp32 -> bf16, 8 elems/thread (n must be multiple of 2048)
__global__ void cvt8(const float* __restrict__ src, unsigned short* __restrict__ dst)
{
    const size_t i = ((size_t)blockIdx.x * 256 + threadIdx.x) * 8;
    float4 f0 = *(const float4*)(src + i);
    float4 f1 = *(const float4*)(src + i + 4);
    unsigned short t8[8];
    t8[0]=f2bf(f0.x); t8[1]=f2bf(f0.y); t8[2]=f2bf(f0.z); t8[3]=f2bf(f0.w);
    t8[4]=f2bf(f1.x); t8[5]=f2bf(f1.y); t8[6]=f2bf(f1.z); t8[7]=f2bf(f1.w);
    *(v8s*)(dst + i) = *(const v8s*)t8;
}

// Wcat[2048][1024] = [Whh | Wih] bf16 (K-dim concat), 8 elems/thread, grid 1024
__global__ void cvt_cat(const float* __restrict__ Whh, const float* __restrict__ Wih,
                        unsigned short* __restrict__ Wcat)
{
    const size_t i = ((size_t)blockIdx.x * 256 + threadIdx.x) * 8;
    const int row = (int)(i >> 10), col = (int)(i & 1023);
    const float* src = (col < 512) ? &Whh[(size_t)row * 512 + col]
                                   : &Wih[(size_t)row * 512 + (col - 512)];
    float4 f0 = *(const float4*)src;
    float4 f1 = *(const float4*)(src + 4);
    unsigned short t8[8];
    t8[0]=f2bf(f0.x); t8[1]=f2bf(f0.y); t8[2]=f2bf(f0.z); t8[3]=f2bf(f0.w);
    t8[4]=f2bf(f1.x); t8[5]=f2bf(f1.y); t8[6]=f2bf(f1.z); t8[7]=f2bf(f1.w);
    *(v8s*)(Wcat + i) = *(const v8s*)t8;
}

// Wa2 (1000x512 fp32) -> zero-padded 1024x512 bf16
__global__ void wa2pad(const float* __restrict__ src, unsigned short* __restrict__ dst)
{
    const int i = blockIdx.x * 256 + threadIdx.x;
    const int row = i >> 9;
    dst[i] = (row < 1000) ? f2bf(src[(size_t)row * 512 + (i & 511)]) : (unsigned short)0;
}

// bsum[2048] = bih+bhh ; bac[1024] = [ba1 ; bc1]   (grid 12 x 256)
__global__ void prep_misc(const float* __restrict__ bih, const float* __restrict__ bhh,
                          const float* __restrict__ ba1, const float* __restrict__ bc1,
                          float* __restrict__ bsum, float* __restrict__ bac)
{
    const int i = blockIdx.x * 256 + threadIdx.x;
    if (i < 2048) bsum[i] = bih[i] + bhh[i];
    else if (i < 3072) {
        int k = i - 2048;
        bac[k] = (k < 512) ? ba1[k] : bc1[k - 512];
    }
}

// masked initial state (bf16) + zero row buffer
__global__ void init_state(const float* __restrict__ h0, const float* __restrict__ c0,
                           const int* __restrict__ done,
                           unsigned short* __restrict__ h_init, unsigned short* __restrict__ c_init,
                           unsigned short* __restrict__ zbuf)
{
    const int b = blockIdx.x;
    const float m = 1.f - (float)done[b];
    for (int k = threadIdx.x; k < 512; k += 256) {
        h_init[(size_t)b * 512 + k] = f2bf(h0[(size_t)b * 512 + k] * m);
        c_init[(size_t)b * 512 + k] = f2bf(c0[(size_t)b * 512 + k] * m);
        if (b == 0) zbuf[k] = 0;
    }
}

// ---------------------------------------------------------------------------
// Segment prep (single WG).  8x-unrolled done loads; s=0 list has the 256
// t=0 rows FIRST so round-0 tiles with mt*128>=256 skip the h-half of K.
// ---------------------------------------------------------------------------
__global__ __launch_bounds__(256, 1)
void seg_prep(const int* __restrict__ done, int* __restrict__ rows,
              int* __restrict__ counts, int* __restrict__ offs,
              int* __restrict__ trows, int* __restrict__ tcnt, int* __restrict__ toffs,
              int* __restrict__ maxS, int* __restrict__ bar, int T)
{
    __shared__ unsigned int   bits[256][8];
    __shared__ unsigned short cnt[256][S0R];
    __shared__ unsigned short base[256][S0R];
    __shared__ int tot[S0R];
    __shared__ int goff[S0R];
    __shared__ int tcl[NLEV];
    __shared__ int tol[NLEV];
    __shared__ int tpos[NLEV];
    __shared__ int mxl[256];
    const int b = threadIdx.x;
    #pragma unroll
    for (int s = 0; s < S0R; ++s) cnt[b][s] = 0;
    #pragma unroll
    for (int i = 0; i < 8; ++i) bits[b][i] = 0;
    for (int l = b; l < NLEV; l += 256) { tcl[l] = 0; tpos[l] = 0; }
    __syncthreads();

    int s = 0, mx = 0;
    for (int t0 = 0; t0 < T; t0 += 8) {
        int d8[8];
        #pragma unroll
        for (int i = 0; i < 8; ++i) d8[i] = done[(t0 + i) * 256 + b];
        #pragma unroll
        for (int i = 0; i < 8; ++i) {
            const int t = t0 + i, d = d8[i];
            if (d) bits[b][t >> 5] |= (1u << (t & 31));
            s = (t == 0 || d) ? 0 : s + 1;
            if (s < S0R) { if (t != 0) cnt[b][s]++; }   // t=0 rows reserved
            else atomicAdd(&tcl[s - S0R], 1);
            mx = mx > s ? mx : s;
        }
    }
    mxl[b] = mx;
    __syncthreads();

    if (b < S0R) {
        int tsum = 0;
        for (int bb = 0; bb < 256; ++bb) { base[bb][b] = (unsigned short)tsum; tsum += cnt[bb][b]; }
        tot[b] = tsum;
    }
    __syncthreads();
    if (b == 0) {
        int run = 256;                               // [0,256) = t=0 rows
        for (int ss = 0; ss < S0R; ++ss) { goff[ss] = run; run += tot[ss]; }
        run = 0;
        for (int l = 0; l < NLEV; ++l) { tol[l] = run; run += tcl[l]; }
        int m = 0;
        for (int bb = 0; bb < 256; ++bb) m = m > mxl[bb] ? m : mxl[bb];
        *maxS = m;
        *bar  = 0;
    }
    __syncthreads();
    if (b < S0R) {
        counts[b] = tot[b] + (b == 0 ? 256 : 0);
        offs[b]   = (b == 0) ? 0 : goff[b];
    }
    for (int l = b; l < NLEV; l += 256) { tcnt[l] = tcl[l]; toffs[l] = tol[l]; }

    s = 0;
    for (int t = 0; t < T; ++t) {
        int d = (bits[b][t >> 5] >> (t & 31)) & 1;
        s = (t == 0 || d) ? 0 : s + 1;
        if (t == 0) {
            rows[b] = b;                             // t=0 row of env b
        } else if (s < S0R) {
            int idx = goff[s] + (int)base[b][s];
            base[b][s]++;
            rows[idx] = t * 256 + b;
        } else {
            int idx = tol[s - S0R] + atomicAdd(&tpos[s - S0R], 1);
            trows[idx] = t * 256 + b;
        }
    }
}

// ---------------------------------------------------------------------------
// Fused LSTM round (s < 12): gates = [h_prev ; h2] @ [Whh|Wih]^T + bsum.
// r5: 2-deep stage-ahead pipeline (counted vmcnt(4), loads span a full
// iteration) + LDS union (staging dbuf 32KB aliases the 34.8KB Gx exchange
// buffer -> 36KB total -> 4 blocks/CU, was 3).  kbeg in {0,16} is even so
// staging-buffer parity == k&1 (static under unroll-2).
// ---------------------------------------------------------------------------
__global__ __launch_bounds__(256, 4)
void lstm_round(const int* __restrict__ rows, const int* __restrict__ counts,
                const int* __restrict__ offs, int s,
                const unsigned short* __restrict__ H2,
                const unsigned short* __restrict__ Wcat,
                const float* __restrict__ bsum,
                const unsigned short* __restrict__ h_init,
                const unsigned short* __restrict__ c_init,
                const unsigned short* __restrict__ zbuf,
                unsigned short* __restrict__ Hraw, unsigned short* __restrict__ Cst,
                unsigned short* __restrict__ Hnew)
{
    const int M = counts[s];
    if (M == 0) return;
    const int off    = offs[s];
    const int mtiles = (M + 127) >> 7;

    // union: [0,16384) = staging dbuf (buf b: A at b*8192, B at b*8192+4096);
    //        [0,17408) = Gx gate-exchange (live only after the K-loop)
    __shared__ __align__(16) unsigned short U[17408];
    __shared__ float bls[128];
    __shared__ int rl[128];
    unsigned short* const Gx = U;

    const int tid  = threadIdx.x;
    const int w    = tid >> 6;
    const int lane = tid & 63;
    const int quad = lane >> 4;
    const int lr   = lane & 15;
    const int wm   = w & 1, wn = w >> 1;
    const int c0   = blockIdx.x * 32;
    const int srow = lane >> 2;
    const int kblk = (lane & 3) ^ ((lane >> 3) & 3);

    if (tid < 128) bls[tid] = bsum[(tid >> 5) * 512 + c0 + (tid & 31)];

    const int br0 = w * 16 + srow;
    const int br1 = 64 + br0;
    const unsigned short* gB0 = Wcat + (size_t)((br0 >> 5) * 512 + c0 + (br0 & 31)) * 1024 + kblk * 8;
    const unsigned short* gB1 = Wcat + (size_t)((br1 >> 5) * 512 + c0 + (br1 & 31)) * 1024 + kblk * 8;

    const int swz = (quad ^ ((lr >> 1) & 3)) * 8;
    int aoff[4], boff[4];
    #pragma unroll
    for (int i = 0; i < 4; ++i) {
        aoff[i] = (wm * 64 + i * 16 + lr) * 32 + swz;
        boff[i] = (wn * 64 + i * 16 + lr) * 32 + swz;
    }

    for (int mt = blockIdx.y; mt < mtiles; mt += gridDim.y) {
        __syncthreads();                      // drains prior stores/reads (vmcnt 0)
        if (tid < 128) {
            int li = mt * 128 + tid;
            rl[tid] = (li < M) ? rows[off + li] : -1;
        }
        __syncthreads();

        // round 0, tiles past the 256 t=0 rows: all h_prev are zero -> skip h-half
        const int kbeg = (s == 0 && mt * 128 >= 256) ? 16 : 0;

        int g0r = rl[w * 16 + srow];
        int g1r = rl[64 + w * 16 + srow];
        const unsigned short* gA0h;
        const unsigned short* gA1h;
        if (s == 0) {
            gA0h = (g0r >= 0 && g0r < 256) ? h_init + (size_t)g0r * 512 + kblk * 8 : zbuf + kblk * 8;
            gA1h = (g1r >= 0 && g1r < 256) ? h_init + (size_t)g1r * 512 + kblk * 8 : zbuf + kblk * 8;
        } else {
            gA0h = (g0r >= 0) ? Hraw + (size_t)(g0r - 256) * 512 + kblk * 8 : zbuf + kblk * 8;
            gA1h = (g1r >= 0) ? Hraw + (size_t)(g1r - 256) * 512 + kblk * 8 : zbuf + kblk * 8;
        }
        const unsigned short* gA0x = (g0r >= 0) ? H2 + (size_t)g0r * 512 + kblk * 8 : zbuf + kblk * 8;
        const unsigned short* gA1x = (g1r >= 0) ? H2 + (size_t)g1r * 512 + kblk * 8 : zbuf + kblk * 8;

        auto STG = [&](int b, int k) {
            const unsigned short* a0 = (k < 16) ? gA0h + k * 32 : gA0x + (k - 16) * 32;
            const unsigned short* a1 = (k < 16) ? gA1h + k * 32 : gA1x + (k - 16) * 32;
            unsigned short* base = U + b * 8192;
            gld_lds16(a0, base + (w * 16) * 32);
            gld_lds16(a1, base + (64 + w * 16) * 32);
            gld_lds16(gB0 + k * 32, base + 4096 + (w * 16) * 32);
            gld_lds16(gB1 + k * 32, base + 4096 + (64 + w * 16) * 32);
        };

        v4f zz = {0.f, 0.f, 0.f, 0.f};
        v4f acc[4][4] = {{zz,zz,zz,zz},{zz,zz,zz,zz},{zz,zz,zz,zz},{zz,zz,zz,zz}};

        STG(0, kbeg);                          // kbeg even -> parity 0
        #pragma unroll 2
        for (int k = kbeg; k < 32; ++k) {
            if (k < 31) {
                STG((k + 1) & 1, k + 1);       // stage-ahead: loads span this iter
                asm volatile("s_waitcnt vmcnt(4)" ::: "memory");   // stage k landed
            } else {
                asm volatile("s_waitcnt vmcnt(0)" ::: "memory");
            }
            __builtin_amdgcn_s_barrier();
            __builtin_amdgcn_sched_barrier(0);
            const unsigned short* Ab = U + (k & 1) * 8192;
            const unsigned short* Bb = Ab + 4096;
            v8s a[4], b[4];
            #pragma unroll
            for (int i = 0; i < 4; ++i) { a[i] = *(const v8s*)&Ab[aoff[i]]; b[i] = *(const v8s*)&Bb[boff[i]]; }
            __builtin_amdgcn_s_setprio(1);
            #pragma unroll
            for (int i = 0; i < 4; ++i)
                #pragma unroll
                for (int j = 0; j < 4; ++j)
                    acc[i][j] = __builtin_amdgcn_mfma_f32_16x16x32_bf16(a[i], b[j], acc[i][j], 0, 0, 0);
            __builtin_amdgcn_s_setprio(0);
            __builtin_amdgcn_s_barrier();      // reads of buf (k&1) done before re-stage
            __builtin_amdgcn_sched_barrier(0);
        }

        // gate exchange into Gx (aliases the now-dead staging buffers)
        #pragma unroll
        for (int j = 0; j < 4; ++j) {
            const int nl = wn * 64 + j * 16 + lr;
            #pragma unroll
            for (int i = 0; i < 4; ++i)
                #pragma unroll
                for (int r = 0; r < 4; ++r)
                    Gx[(wm * 64 + i * 16 + quad * 4 + r) * 136 + nl] = f2bf(acc[i][j][r]);
        }
        __syncthreads();

        {
            const int rloc = tid >> 1;
            const int half = tid & 1;
            const int gr   = rl[rloc];
            if (gr >= 0) {
                #pragma unroll
                for (int ch = 0; ch < 2; ++ch) {
                    const int co = half * 16 + ch * 8;
                    const int kg = c0 + co;
                    v8s q0 = *(const v8s*)&Gx[rloc * 136 +   0 + co];
                    v8s q1 = *(const v8s*)&Gx[rloc * 136 +  32 + co];
                    v8s q2 = *(const v8s*)&Gx[rloc * 136 +  64 + co];
                    v8s q3 = *(const v8s*)&Gx[rloc * 136 +  96 + co];
                    v8s h2v = *(const v8s*)&H2[(size_t)gr * 512 + kg];
                    float cprev[8];
                    if (s == 0) {
                        if (gr < 256) {
                            v8s cv = *(const v8s*)&c_init[(size_t)gr * 512 + kg];
                            #pragma unroll
                            for (int e = 0; e < 8; ++e) cprev[e] = bf2f((unsigned short)cv[e]);
                        } else {
                            #pragma unroll
                            for (int e = 0; e < 8; ++e) cprev[e] = 0.f;
                        }
                    } else {
                        v8s cv = *(const v8s*)&Cst[(size_t)(gr - 256) * 512 + kg];
                        #pragma unroll
                        for (int e = 0; e < 8; ++e) cprev[e] = bf2f((unsigned short)cv[e]);
                    }
                    unsigned short hc[8], cc[8], hn[8];
                    #pragma unroll
                    for (int e = 0; e < 8; ++e) {
                        float gi = bf2f((unsigned short)q0[e]) + bls[ 0 + co + e];
                        float gf = bf2f((unsigned short)q1[e]) + bls[32 + co + e];
                        float gg = bf2f((unsigned short)q2[e]) + bls[64 + co + e];
                        float go = bf2f((unsigned short)q3[e]) + bls[96 + co + e];
                        float c  = fsig(gf) * cprev[e] + fsig(gi) * ftanh(gg);
                        float h  = fsig(go) * ftanh(c);
                        cc[e] = f2bf(c);
                        hc[e] = f2bf(h);
                        hn[e] = f2bf(h + bf2f((unsigned short)h2v[e]));
                    }
                    *(v8s*)&Cst[(size_t)gr * 512 + kg]  = *(const v8s*)cc;
                    *(v8s*)&Hraw[(size_t)gr * 512 + kg] = *(const v8s*)hc;
                    *(v8s*)&Hnew[(size_t)gr * 512 + kg] = *(const v8s*)hn;
                }
            }
        }
    }
}

// ---------------------------------------------------------------------------
// Tail (s >= 12): 64 WGs, resident [Whh|Wih] slice (32 rows x 1024 = 64 KB),
// K=1024 over [h_prev ; h2]; device-scope spin barrier between levels.
// ---------------------------------------------------------------------------
__global__ __launch_bounds__(256, 1)
void lstm_tail(const int* __restrict__ trows, const int* __restrict__ tcnt,
               const int* __restrict__ toffs, const int* __restrict__ maxS_p,
               const unsigned short* __restrict__ H2,
               const unsigned short* __restrict__ Wcat,
               const float* __restrict__ bsum,
               unsigned short* __restrict__ Hraw, unsigned short* __restrict__ Cst,
               unsigned short* __restrict__ Hnew,
               int* __restrict__ bar)
{
    const int mS = *maxS_p;
    if (mS < S0R) return;
    __shared__ __align__(16) unsigned short Wl[32 * 1024];   // 64 KB
    __shared__ __align__(16) unsigned short Hb[16 * 1024];   // 32 KB
    __shared__ float Gb[16 * 32];
    __shared__ float bl[32];
    __shared__ int rl[16];
    const int j    = blockIdx.x;
    const int tid  = threadIdx.x;
    const int w    = tid >> 6;
    const int lane = tid & 63;
    const int quad = lane >> 4;
    const int lr   = lane & 15;

    if (tid < 32) bl[tid] = bsum[(tid >> 3) * 512 + j * 8 + (tid & 7)];

    for (int e = tid; e < 32 * 128; e += 256) {
        int n = e >> 7, kb = e & 127;
        int g = n >> 3, c = n & 7;
        *(v8s*)&Wl[n * 1024 + kb * 8] = *(const v8s*)&Wcat[(size_t)(g * 512 + j * 8 + c) * 1024 + kb * 8];
    }

    int target = 0;
    for (int s = S0R; s <= mS; ++s) {
        const int lev = s - S0R;
        const int M   = tcnt[lev];
        const int off = toffs[lev];
        for (int ch = 0; ch < M; ch += 16) {
            __syncthreads();
            if (tid < 16) rl[tid] = (ch + tid < M) ? trows[off + ch + tid] : -1;
            __syncthreads();
            {   // stage [h_prev ; h2] rows
                int r = tid >> 4, seg = (tid & 15) * 32;
                int gr = rl[r];
                if (gr >= 0) {
                    const unsigned short* srcH = &Hraw[(size_t)(gr - 256) * 512 + seg];
                    const unsigned short* srcX = &H2[(size_t)gr * 512 + seg];
                    #pragma unroll
                    for (int q = 0; q < 4; ++q) {
                        *(v8s*)&Hb[r * 1024 + seg + q * 8]       = *(const v8s*)(srcH + q * 8);
                        *(v8s*)&Hb[r * 1024 + 512 + seg + q * 8] = *(const v8s*)(srcX + q * 8);
                    }
                } else {
                    v8s z = {0,0,0,0,0,0,0,0};
                    #pragma unroll
                    for (int q = 0; q < 4; ++q) {
                        *(v8s*)&Hb[r * 1024 + seg + q * 8]       = z;
                        *(v8s*)&Hb[r * 1024 + 512 + seg + q * 8] = z;
                    }
                }
            }
            __syncthreads();
            if (w < 2) {
                v4f acc = {0.f, 0.f, 0.f, 0.f};
                for (int k = 0; k < 32; ++k) {
                    v8s a = *(const v8s*)&Hb[lr * 1024 + k * 32 + quad * 8];
                    v8s b = *(const v8s*)&Wl[(w * 16 + lr) * 1024 + k * 32 + quad * 8];
                    acc = __builtin_amdgcn_mfma_f32_16x16x32_bf16(a, b, acc, 0, 0, 0);
                }
                #pragma unroll
                for (int r = 0; r < 4; ++r)
                    Gb[(quad * 4 + r) * 32 + w * 16 + lr] = acc[r];
            }
            __syncthreads();
            if (tid < 128) {
                int r = tid >> 3, c = tid & 7;
                int gr = rl[r];
                if (gr >= 0) {
                    int k = j * 8 + c;
                    float gi = Gb[r * 32 +  0 + c] + bl[ 0 + c];
                    float gf = Gb[r * 32 +  8 + c] + bl[ 8 + c];
                    float gg = Gb[r * 32 + 16 + c] + bl[16 + c];
                    float go = Gb[r * 32 + 24 + c] + bl[24 + c];
                    float cp = bf2f(Cst[(size_t)(gr - 256) * 512 + k]);
                    float cc = fsig(gf) * cp + fsig(gi) * ftanh(gg);
                    float hh = fsig(go) * ftanh(cc);
                    Cst[(size_t)gr * 512 + k]  = f2bf(cc);
                    Hraw[(size_t)gr * 512 + k] = f2bf(hh);
                    Hnew[(size_t)gr * 512 + k] = f2bf(hh + bf2f(H2[(size_t)gr * 512 + k]));
                }
            }
        }
        target += 64;
        __threadfence();
        __syncthreads();
        if (tid == 0) {
            __hip_atomic_fetch_add(bar, 1, __ATOMIC_RELEASE, __HIP_MEMORY_SCOPE_AGENT);
            while (__hip_atomic_load(bar, __ATOMIC_ACQUIRE, __HIP_MEMORY_SCOPE_AGENT) < target) {}
        }
        __syncthreads();
        __threadfence();
    }
}

// actor head: one wave per row over bf16 logits (stride 1024, 1000 valid)
__global__ void head_reduce(const unsigned short* __restrict__ logits,
                            const int* __restrict__ action,
                            float* __restrict__ out, int TB)
{
    const int r = blockIdx.x * 4 + (threadIdx.x >> 6);
    const int lane = threadIdx.x & 63;
    const unsigned short* row = logits + (size_t)r * 1024;
    float m = -1e30f, Z = 0.f, S = 0.f;
    v8s v0 = *(const v8s*)&row[lane * 8];
    #pragma unroll
    for (int e = 0; e < 8; ++e) {
        float xv = bf2f((unsigned short)v0[e]);
        if (xv > m) { float sc = __builtin_amdgcn_exp2f((m - xv) * L2E); Z *= sc; S *= sc; m = xv; }
        float ev = __builtin_amdgcn_exp2f((xv - m) * L2E);
        Z += ev; S += xv * ev;
    }
    v8s v1 = *(const v8s*)&row[512 + lane * 8];
    #pragma unroll
    for (int e = 0; e < 8; ++e) {
        int c = 512 + lane * 8 + e;
        if (c < 1000) {
            float xv = bf2f((unsigned short)v1[e]);
            if (xv > m) { float sc = __builtin_amdgcn_exp2f((m - xv) * L2E); Z *= sc; S *= sc; m = xv; }
            float ev = __builtin_amdgcn_exp2f((xv - m) * L2E);
            Z += ev; S += xv * ev;
        }
    }
    #pragma unroll
    for (int offb = 32; offb > 0; offb >>= 1) {
        float m2 = __shfl_xor(m, offb);
        float Z2 = __shfl_xor(Z, offb);
        float S2 = __shfl_xor(S, offb);
        float M  = fmaxf(m, m2);
        float s1 = __builtin_amdgcn_exp2f((m - M) * L2E), s2 = __builtin_amdgcn_exp2f((m2 - M) * L2E);
        Z = Z * s1 + Z2 * s2;
        S = S * s1 + S2 * s2;
        m = M;
    }
    if (lane == 0) {
        float lse = m + 0.6931471805599453f * __builtin_amdgcn_logf(Z);
        float xa  = bf2f(row[action[r]]);
        out[r]      = xa - lse;
        out[TB + r] = lse - S / Z;
    }
}

// critic head over fused AC1 (stride 1024, critic half at +512)
__global__ void critic_v(const unsigned short* __restrict__ AC, const float* __restrict__ Wc2,
                         const float* __restrict__ bc2, float* __restrict__ out, int TB)
{
    const int r = blockIdx.x * 4 + (threadIdx.x >> 6);
    const int lane = threadIdx.x & 63;
    const unsigned short* row = AC + (size_t)r * 1024 + 512;
    v8s hv = *(const v8s*)&row[lane * 8];
    float4 w0 = *(const float4*)&Wc2[lane * 8];
    float4 w1 = *(const float4*)&Wc2[lane * 8 + 4];
    float s = bf2f((unsigned short)hv[0]) * w0.x + bf2f((unsigned short)hv[1]) * w0.y +
              bf2f((unsigned short)hv[2]) * w0.z + bf2f((unsigned short)hv[3]) * w0.w +
              bf2f((unsigned short)hv[4]) * w1.x + bf2f((unsigned short)hv[5]) * w1.y +
              bf2f((unsigned short)hv[6]) * w1.z + bf2f((unsigned short)hv[7]) * w1.w;
    #pragma unroll
    for (int offb = 32; offb > 0; offb >>= 1) s += __shfl_xor(s, offb);
    if (lane == 0) out[2 * TB + r] = s + bc2[0];
}

extern "C" void kernel_launch(void* const* d_in, const int* in_sizes, int n_in,
                              void* d_out, int out_size, void* d_ws, size_t ws_size,
                              hipStream_t stream)
{
    const float* x    = (const float*)d_in[0];
    const int*  done  = (const int*)d_in[1];
    const int*  action= (const int*)d_in[2];
    const float* W_t1 = (const float*)d_in[4];
    const float* b_t1 = (const float*)d_in[5];
    const float* W_t2 = (const float*)d_in[6];
    const float* b_t2 = (const float*)d_in[7];
    const float* Wih  = (const float*)d_in[8];
    const float* Whh  = (const float*)d_in[9];
    const float* bih  = (const float*)d_in[10];
    const float* bhh  = (const float*)d_in[11];
    const float* Wa1  = (const float*)d_in[12];
    const float* ba1  = (const float*)d_in[13];
    const float* Wa2  = (const float*)d_in[14];
    const float* ba2  = (const float*)d_in[15];
    const float* Wc1  = (const float*)d_in[16];
    const float* bc1  = (const float*)d_in[17];
    const float* Wc2  = (const float*)d_in[18];
    const float* bc2  = (const float*)d_in[19];
    const float* h0   = (const float*)d_in[20];
    const float* c0   = (const float*)d_in[21];
    float* out = (float*)d_out;

    const int TB = in_sizes[1];      // 65536
    const int T  = TB / 256;         // 256

    const size_t MiB = 1024 * 1024;
    char* ws = (char*)d_ws;
    unsigned short* H1     = (unsigned short*)(ws);               // 64 MiB (trunk tmp)
    unsigned short* Hnew   = (unsigned short*)(ws);               // alias: H1 dead before rounds
    unsigned short* logits = (unsigned short*)(ws);               // alias: Hnew dead after AC1
    unsigned short* AC1    = (unsigned short*)(ws + 128 * MiB);   // 128 MiB
    unsigned short* Cst    = (unsigned short*)(ws + 256 * MiB);   // 64 MiB
    unsigned short* H2     = (unsigned short*)(ws + 320 * MiB);   // 64 MiB
    unsigned short* Hraw   = (unsigned short*)(ws + 384 * MiB);   // 64 MiB
    unsigned short* xbf    = Hraw;                                 // alias (x dead after trunk1)
    unsigned short* Wt1b   = (unsigned short*)(ws + 448 * MiB);
    unsigned short* Wt2b   = Wt1b + 512 * 512;
    unsigned short* Wcat   = Wt2b + 512 * 512;                     // 2048 x 1024
    unsigned short* Wacb   = Wcat + 2048 * 1024;                   // 1024 x 512
    unsigned short* Wa2b   = Wacb + 1024 * 512;                    // 1024 x 512
    unsigned short* h_init = Wa2b + 1024 * 512;
    unsigned short* c_init = h_init + 256 * 512;
    unsigned short* zbuf   = c_init + 256 * 512;
    int* rows   = (int*)(zbuf + 512);
    int* trows  = rows + 65536;
    int* counts = trows + 65536;
    int* offs   = counts + S0R;
    int* tcnt   = offs + S0R;
    int* toffs  = tcnt + NLEV;
    int* maxS   = toffs + NLEV;
    int* bar    = maxS + 1;
    float* bsum = (float*)(bar + 1);          // 2048 f32
    float* bac  = bsum + 2048;                // 1024 f32

    dim3 blk(256);
    dim3 blk5(512);

    // dtype conversions + weight packing + init + segment lists
    cvt8<<<16384, blk, 0, stream>>>(x, xbf);
    cvt8<<<128,  blk, 0, stream>>>(W_t1, Wt1b);
    cvt8<<<128,  blk, 0, stream>>>(W_t2, Wt2b);
    cvt_cat<<<1024, blk, 0, stream>>>(Whh, Wih, Wcat);
    cvt8<<<128,  blk, 0, stream>>>(Wa1, Wacb);
    cvt8<<<128,  blk, 0, stream>>>(Wc1, Wacb + 512 * 512);
    wa2pad<<<2048, blk, 0, stream>>>(Wa2, Wa2b);
    prep_misc<<<12, blk, 0, stream>>>(bih, bhh, ba1, bc1, bsum, bac);
    init_state<<<256, blk, 0, stream>>>(h0, c0, done, h_init, c_init, zbuf);
    seg_prep<<<1, blk, 0, stream>>>(done, rows, counts, offs, trows, tcnt, toffs, maxS, bar, T);

    // trunk
    gemm256<true ><<<512, blk5, 0, stream>>>(xbf, Wt1b, b_t1, H1, 512, 512, 2, 512);
    gemm256<true ><<<512, blk5, 0, stream>>>(H1,  Wt2b, b_t2, H2, 512, 512, 2, 512);

    // segment-parallel LSTM, x-gates fused (K=1024), residual fused into epilogue
    static const int Gs[S0R] = {256, 128, 64, 32, 16, 8, 4, 2, 1, 1, 1, 1};
    for (int s = 0; s < S0R; ++s)
        lstm_round<<<dim3(16, Gs[s]), blk, 0, stream>>>(rows, counts, offs, s, H2, Wcat, bsum,
                                                        h_init, c_init, zbuf, Hraw, Cst, Hnew);
    lstm_tail<<<64, blk, 0, stream>>>(trows, tcnt, toffs, maxS, H2, Wcat, bsum, Hraw, Cst, Hnew, bar);

    // fused actor/critic first layers: AC1 = tanh(Hnew @ [Wa1;Wc1]^T + [ba1;bc1])
    gemm256<true ><<<1024, blk5, 0, stream>>>(Hnew, Wacb, bac, AC1, 1024, 1024, 4, 512);

    // actor logits from A1 half (stride-1024 A)
    gemm256<false><<<1024, blk5, 0, stream>>>(AC1, Wa2b, ba2, logits, 1000, 1024, 4, 1024);
    head_reduce<<<TB / 4, blk, 0, stream>>>(logits, action, out, TB);

    // critic from C1 half
    critic_v<<<TB / 4, blk, 0, stream>>>(AC1, Wc2, bc2, out, TB);
}

// Round 6
// 1262.678 us; speedup vs baseline: 1.4918x; 1.0569x over previous
//
#include <hip/hip_runtime.h>
#include <hip/hip_bf16.h>

typedef short v8s __attribute__((ext_vector_type(8)));
typedef float v4f __attribute__((ext_vector_type(4)));

#define S0R 12      // rounds 0..11 via gather-GEMM; lstm_tail covers s >= 12
#define NLEV 244    // tail levels 12..255
#define L2E 1.4426950408889634f

__device__ __forceinline__ float bf2f(unsigned short u) {
    union { unsigned int i; float f; } v; v.i = ((unsigned int)u) << 16; return v.f;
}
__device__ __forceinline__ unsigned short f2bf(float f) {
    union { float f; unsigned int i; } v; v.f = f;
    unsigned int x = v.i;
    return (unsigned short)((x + 0x7fffu + ((x >> 16) & 1u)) >> 16);
}
// fast sigmoid/tanh: v_exp_f32 + v_rcp_f32 (1-2 ulp; invisible under bf16)
__device__ __forceinline__ float fsig(float x) {
    return __builtin_amdgcn_rcpf(1.f + __builtin_amdgcn_exp2f(-L2E * x));
}
__device__ __forceinline__ float ftanh(float x) {
    return 2.f * __builtin_amdgcn_rcpf(1.f + __builtin_amdgcn_exp2f((-2.f * L2E) * x)) - 1.f;
}

// async global->LDS, 16B per lane; LDS dst is wave-uniform base + lane*16
__device__ __forceinline__ void gld_lds16(const unsigned short* g, unsigned short* l) {
    __builtin_amdgcn_global_load_lds(
        (const __attribute__((address_space(1))) unsigned int*)g,
        (__attribute__((address_space(3))) unsigned int*)l, 16, 0, 0);
}

// ---------------------------------------------------------------------------
// gemm256: C[M,Npad] = act(A[.,Astr][:512] @ W[Npad,512]^T + b1), bf16.
// 256x256 tile, BK=64, 8 waves, 8-phase counted-vmcnt schedule, XOR-swizzled
// LDS, setprio, XCD-chunked swizzle.  Epilogue via LDS -> coalesced stores.
// ---------------------------------------------------------------------------
template <bool TANH>
__global__ __launch_bounds__(512, 2)
void gemm256(const unsigned short* __restrict__ Ag, const unsigned short* __restrict__ Wg,
             const float* __restrict__ b1,
             unsigned short* __restrict__ Cg, int Nreal, int Npad, int Ntiles, int Astr)
{
    __shared__ __align__(16) unsigned short As[2][256 * 64];   // 64 KB
    __shared__ __align__(16) unsigned short Bs[2][256 * 64];   // 64 KB

    const int tid  = threadIdx.x;
    const int w    = tid >> 6;          // 0..7
    const int lane = tid & 63;
    const int quad = lane >> 4;
    const int lr   = lane & 15;
    const int wm   = w >> 2;            // 0..1
    const int wn   = w & 3;             // 0..3

    const int nwg = gridDim.x;
    const int cpx = nwg >> 3;
    const int swz = (blockIdx.x & 7) * cpx + (blockIdx.x >> 3);
    const int m0  = (swz / Ntiles) * 256;
    const int n0  = (swz % Ntiles) * 256;

    const unsigned short* gA = Ag + (size_t)m0 * Astr;
    const unsigned short* gB = Wg + (size_t)n0 * 512;

    const int sr  = w * 8 + (lane >> 3);
    const int skg = (lane & 7) ^ ((lane >> 3) & 7);

    auto SA = [&](int buf, int u, int kt) {
        gld_lds16(gA + (size_t)(u * 64 + sr) * Astr + kt * 64 + skg * 8,
                  &As[buf][(u * 64 + w * 8) * 64]);
    };
    auto SB = [&](int buf, int u, int kt) {
        gld_lds16(gB + (size_t)(u * 64 + sr) * 512 + kt * 64 + skg * 8,
                  &Bs[buf][(u * 64 + w * 8) * 64]);
    };

    const int g8_0  = (quad ^ (lr & 7)) * 8;
    const int g8_1  = ((quad + 4) ^ (lr & 7)) * 8;
    const int aBase = (wm * 128 + lr) * 64;
    const int bBase = (wn * 64 + lr) * 64;

    v4f zz = {0.f, 0.f, 0.f, 0.f};
    v4f acc[8][4];
    #pragma unroll
    for (int m = 0; m < 8; ++m)
        #pragma unroll
        for (int n = 0; n < 4; ++n) acc[m][n] = zz;
    v8s Bf[4][2];

#define DSB(BUF)                                                         \
    _Pragma("unroll")                                                    \
    for (int n = 0; n < 4; ++n) {                                        \
        Bf[n][0] = *(const v8s*)&Bs[BUF][bBase + n * 1024 + g8_0];       \
        Bf[n][1] = *(const v8s*)&Bs[BUF][bBase + n * 1024 + g8_1];       \
    }

#define PH(BUF, Q, STMTS, PREBAR)                                                     \
    {                                                                                 \
        const v8s a00 = *(const v8s*)&As[BUF][aBase + ((Q)*2 + 0) * 1024 + g8_0];     \
        const v8s a01 = *(const v8s*)&As[BUF][aBase + ((Q)*2 + 0) * 1024 + g8_1];     \
        const v8s a10 = *(const v8s*)&As[BUF][aBase + ((Q)*2 + 1) * 1024 + g8_0];     \
        const v8s a11 = *(const v8s*)&As[BUF][aBase + ((Q)*2 + 1) * 1024 + g8_1];     \
        STMTS;                                                                        \
        PREBAR;                                                                       \
        __builtin_amdgcn_s_barrier();                                                 \
        asm volatile("s_waitcnt lgkmcnt(0)" ::: "memory");                            \
        __builtin_amdgcn_sched_barrier(0);                                            \
        __builtin_amdgcn_s_setprio(1);                                                \
        _Pragma("unroll")                                                             \
        for (int n = 0; n < 4; ++n) {                                                 \
            acc[(Q)*2    ][n] = __builtin_amdgcn_mfma_f32_16x16x32_bf16(a00, Bf[n][0], acc[(Q)*2    ][n], 0, 0, 0); \
            acc[(Q)*2    ][n] = __builtin_amdgcn_mfma_f32_16x16x32_bf16(a01, Bf[n][1], acc[(Q)*2    ][n], 0, 0, 0); \
            acc[(Q)*2 + 1][n] = __builtin_amdgcn_mfma_f32_16x16x32_bf16(a10, Bf[n][0], acc[(Q)*2 + 1][n], 0, 0, 0); \
            acc[(Q)*2 + 1][n] = __builtin_amdgcn_mfma_f32_16x16x32_bf16(a11, Bf[n][1], acc[(Q)*2 + 1][n], 0, 0, 0); \
        }                                                                             \
        __builtin_amdgcn_s_setprio(0);                                                \
        __builtin_amdgcn_s_barrier();                                                 \
    }

    SB(0, 0, 0); SB(0, 1, 0); SB(0, 2, 0); SB(0, 3, 0);
    SA(0, 0, 0); SA(0, 2, 0); SA(0, 1, 0); SA(0, 3, 0);
    SB(1, 0, 1); SB(1, 1, 1); SB(1, 2, 1); SB(1, 3, 1);
    SA(1, 0, 1); SA(1, 2, 1);
    asm volatile("s_waitcnt vmcnt(6)" ::: "memory");
    __builtin_amdgcn_s_barrier();

    #pragma unroll
    for (int i = 0; i < 4; ++i) {                 // 2 K-tiles / iteration
        const bool more = (i < 3);
        const int t1 = 2 * i + 1, t2 = 2 * i + 2, t3 = 2 * i + 3;
        PH(0, 0, { DSB(0); SA(1, 1, t1); SA(1, 3, t1); }, )
        PH(0, 1, { if (more) { SB(0, 0, t2); SB(0, 1, t2); } }, )
        PH(0, 2, { if (more) { SB(0, 2, t2); SB(0, 3, t2); } }, )
        PH(0, 3, { if (more) { SA(0, 0, t2); SA(0, 2, t2); } },
           if (more) { asm volatile("s_waitcnt vmcnt(6)" ::: "memory"); }
           else      { asm volatile("s_waitcnt vmcnt(0)" ::: "memory"); } )
        PH(1, 0, { DSB(1); if (more) { SA(0, 1, t2); SA(0, 3, t2); } }, )
        PH(1, 1, { if (more) { SB(1, 0, t3); SB(1, 1, t3); } }, )
        PH(1, 2, { if (more) { SB(1, 2, t3); SB(1, 3, t3); } }, )
        PH(1, 3, { if (more) { SA(1, 0, t3); SA(1, 2, t3); } },
           if (more) { asm volatile("s_waitcnt vmcnt(6)" ::: "memory"); } )
    }
#undef PH
#undef DSB

    // ---- epilogue: acc -> LDS (swizzled bf16 [256][256]) -> coalesced flush
    __syncthreads();
    unsigned short* Ct = wm ? &Bs[0][0] : &As[0][0];
    #pragma unroll
    for (int n = 0; n < 4; ++n) {
        const int nn = n0 + wn * 64 + n * 16 + lr;
        const float bias = (nn < Nreal) ? b1[nn] : 0.f;
        const int col = wn * 64 + n * 16 + lr;
        #pragma unroll
        for (int m = 0; m < 8; ++m) {
            #pragma unroll
            for (int r = 0; r < 4; ++r) {
                const int row = m * 16 + quad * 4 + r;
                float v = acc[m][n][r] + bias;
                if (TANH) v = ftanh(v);
                Ct[row * 256 + (((col >> 3) ^ (row & 7)) << 3) + (col & 7)] = f2bf(v);
            }
        }
    }
    __syncthreads();
    #pragma unroll
    for (int it = 0; it < 16; ++it) {
        const int c   = it * 512 + tid;
        const int row = c >> 5;
        const int gc  = c & 31;
        const unsigned short* src = (row < 128)
            ? &As[0][row * 256 + ((gc ^ (row & 7)) << 3)]
            : &Bs[0][(row - 128) * 256 + ((gc ^ (row & 7)) << 3)];
        v8s val = *(const v8s*)src;
        *(v8s*)&Cg[(size_t)(m0 + row) * Npad + n0 + gc * 8] = val;
    }
}

// fp32 -> bf16, 8 elems/thread (n must be multiple of 2048)
__global__ void cvt8(const float* __restrict__ src, unsigned short* __restrict__ dst)
{
    const size_t i = ((size_t)blockIdx.x * 256 + threadIdx.x) * 8;
    float4 f0 = *(const float4*)(src + i);
    float4 f1 = *(const float4*)(src + i + 4);
    unsigned short t8[8];
    t8[0]=f2bf(f0.x); t8[1]=f2bf(f0.y); t8[2]=f2bf(f0.z); t8[3]=f2bf(f0.w);
    t8[4]=f2bf(f1.x); t8[5]=f2bf(f1.y); t8[6]=f2bf(f1.z); t8[7]=f2bf(f1.w);
    *(v8s*)(dst + i) = *(const v8s*)t8;
}

// Wcat[2048][1024] = [Whh | Wih] bf16 (K-dim concat), 8 elems/thread, grid 1024
__global__ void cvt_cat(const float* __restrict__ Whh, const float* __restrict__ Wih,
                        unsigned short* __restrict__ Wcat)
{
    const size_t i = ((size_t)blockIdx.x * 256 + threadIdx.x) * 8;
    const int row = (int)(i >> 10), col = (int)(i & 1023);
    const float* src = (col < 512) ? &Whh[(size_t)row * 512 + col]
                                   : &Wih[(size_t)row * 512 + (col - 512)];
    float4 f0 = *(const float4*)src;
    float4 f1 = *(const float4*)(src + 4);
    unsigned short t8[8];
    t8[0]=f2bf(f0.x); t8[1]=f2bf(f0.y); t8[2]=f2bf(f0.z); t8[3]=f2bf(f0.w);
    t8[4]=f2bf(f1.x); t8[5]=f2bf(f1.y); t8[6]=f2bf(f1.z); t8[7]=f2bf(f1.w);
    *(v8s*)(Wcat + i) = *(const v8s*)t8;
}

// Wa2 (1000x512 fp32) -> zero-padded 1024x512 bf16
__global__ void wa2pad(const float* __restrict__ src, unsigned short* __restrict__ dst)
{
    const int i = blockIdx.x * 256 + threadIdx.x;
    const int row = i >> 9;
    dst[i] = (row < 1000) ? f2bf(src[(size_t)row * 512 + (i & 511)]) : (unsigned short)0;
}

// bsum[2048] = bih+bhh ; bac[1024] = [ba1 ; bc1]   (grid 12 x 256)
__global__ void prep_misc(const float* __restrict__ bih, const float* __restrict__ bhh,
                          const float* __restrict__ ba1, const float* __restrict__ bc1,
                          float* __restrict__ bsum, float* __restrict__ bac)
{
    const int i = blockIdx.x * 256 + threadIdx.x;
    if (i < 2048) bsum[i] = bih[i] + bhh[i];
    else if (i < 3072) {
        int k = i - 2048;
        bac[k] = (k < 512) ? ba1[k] : bc1[k - 512];
    }
}

// masked initial state (bf16) + zero row buffer
__global__ void init_state(const float* __restrict__ h0, const float* __restrict__ c0,
                           const int* __restrict__ done,
                           unsigned short* __restrict__ h_init, unsigned short* __restrict__ c_init,
                           unsigned short* __restrict__ zbuf)
{
    const int b = blockIdx.x;
    const float m = 1.f - (float)done[b];
    for (int k = threadIdx.x; k < 512; k += 256) {
        h_init[(size_t)b * 512 + k] = f2bf(h0[(size_t)b * 512 + k] * m);
        c_init[(size_t)b * 512 + k] = f2bf(c0[(size_t)b * 512 + k] * m);
        if (b == 0) zbuf[k] = 0;
    }
}

// ---------------------------------------------------------------------------
// Segment prep (single WG).  8x-unrolled done loads; s=0 list has the 256
// t=0 rows FIRST so round-0 tiles with mt*128>=256 skip the h-half of K.
// ---------------------------------------------------------------------------
__global__ __launch_bounds__(256, 1)
void seg_prep(const int* __restrict__ done, int* __restrict__ rows,
              int* __restrict__ counts, int* __restrict__ offs,
              int* __restrict__ trows, int* __restrict__ tcnt, int* __restrict__ toffs,
              int* __restrict__ maxS, int* __restrict__ bar, int T)
{
    __shared__ unsigned int   bits[256][8];
    __shared__ unsigned short cnt[256][S0R];
    __shared__ unsigned short base[256][S0R];
    __shared__ int tot[S0R];
    __shared__ int goff[S0R];
    __shared__ int tcl[NLEV];
    __shared__ int tol[NLEV];
    __shared__ int tpos[NLEV];
    __shared__ int mxl[256];
    const int b = threadIdx.x;
    #pragma unroll
    for (int s = 0; s < S0R; ++s) cnt[b][s] = 0;
    #pragma unroll
    for (int i = 0; i < 8; ++i) bits[b][i] = 0;
    for (int l = b; l < NLEV; l += 256) { tcl[l] = 0; tpos[l] = 0; }
    __syncthreads();

    int s = 0, mx = 0;
    for (int t0 = 0; t0 < T; t0 += 8) {
        int d8[8];
        #pragma unroll
        for (int i = 0; i < 8; ++i) d8[i] = done[(t0 + i) * 256 + b];
        #pragma unroll
        for (int i = 0; i < 8; ++i) {
            const int t = t0 + i, d = d8[i];
            if (d) bits[b][t >> 5] |= (1u << (t & 31));
            s = (t == 0 || d) ? 0 : s + 1;
            if (s < S0R) { if (t != 0) cnt[b][s]++; }   // t=0 rows reserved
            else atomicAdd(&tcl[s - S0R], 1);
            mx = mx > s ? mx : s;
        }
    }
    mxl[b] = mx;
    __syncthreads();

    if (b < S0R) {
        int tsum = 0;
        for (int bb = 0; bb < 256; ++bb) { base[bb][b] = (unsigned short)tsum; tsum += cnt[bb][b]; }
        tot[b] = tsum;
    }
    __syncthreads();
    if (b == 0) {
        int run = 256;                               // [0,256) = t=0 rows
        for (int ss = 0; ss < S0R; ++ss) { goff[ss] = run; run += tot[ss]; }
        run = 0;
        for (int l = 0; l < NLEV; ++l) { tol[l] = run; run += tcl[l]; }
        int m = 0;
        for (int bb = 0; bb < 256; ++bb) m = m > mxl[bb] ? m : mxl[bb];
        *maxS = m;
        *bar  = 0;
    }
    __syncthreads();
    if (b < S0R) {
        counts[b] = tot[b] + (b == 0 ? 256 : 0);
        offs[b]   = (b == 0) ? 0 : goff[b];
    }
    for (int l = b; l < NLEV; l += 256) { tcnt[l] = tcl[l]; toffs[l] = tol[l]; }

    s = 0;
    for (int t = 0; t < T; ++t) {
        int d = (bits[b][t >> 5] >> (t & 31)) & 1;
        s = (t == 0 || d) ? 0 : s + 1;
        if (t == 0) {
            rows[b] = b;                             // t=0 row of env b
        } else if (s < S0R) {
            int idx = goff[s] + (int)base[b][s];
            base[b][s]++;
            rows[idx] = t * 256 + b;
        } else {
            int idx = tol[s - S0R] + atomicAdd(&tpos[s - S0R], 1);
            trows[idx] = t * 256 + b;
        }
    }
}

// ---------------------------------------------------------------------------
// Fused LSTM round (s < 12): gates = [h_prev ; h2] @ [Whh|Wih]^T + bsum.
// r6: XCD-cooperative block decode.  Old grid (x=c0 fastest) put the 16
// c0-slices of one row-tile on 8 XCDs -> every gathered A-row filled 8 L2s
// (FETCH 178MB vs ~40 logical) and outputs written as 64B slices from 8
// XCDs (WRITE 180MB vs 101).  New decode: xcd(bid)=bid%8=(r&3)*2+(c0>>3),
// j=bid>>3=(r>>2)*8+(c0&7): each row-tile occupies exactly 2 XCDs (8
// adjacent-dispatch slices each); per XCD Wcat footprint = 2MB (L2-fits),
// A fetched 2x not 8x, each XCD writes a contiguous 256-col half per row.
// Bijective for nrt%4==0 (rounds 0..6); trivial decode for tiny rounds.
// ---------------------------------------------------------------------------
__global__ __launch_bounds__(256, 4)
void lstm_round(const int* __restrict__ rows, const int* __restrict__ counts,
                const int* __restrict__ offs, int s,
                const unsigned short* __restrict__ H2,
                const unsigned short* __restrict__ Wcat,
                const float* __restrict__ bsum,
                const unsigned short* __restrict__ h_init,
                const unsigned short* __restrict__ c_init,
                const unsigned short* __restrict__ zbuf,
                unsigned short* __restrict__ Hraw, unsigned short* __restrict__ Cst,
                unsigned short* __restrict__ Hnew)
{
    const int M = counts[s];
    if (M == 0) return;
    const int off    = offs[s];
    const int mtiles = (M + 127) >> 7;

    // union: [0,16384) = staging dbuf (buf b: A at b*8192, B at b*8192+4096);
    //        [0,17408) = Gx gate-exchange (live only after the K-loop)
    __shared__ __align__(16) unsigned short U[17408];
    __shared__ float bls[128];
    __shared__ int rl[128];
    unsigned short* const Gx = U;

    const int tid  = threadIdx.x;
    const int w    = tid >> 6;
    const int lane = tid & 63;
    const int quad = lane >> 4;
    const int lr   = lane & 15;
    const int wm   = w & 1, wn = w >> 1;
    const int srow = lane >> 2;
    const int kblk = (lane & 3) ^ ((lane >> 3) & 3);

    // XCD-cooperative decode (see header comment)
    const int nrt = gridDim.x >> 4;       // row-tile blocks
    const int bid = blockIdx.x;
    int r0, c0i;
    if (nrt >= 4) {
        const int xcd = bid & 7, j = bid >> 3;
        r0  = (xcd >> 1) + ((j >> 3) << 2);
        c0i = ((xcd & 1) << 3) + (j & 7);
    } else {
        r0  = bid % nrt;
        c0i = bid / nrt;
    }
    const int c0 = c0i * 32;

    if (tid < 128) bls[tid] = bsum[(tid >> 5) * 512 + c0 + (tid & 31)];

    const int br0 = w * 16 + srow;
    const int br1 = 64 + br0;
    const unsigned short* gB0 = Wcat + (size_t)((br0 >> 5) * 512 + c0 + (br0 & 31)) * 1024 + kblk * 8;
    const unsigned short* gB1 = Wcat + (size_t)((br1 >> 5) * 512 + c0 + (br1 & 31)) * 1024 + kblk * 8;

    const int swz = (quad ^ ((lr >> 1) & 3)) * 8;
    int aoff[4], boff[4];
    #pragma unroll
    for (int i = 0; i < 4; ++i) {
        aoff[i] = (wm * 64 + i * 16 + lr) * 32 + swz;
        boff[i] = (wn * 64 + i * 16 + lr) * 32 + swz;
    }

    for (int mt = r0; mt < mtiles; mt += nrt) {
        __syncthreads();                      // drains prior stores/reads (vmcnt 0)
        if (tid < 128) {
            int li = mt * 128 + tid;
            rl[tid] = (li < M) ? rows[off + li] : -1;
        }
        __syncthreads();

        // round 0, tiles past the 256 t=0 rows: all h_prev are zero -> skip h-half
        const int kbeg = (s == 0 && mt * 128 >= 256) ? 16 : 0;

        int g0r = rl[w * 16 + srow];
        int g1r = rl[64 + w * 16 + srow];
        const unsigned short* gA0h;
        const unsigned short* gA1h;
        if (s == 0) {
            gA0h = (g0r >= 0 && g0r < 256) ? h_init + (size_t)g0r * 512 + kblk * 8 : zbuf + kblk * 8;
            gA1h = (g1r >= 0 && g1r < 256) ? h_init + (size_t)g1r * 512 + kblk * 8 : zbuf + kblk * 8;
        } else {
            gA0h = (g0r >= 0) ? Hraw + (size_t)(g0r - 256) * 512 + kblk * 8 : zbuf + kblk * 8;
            gA1h = (g1r >= 0) ? Hraw + (size_t)(g1r - 256) * 512 + kblk * 8 : zbuf + kblk * 8;
        }
        const unsigned short* gA0x = (g0r >= 0) ? H2 + (size_t)g0r * 512 + kblk * 8 : zbuf + kblk * 8;
        const unsigned short* gA1x = (g1r >= 0) ? H2 + (size_t)g1r * 512 + kblk * 8 : zbuf + kblk * 8;

        auto STG = [&](int b, int k) {
            const unsigned short* a0 = (k < 16) ? gA0h + k * 32 : gA0x + (k - 16) * 32;
            const unsigned short* a1 = (k < 16) ? gA1h + k * 32 : gA1x + (k - 16) * 32;
            unsigned short* base = U + b * 8192;
            gld_lds16(a0, base + (w * 16) * 32);
            gld_lds16(a1, base + (64 + w * 16) * 32);
            gld_lds16(gB0 + k * 32, base + 4096 + (w * 16) * 32);
            gld_lds16(gB1 + k * 32, base + 4096 + (64 + w * 16) * 32);
        };

        v4f zz = {0.f, 0.f, 0.f, 0.f};
        v4f acc[4][4] = {{zz,zz,zz,zz},{zz,zz,zz,zz},{zz,zz,zz,zz},{zz,zz,zz,zz}};

        STG(0, kbeg);                          // kbeg even -> parity 0
        #pragma unroll 2
        for (int k = kbeg; k < 32; ++k) {
            if (k < 31) {
                STG((k + 1) & 1, k + 1);       // stage-ahead: loads span this iter
                asm volatile("s_waitcnt vmcnt(4)" ::: "memory");   // stage k landed
            } else {
                asm volatile("s_waitcnt vmcnt(0)" ::: "memory");
            }
            __builtin_amdgcn_s_barrier();
            __builtin_amdgcn_sched_barrier(0);
            const unsigned short* Ab = U + (k & 1) * 8192;
            const unsigned short* Bb = Ab + 4096;
            v8s a[4], b[4];
            #pragma unroll
            for (int i = 0; i < 4; ++i) { a[i] = *(const v8s*)&Ab[aoff[i]]; b[i] = *(const v8s*)&Bb[boff[i]]; }
            __builtin_amdgcn_s_setprio(1);
            #pragma unroll
            for (int i = 0; i < 4; ++i)
                #pragma unroll
                for (int j = 0; j < 4; ++j)
                    acc[i][j] = __builtin_amdgcn_mfma_f32_16x16x32_bf16(a[i], b[j], acc[i][j], 0, 0, 0);
            __builtin_amdgcn_s_setprio(0);
            __builtin_amdgcn_s_barrier();      // reads of buf (k&1) done before re-stage
            __builtin_amdgcn_sched_barrier(0);
        }

        // gate exchange into Gx (aliases the now-dead staging buffers)
        #pragma unroll
        for (int j = 0; j < 4; ++j) {
            const int nl = wn * 64 + j * 16 + lr;
            #pragma unroll
            for (int i = 0; i < 4; ++i)
                #pragma unroll
                for (int r = 0; r < 4; ++r)
                    Gx[(wm * 64 + i * 16 + quad * 4 + r) * 136 + nl] = f2bf(acc[i][j][r]);
        }
        __syncthreads();

        {
            const int rloc = tid >> 1;
            const int half = tid & 1;
            const int gr   = rl[rloc];
            if (gr >= 0) {
                #pragma unroll
                for (int ch = 0; ch < 2; ++ch) {
                    const int co = half * 16 + ch * 8;
                    const int kg = c0 + co;
                    v8s q0 = *(const v8s*)&Gx[rloc * 136 +   0 + co];
                    v8s q1 = *(const v8s*)&Gx[rloc * 136 +  32 + co];
                    v8s q2 = *(const v8s*)&Gx[rloc * 136 +  64 + co];
                    v8s q3 = *(const v8s*)&Gx[rloc * 136 +  96 + co];
                    v8s h2v = *(const v8s*)&H2[(size_t)gr * 512 + kg];
                    float cprev[8];
                    if (s == 0) {
                        if (gr < 256) {
                            v8s cv = *(const v8s*)&c_init[(size_t)gr * 512 + kg];
                            #pragma unroll
                            for (int e = 0; e < 8; ++e) cprev[e] = bf2f((unsigned short)cv[e]);
                        } else {
                            #pragma unroll
                            for (int e = 0; e < 8; ++e) cprev[e] = 0.f;
                        }
                    } else {
                        v8s cv = *(const v8s*)&Cst[(size_t)(gr - 256) * 512 + kg];
                        #pragma unroll
                        for (int e = 0; e < 8; ++e) cprev[e] = bf2f((unsigned short)cv[e]);
                    }
                    unsigned short hc[8], cc[8], hn[8];
                    #pragma unroll
                    for (int e = 0; e < 8; ++e) {
                        float gi = bf2f((unsigned short)q0[e]) + bls[ 0 + co + e];
                        float gf = bf2f((unsigned short)q1[e]) + bls[32 + co + e];
                        float gg = bf2f((unsigned short)q2[e]) + bls[64 + co + e];
                        float go = bf2f((unsigned short)q3[e]) + bls[96 + co + e];
                        float c  = fsig(gf) * cprev[e] + fsig(gi) * ftanh(gg);
                        float h  = fsig(go) * ftanh(c);
                        cc[e] = f2bf(c);
                        hc[e] = f2bf(h);
                        hn[e] = f2bf(h + bf2f((unsigned short)h2v[e]));
                    }
                    *(v8s*)&Cst[(size_t)gr * 512 + kg]  = *(const v8s*)cc;
                    *(v8s*)&Hraw[(size_t)gr * 512 + kg] = *(const v8s*)hc;
                    *(v8s*)&Hnew[(size_t)gr * 512 + kg] = *(const v8s*)hn;
                }
            }
        }
    }
}

// ---------------------------------------------------------------------------
// Tail (s >= 12): 64 WGs, resident [Whh|Wih] slice (32 rows x 1024 = 64 KB),
// K=1024 over [h_prev ; h2]; device-scope spin barrier between levels.
// ---------------------------------------------------------------------------
__global__ __launch_bounds__(256, 1)
void lstm_tail(const int* __restrict__ trows, const int* __restrict__ tcnt,
               const int* __restrict__ toffs, const int* __restrict__ maxS_p,
               const unsigned short* __restrict__ H2,
               const unsigned short* __restrict__ Wcat,
               const float* __restrict__ bsum,
               unsigned short* __restrict__ Hraw, unsigned short* __restrict__ Cst,
               unsigned short* __restrict__ Hnew,
               int* __restrict__ bar)
{
    const int mS = *maxS_p;
    if (mS < S0R) return;
    __shared__ __align__(16) unsigned short Wl[32 * 1024];   // 64 KB
    __shared__ __align__(16) unsigned short Hb[16 * 1024];   // 32 KB
    __shared__ float Gb[16 * 32];
    __shared__ float bl[32];
    __shared__ int rl[16];
    const int j    = blockIdx.x;
    const int tid  = threadIdx.x;
    const int w    = tid >> 6;
    const int lane = tid & 63;
    const int quad = lane >> 4;
    const int lr   = lane & 15;

    if (tid < 32) bl[tid] = bsum[(tid >> 3) * 512 + j * 8 + (tid & 7)];

    for (int e = tid; e < 32 * 128; e += 256) {
        int n = e >> 7, kb = e & 127;
        int g = n >> 3, c = n & 7;
        *(v8s*)&Wl[n * 1024 + kb * 8] = *(const v8s*)&Wcat[(size_t)(g * 512 + j * 8 + c) * 1024 + kb * 8];
    }

    int target = 0;
    for (int s = S0R; s <= mS; ++s) {
        const int lev = s - S0R;
        const int M   = tcnt[lev];
        const int off = toffs[lev];
        for (int ch = 0; ch < M; ch += 16) {
            __syncthreads();
            if (tid < 16) rl[tid] = (ch + tid < M) ? trows[off + ch + tid] : -1;
            __syncthreads();
            {   // stage [h_prev ; h2] rows
                int r = tid >> 4, seg = (tid & 15) * 32;
                int gr = rl[r];
                if (gr >= 0) {
                    const unsigned short* srcH = &Hraw[(size_t)(gr - 256) * 512 + seg];
                    const unsigned short* srcX = &H2[(size_t)gr * 512 + seg];
                    #pragma unroll
                    for (int q = 0; q < 4; ++q) {
                        *(v8s*)&Hb[r * 1024 + seg + q * 8]       = *(const v8s*)(srcH + q * 8);
                        *(v8s*)&Hb[r * 1024 + 512 + seg + q * 8] = *(const v8s*)(srcX + q * 8);
                    }
                } else {
                    v8s z = {0,0,0,0,0,0,0,0};
                    #pragma unroll
                    for (int q = 0; q < 4; ++q) {
                        *(v8s*)&Hb[r * 1024 + seg + q * 8]       = z;
                        *(v8s*)&Hb[r * 1024 + 512 + seg + q * 8] = z;
                    }
                }
            }
            __syncthreads();
            if (w < 2) {
                v4f acc = {0.f, 0.f, 0.f, 0.f};
                for (int k = 0; k < 32; ++k) {
                    v8s a = *(const v8s*)&Hb[lr * 1024 + k * 32 + quad * 8];
                    v8s b = *(const v8s*)&Wl[(w * 16 + lr) * 1024 + k * 32 + quad * 8];
                    acc = __builtin_amdgcn_mfma_f32_16x16x32_bf16(a, b, acc, 0, 0, 0);
                }
                #pragma unroll
                for (int r = 0; r < 4; ++r)
                    Gb[(quad * 4 + r) * 32 + w * 16 + lr] = acc[r];
            }
            __syncthreads();
            if (tid < 128) {
                int r = tid >> 3, c = tid & 7;
                int gr = rl[r];
                if (gr >= 0) {
                    int k = j * 8 + c;
                    float gi = Gb[r * 32 +  0 + c] + bl[ 0 + c];
                    float gf = Gb[r * 32 +  8 + c] + bl[ 8 + c];
                    float gg = Gb[r * 32 + 16 + c] + bl[16 + c];
                    float go = Gb[r * 32 + 24 + c] + bl[24 + c];
                    float cp = bf2f(Cst[(size_t)(gr - 256) * 512 + k]);
                    float cc = fsig(gf) * cp + fsig(gi) * ftanh(gg);
                    float hh = fsig(go) * ftanh(cc);
                    Cst[(size_t)gr * 512 + k]  = f2bf(cc);
                    Hraw[(size_t)gr * 512 + k] = f2bf(hh);
                    Hnew[(size_t)gr * 512 + k] = f2bf(hh + bf2f(H2[(size_t)gr * 512 + k]));
                }
            }
        }
        target += 64;
        __threadfence();
        __syncthreads();
        if (tid == 0) {
            __hip_atomic_fetch_add(bar, 1, __ATOMIC_RELEASE, __HIP_MEMORY_SCOPE_AGENT);
            while (__hip_atomic_load(bar, __ATOMIC_ACQUIRE, __HIP_MEMORY_SCOPE_AGENT) < target) {}
        }
        __syncthreads();
        __threadfence();
    }
}

// actor head: one wave per row over bf16 logits (stride 1024, 1000 valid)
__global__ void head_reduce(const unsigned short* __restrict__ logits,
                            const int* __restrict__ action,
                            float* __restrict__ out, int TB)
{
    const int r = blockIdx.x * 4 + (threadIdx.x >> 6);
    const int lane = threadIdx.x & 63;
    const unsigned short* row = logits + (size_t)r * 1024;
    float m = -1e30f, Z = 0.f, S = 0.f;
    v8s v0 = *(const v8s*)&row[lane * 8];
    #pragma unroll
    for (int e = 0; e < 8; ++e) {
        float xv = bf2f((unsigned short)v0[e]);
        if (xv > m) { float sc = __builtin_amdgcn_exp2f((m - xv) * L2E); Z *= sc; S *= sc; m = xv; }
        float ev = __builtin_amdgcn_exp2f((xv - m) * L2E);
        Z += ev; S += xv * ev;
    }
    v8s v1 = *(const v8s*)&row[512 + lane * 8];
    #pragma unroll
    for (int e = 0; e < 8; ++e) {
        int c = 512 + lane * 8 + e;
        if (c < 1000) {
            float xv = bf2f((unsigned short)v1[e]);
            if (xv > m) { float sc = __builtin_amdgcn_exp2f((m - xv) * L2E); Z *= sc; S *= sc; m = xv; }
            float ev = __builtin_amdgcn_exp2f((xv - m) * L2E);
            Z += ev; S += xv * ev;
        }
    }
    #pragma unroll
    for (int offb = 32; offb > 0; offb >>= 1) {
        float m2 = __shfl_xor(m, offb);
        float Z2 = __shfl_xor(Z, offb);
        float S2 = __shfl_xor(S, offb);
        float M  = fmaxf(m, m2);
        float s1 = __builtin_amdgcn_exp2f((m - M) * L2E), s2 = __builtin_amdgcn_exp2f((m2 - M) * L2E);
        Z = Z * s1 + Z2 * s2;
        S = S * s1 + S2 * s2;
        m = M;
    }
    if (lane == 0) {
        float lse = m + 0.6931471805599453f * __builtin_amdgcn_logf(Z);
        float xa  = bf2f(row[action[r]]);
        out[r]      = xa - lse;
        out[TB + r] = lse - S / Z;
    }
}

// critic head over fused AC1 (stride 1024, critic half at +512)
__global__ void critic_v(const unsigned short* __restrict__ AC, const float* __restrict__ Wc2,
                         const float* __restrict__ bc2, float* __restrict__ out, int TB)
{
    const int r = blockIdx.x * 4 + (threadIdx.x >> 6);
    const int lane = threadIdx.x & 63;
    const unsigned short* row = AC + (size_t)r * 1024 + 512;
    v8s hv = *(const v8s*)&row[lane * 8];
    float4 w0 = *(const float4*)&Wc2[lane * 8];
    float4 w1 = *(const float4*)&Wc2[lane * 8 + 4];
    float s = bf2f((unsigned short)hv[0]) * w0.x + bf2f((unsigned short)hv[1]) * w0.y +
              bf2f((unsigned short)hv[2]) * w0.z + bf2f((unsigned short)hv[3]) * w0.w +
              bf2f((unsigned short)hv[4]) * w1.x + bf2f((unsigned short)hv[5]) * w1.y +
              bf2f((unsigned short)hv[6]) * w1.z + bf2f((unsigned short)hv[7]) * w1.w;
    #pragma unroll
    for (int offb = 32; offb > 0; offb >>= 1) s += __shfl_xor(s, offb);
    if (lane == 0) out[2 * TB + r] = s + bc2[0];
}

extern "C" void kernel_launch(void* const* d_in, const int* in_sizes, int n_in,
                              void* d_out, int out_size, void* d_ws, size_t ws_size,
                              hipStream_t stream)
{
    const float* x    = (const float*)d_in[0];
    const int*  done  = (const int*)d_in[1];
    const int*  action= (const int*)d_in[2];
    const float* W_t1 = (const float*)d_in[4];
    const float* b_t1 = (const float*)d_in[5];
    const float* W_t2 = (const float*)d_in[6];
    const float* b_t2 = (const float*)d_in[7];
    const float* Wih  = (const float*)d_in[8];
    const float* Whh  = (const float*)d_in[9];
    const float* bih  = (const float*)d_in[10];
    const float* bhh  = (const float*)d_in[11];
    const float* Wa1  = (const float*)d_in[12];
    const float* ba1  = (const float*)d_in[13];
    const float* Wa2  = (const float*)d_in[14];
    const float* ba2  = (const float*)d_in[15];
    const float* Wc1  = (const float*)d_in[16];
    const float* bc1  = (const float*)d_in[17];
    const float* Wc2  = (const float*)d_in[18];
    const float* bc2  = (const float*)d_in[19];
    const float* h0   = (const float*)d_in[20];
    const float* c0   = (const float*)d_in[21];
    float* out = (float*)d_out;

    const int TB = in_sizes[1];      // 65536
    const int T  = TB / 256;         // 256

    const size_t MiB = 1024 * 1024;
    char* ws = (char*)d_ws;
    unsigned short* H1     = (unsigned short*)(ws);               // 64 MiB (trunk tmp)
    unsigned short* Hnew   = (unsigned short*)(ws);               // alias: H1 dead before rounds
    unsigned short* logits = (unsigned short*)(ws);               // alias: Hnew dead after AC1
    unsigned short* AC1    = (unsigned short*)(ws + 128 * MiB);   // 128 MiB
    unsigned short* Cst    = (unsigned short*)(ws + 256 * MiB);   // 64 MiB
    unsigned short* H2     = (unsigned short*)(ws + 320 * MiB);   // 64 MiB
    unsigned short* Hraw   = (unsigned short*)(ws + 384 * MiB);   // 64 MiB
    unsigned short* xbf    = Hraw;                                 // alias (x dead after trunk1)
    unsigned short* Wt1b   = (unsigned short*)(ws + 448 * MiB);
    unsigned short* Wt2b   = Wt1b + 512 * 512;
    unsigned short* Wcat   = Wt2b + 512 * 512;                     // 2048 x 1024
    unsigned short* Wacb   = Wcat + 2048 * 1024;                   // 1024 x 512
    unsigned short* Wa2b   = Wacb + 1024 * 512;                    // 1024 x 512
    unsigned short* h_init = Wa2b + 1024 * 512;
    unsigned short* c_init = h_init + 256 * 512;
    unsigned short* zbuf   = c_init + 256 * 512;
    int* rows   = (int*)(zbuf + 512);
    int* trows  = rows + 65536;
    int* counts = trows + 65536;
    int* offs   = counts + S0R;
    int* tcnt   = offs + S0R;
    int* toffs  = tcnt + NLEV;
    int* maxS   = toffs + NLEV;
    int* bar    = maxS + 1;
    float* bsum = (float*)(bar + 1);          // 2048 f32
    float* bac  = bsum + 2048;                // 1024 f32

    dim3 blk(256);
    dim3 blk5(512);

    // dtype conversions + weight packing + init + segment lists
    cvt8<<<16384, blk, 0, stream>>>(x, xbf);
    cvt8<<<128,  blk, 0, stream>>>(W_t1, Wt1b);
    cvt8<<<128,  blk, 0, stream>>>(W_t2, Wt2b);
    cvt_cat<<<1024, blk, 0, stream>>>(Whh, Wih, Wcat);
    cvt8<<<128,  blk, 0, stream>>>(Wa1, Wacb);
    cvt8<<<128,  blk, 0, stream>>>(Wc1, Wacb + 512 * 512);
    wa2pad<<<2048, blk, 0, stream>>>(Wa2, Wa2b);
    prep_misc<<<12, blk, 0, stream>>>(bih, bhh, ba1, bc1, bsum, bac);
    init_state<<<256, blk, 0, stream>>>(h0, c0, done, h_init, c_init, zbuf);
    seg_prep<<<1, blk, 0, stream>>>(done, rows, counts, offs, trows, tcnt, toffs, maxS, bar, T);

    // trunk
    gemm256<true ><<<512, blk5, 0, stream>>>(xbf, Wt1b, b_t1, H1, 512, 512, 2, 512);
    gemm256<true ><<<512, blk5, 0, stream>>>(H1,  Wt2b, b_t2, H2, 512, 512, 2, 512);

    // segment-parallel LSTM, x-gates fused (K=1024), residual fused, XCD-grouped
    static const int Gs[S0R] = {256, 128, 64, 32, 16, 8, 4, 2, 1, 1, 1, 1};
    for (int s = 0; s < S0R; ++s)
        lstm_round<<<dim3(16 * Gs[s]), blk, 0, stream>>>(rows, counts, offs, s, H2, Wcat, bsum,
                                                         h_init, c_init, zbuf, Hraw, Cst, Hnew);
    lstm_tail<<<64, blk, 0, stream>>>(trows, tcnt, toffs, maxS, H2, Wcat, bsum, Hraw, Cst, Hnew, bar);

    // fused actor/critic first layers: AC1 = tanh(Hnew @ [Wa1;Wc1]^T + [ba1;bc1])
    gemm256<true ><<<1024, blk5, 0, stream>>>(Hnew, Wacb, bac, AC1, 1024, 1024, 4, 512);

    // actor logits from A1 half (stride-1024 A)
    gemm256<false><<<1024, blk5, 0, stream>>>(AC1, Wa2b, ba2, logits, 1000, 1024, 4, 1024);
    head_reduce<<<TB / 4, blk, 0, stream>>>(logits, action, out, TB);

    // critic from C1 half
    critic_v<<<TB / 4, blk, 0, stream>>>(AC1, Wc2, bc2, out, TB);
}